// Round 1
// baseline (3229.126 us; speedup 1.0000x reference)
//
#include <hip/hip_runtime.h>
#include <cstdint>
#include <cstddef>

#define B_ 8
#define S_ 1024
#define D_ 512
#define H_ 8
#define DH_ 64
#define FF_ 2048
#define INNER_ 1024
#define NROWS 8192
#define INV_SQRT_D 0.04419417382415922f  // 1/sqrt(512)

__device__ __forceinline__ float sigmoidf_(float x) { return 1.f / (1.f + expf(-x)); }

// ---------------- LayerNorm over D=512, one block (256 thr) per row ----------------
__global__ __launch_bounds__(256) void ln_kernel(const float* __restrict__ in,
    const float* __restrict__ g, const float* __restrict__ b,
    float* __restrict__ out) {
  int row = blockIdx.x;
  const float* x = in + (size_t)row * D_;
  float* o = out + (size_t)row * D_;
  int t = threadIdx.x;
  float v0 = x[t], v1 = x[t + 256];
  float s = v0 + v1, q = v0 * v0 + v1 * v1;
#pragma unroll
  for (int off = 32; off > 0; off >>= 1) {
    s += __shfl_down(s, off);
    q += __shfl_down(q, off);
  }
  __shared__ float red[8];
  int wid = t >> 6, lane = t & 63;
  if (lane == 0) { red[wid] = s; red[wid + 4] = q; }
  __syncthreads();
  if (t == 0) {
    float S = red[0] + red[1] + red[2] + red[3];
    float Q = red[4] + red[5] + red[6] + red[7];
    float mean = S * (1.f / D_);
    float var = Q * (1.f / D_) - mean * mean;
    red[0] = mean;
    red[1] = rsqrtf(var + 1e-5f);
  }
  __syncthreads();
  float mean = red[0], inv = red[1];
  o[t] = (v0 - mean) * inv * g[t] + b[t];
  o[t + 256] = (v1 - mean) * inv * g[t + 256] + b[t + 256];
}

// ---------------- Tiled fp32 GEMM: C[M,N] = epi(A[M,K] @ W[K,N] + bias) ----------------
// EPI: 0 = bias, 1 = bias+swish, 2 = 0.5*(bias'ed)+res, 3 = bias'ed+res
template <int EPI>
__global__ __launch_bounds__(256) void gemm_kernel(const float* __restrict__ A,
    const float* __restrict__ W, const float* __restrict__ bias,
    const float* __restrict__ res, float* __restrict__ C, int M, int N, int K) {
  __shared__ float As[16][68];
  __shared__ float Ws[16][68];
  int tid = threadIdx.x;
  int bm = blockIdx.y << 6, bn = blockIdx.x << 6;
  int tx = tid & 15, ty = tid >> 4;
  float acc[4][4] = {};
  int am = tid >> 2, ak4 = (tid & 3) << 2;
  int wk = tid >> 4, wn4 = (tid & 15) << 2;
  const float* Ap = A + (size_t)(bm + am) * K + ak4;
  const float* Wp = W + (size_t)wk * N + bn + wn4;
  for (int k0 = 0; k0 < K; k0 += 16) {
    float4 av = *(const float4*)(Ap + k0);
    float4 wv = *(const float4*)(Wp + (size_t)k0 * N);
    As[ak4 + 0][am] = av.x;
    As[ak4 + 1][am] = av.y;
    As[ak4 + 2][am] = av.z;
    As[ak4 + 3][am] = av.w;
    *(float4*)&Ws[wk][wn4] = wv;
    __syncthreads();
#pragma unroll
    for (int k = 0; k < 16; ++k) {
      float a0 = As[k][(ty << 2) + 0], a1 = As[k][(ty << 2) + 1];
      float a2 = As[k][(ty << 2) + 2], a3 = As[k][(ty << 2) + 3];
      float w0 = Ws[k][(tx << 2) + 0], w1 = Ws[k][(tx << 2) + 1];
      float w2 = Ws[k][(tx << 2) + 2], w3 = Ws[k][(tx << 2) + 3];
      acc[0][0] += a0 * w0; acc[0][1] += a0 * w1; acc[0][2] += a0 * w2; acc[0][3] += a0 * w3;
      acc[1][0] += a1 * w0; acc[1][1] += a1 * w1; acc[1][2] += a1 * w2; acc[1][3] += a1 * w3;
      acc[2][0] += a2 * w0; acc[2][1] += a2 * w1; acc[2][2] += a2 * w2; acc[2][3] += a2 * w3;
      acc[3][0] += a3 * w0; acc[3][1] += a3 * w1; acc[3][2] += a3 * w2; acc[3][3] += a3 * w3;
    }
    __syncthreads();
  }
#pragma unroll
  for (int i = 0; i < 4; ++i) {
    int m = bm + (ty << 2) + i;
#pragma unroll
    for (int j = 0; j < 4; ++j) {
      int n = bn + (tx << 2) + j;
      float v = acc[i][j] + (bias ? bias[n] : 0.f);
      size_t idx = (size_t)m * N + n;
      if (EPI == 1) v = v * sigmoidf_(v);
      else if (EPI == 2) v = 0.5f * v + res[idx];
      else if (EPI == 3) v = v + res[idx];
      C[idx] = v;
    }
  }
}

// ---------------- sinusoidal positional encoding (S=1024, D=512) ----------------
__global__ __launch_bounds__(256) void pe_kernel(float* __restrict__ pe) {
  int t = blockIdx.x, i = threadIdx.x;  // i in 0..255
  float freq = expf((float)(2 * i) * (-9.2103403719761836f / 512.f));  // ln(10000)
  float arg = (float)t * freq;
  pe[(size_t)t * D_ + 2 * i] = sinf(arg);
  pe[(size_t)t * D_ + 2 * i + 1] = cosf(arg);
}

// ---------------- attention: raw pos scores P[z,i,t] = (q+v_bias).pos  (64x64 tile) ----------------
__global__ __launch_bounds__(256) void attn_pos_kernel(const float* __restrict__ q,
    const float* __restrict__ pos, const float* __restrict__ vbias,
    float* __restrict__ P, int bh0) {
  int z = blockIdx.z;
  int bh = bh0 + z, b = bh >> 3, h = bh & 7;
  int i0 = blockIdx.y << 6, t0 = blockIdx.x << 6;
  __shared__ float Qs[64][68];  // [d][i]
  __shared__ float Ps[64][68];  // [d][t]
  int tid = threadIdx.x;
  int am = tid >> 2, ak4 = (tid & 3) << 2;
  const float* qp = q + ((size_t)((b * S_ + i0 + am) * H_ + h) << 6);
  const float* pp = pos + (size_t)(t0 + am) * D_ + h * DH_;
  const float* vb = vbias + h * DH_;
#pragma unroll
  for (int e = 0; e < 4; ++e) {
    int d = ak4 + (e << 4);
    float4 qv = *(const float4*)(qp + d);
    float4 bv = *(const float4*)(vb + d);
    Qs[d + 0][am] = qv.x + bv.x;
    Qs[d + 1][am] = qv.y + bv.y;
    Qs[d + 2][am] = qv.z + bv.z;
    Qs[d + 3][am] = qv.w + bv.w;
    float4 pv = *(const float4*)(pp + d);
    Ps[d + 0][am] = pv.x;
    Ps[d + 1][am] = pv.y;
    Ps[d + 2][am] = pv.z;
    Ps[d + 3][am] = pv.w;
  }
  __syncthreads();
  int tx = tid & 15, ty = tid >> 4;
  float acc[4][4] = {};
#pragma unroll 8
  for (int d = 0; d < 64; ++d) {
    float a0 = Qs[d][(ty << 2) + 0], a1 = Qs[d][(ty << 2) + 1];
    float a2 = Qs[d][(ty << 2) + 2], a3 = Qs[d][(ty << 2) + 3];
    float w0 = Ps[d][(tx << 2) + 0], w1 = Ps[d][(tx << 2) + 1];
    float w2 = Ps[d][(tx << 2) + 2], w3 = Ps[d][(tx << 2) + 3];
    acc[0][0] += a0 * w0; acc[0][1] += a0 * w1; acc[0][2] += a0 * w2; acc[0][3] += a0 * w3;
    acc[1][0] += a1 * w0; acc[1][1] += a1 * w1; acc[1][2] += a1 * w2; acc[1][3] += a1 * w3;
    acc[2][0] += a2 * w0; acc[2][1] += a2 * w1; acc[2][2] += a2 * w2; acc[2][3] += a2 * w3;
    acc[3][0] += a3 * w0; acc[3][1] += a3 * w1; acc[3][2] += a3 * w2; acc[3][3] += a3 * w3;
  }
#pragma unroll
  for (int i = 0; i < 4; ++i)
#pragma unroll
    for (int j = 0; j < 4; ++j)
      P[((size_t)z * S_ + i0 + (ty << 2) + i) * S_ + t0 + (tx << 2) + j] = acc[i][j];
}

// ---------------- attention scores with rel-shift gather ----------------
__global__ __launch_bounds__(256) void attn_score_kernel(const float* __restrict__ q,
    const float* __restrict__ k, const float* __restrict__ ubias,
    const float* __restrict__ P, float* __restrict__ Sout, int bh0) {
  int z = blockIdx.z;
  int bh = bh0 + z, b = bh >> 3, h = bh & 7;
  int i0 = blockIdx.y << 6, j0 = blockIdx.x << 6;
  __shared__ float Qs[64][68];
  __shared__ float Ks[64][68];
  int tid = threadIdx.x;
  int am = tid >> 2, ak4 = (tid & 3) << 2;
  const float* qp = q + ((size_t)((b * S_ + i0 + am) * H_ + h) << 6);
  const float* kp = k + ((size_t)((b * S_ + j0 + am) * H_ + h) << 6);
  const float* ub = ubias + h * DH_;
#pragma unroll
  for (int e = 0; e < 4; ++e) {
    int d = ak4 + (e << 4);
    float4 qv = *(const float4*)(qp + d);
    float4 bv = *(const float4*)(ub + d);
    Qs[d + 0][am] = qv.x + bv.x;
    Qs[d + 1][am] = qv.y + bv.y;
    Qs[d + 2][am] = qv.z + bv.z;
    Qs[d + 3][am] = qv.w + bv.w;
    float4 kv = *(const float4*)(kp + d);
    Ks[d + 0][am] = kv.x;
    Ks[d + 1][am] = kv.y;
    Ks[d + 2][am] = kv.z;
    Ks[d + 3][am] = kv.w;
  }
  __syncthreads();
  int tx = tid & 15, ty = tid >> 4;
  float acc[4][4] = {};
#pragma unroll 8
  for (int d = 0; d < 64; ++d) {
    float a0 = Qs[d][(ty << 2) + 0], a1 = Qs[d][(ty << 2) + 1];
    float a2 = Qs[d][(ty << 2) + 2], a3 = Qs[d][(ty << 2) + 3];
    float w0 = Ks[d][(tx << 2) + 0], w1 = Ks[d][(tx << 2) + 1];
    float w2 = Ks[d][(tx << 2) + 2], w3 = Ks[d][(tx << 2) + 3];
    acc[0][0] += a0 * w0; acc[0][1] += a0 * w1; acc[0][2] += a0 * w2; acc[0][3] += a0 * w3;
    acc[1][0] += a1 * w0; acc[1][1] += a1 * w1; acc[1][2] += a1 * w2; acc[1][3] += a1 * w3;
    acc[2][0] += a2 * w0; acc[2][1] += a2 * w1; acc[2][2] += a2 * w2; acc[2][3] += a2 * w3;
    acc[3][0] += a3 * w0; acc[3][1] += a3 * w1; acc[3][2] += a3 * w2; acc[3][3] += a3 * w3;
  }
#pragma unroll
  for (int i = 0; i < 4; ++i) {
    int iG = i0 + (ty << 2) + i;
#pragma unroll
    for (int j = 0; j < 4; ++j) {
      int jG = j0 + (tx << 2) + j;
      float pv;
      if (jG <= iG)
        pv = P[((size_t)z * S_ + iG) * S_ + (S_ - 1 - iG + jG)];
      else if (jG == iG + 1)
        pv = 0.f;
      else
        pv = P[((size_t)z * S_ + iG + 1) * S_ + (jG - iG - 2)];
      Sout[((size_t)z * S_ + iG) * S_ + jG] = (acc[i][j] + pv) * INV_SQRT_D;
    }
  }
}

// ---------------- row softmax over 1024 cols, in place ----------------
__global__ __launch_bounds__(256) void softmax_kernel(float* __restrict__ Sb) {
  float* p = Sb + ((size_t)blockIdx.y * S_ + blockIdx.x) * S_;
  int t = threadIdx.x;
  float v[4];
  float mx = -1e30f;
#pragma unroll
  for (int e = 0; e < 4; ++e) {
    v[e] = p[t + (e << 8)];
    mx = fmaxf(mx, v[e]);
  }
#pragma unroll
  for (int off = 32; off > 0; off >>= 1) mx = fmaxf(mx, __shfl_xor(mx, off));
  __shared__ float red[8];
  int wid = t >> 6, lane = t & 63;
  if (lane == 0) red[wid] = mx;
  __syncthreads();
  mx = fmaxf(fmaxf(red[0], red[1]), fmaxf(red[2], red[3]));
  float sum = 0.f;
#pragma unroll
  for (int e = 0; e < 4; ++e) {
    v[e] = expf(v[e] - mx);
    sum += v[e];
  }
#pragma unroll
  for (int off = 32; off > 0; off >>= 1) sum += __shfl_xor(sum, off);
  if (lane == 0) red[4 + wid] = sum;
  __syncthreads();
  sum = red[4] + red[5] + red[6] + red[7];
  float inv = 1.f / sum;
#pragma unroll
  for (int e = 0; e < 4; ++e) p[t + (e << 8)] = v[e] * inv;
}

// ---------------- ctx[b,i,h,:] = sum_j A[z,i,j] * v[b,j,h,:]  (i-tile 16 x d 64) ----------------
__global__ __launch_bounds__(256) void attn_ctx_kernel(const float* __restrict__ A,
    const float* __restrict__ v, float* __restrict__ ctx, int bh0) {
  int z = blockIdx.y;
  int bh = bh0 + z, b = bh >> 3, h = bh & 7;
  int i0 = blockIdx.x << 4;
  __shared__ float Asm[16][36];
  __shared__ float Vs[32][68];
  int tid = threadIdx.x;
  int ty = tid >> 4;  // i 0..15
  int tx = tid & 15;  // d = tx*4..
  float acc[4] = {};
  for (int j0 = 0; j0 < S_; j0 += 32) {
    {
      int flat = tid << 1, r = flat >> 5, c = flat & 31;
      float2 a2 = *(const float2*)(A + ((size_t)z * S_ + i0 + r) * S_ + j0 + c);
      Asm[r][c] = a2.x;
      Asm[r][c + 1] = a2.y;
    }
#pragma unroll
    for (int e = 0; e < 8; ++e) {
      int flat = tid + (e << 8), r = flat >> 6, c = flat & 63;
      Vs[r][c] = v[((size_t)((b * S_ + j0 + r) * H_ + h) << 6) + c];
    }
    __syncthreads();
#pragma unroll
    for (int jj = 0; jj < 32; ++jj) {
      float a = Asm[ty][jj];
      acc[0] += a * Vs[jj][(tx << 2) + 0];
      acc[1] += a * Vs[jj][(tx << 2) + 1];
      acc[2] += a * Vs[jj][(tx << 2) + 2];
      acc[3] += a * Vs[jj][(tx << 2) + 3];
    }
    __syncthreads();
  }
  float4 o = {acc[0], acc[1], acc[2], acc[3]};
  *(float4*)(ctx + ((size_t)((b * S_ + i0 + ty) * H_ + h) << 6) + (tx << 2)) = o;
}

// ---------------- GLU: z[r,c] = h[r,c] * sigmoid(h[r,1024+c]) ----------------
__global__ __launch_bounds__(256) void glu_kernel(const float* __restrict__ hbuf,
                                                  float* __restrict__ z) {
  size_t idx = (size_t)blockIdx.x * 256 + threadIdx.x;
  size_t row = idx >> 10, c = idx & 1023;
  float a = hbuf[row * 2048 + c];
  float g = hbuf[row * 2048 + 1024 + c];
  z[idx] = a * sigmoidf_(g);
}

// ---------------- depthwise conv k=31 (+BN+swish), layout (b,s,c) ----------------
__global__ __launch_bounds__(256) void dwconv_kernel(const float* __restrict__ z,
    const float* __restrict__ w, const float* __restrict__ wb,
    const float* __restrict__ bng, const float* __restrict__ bnb,
    const float* __restrict__ bnm, const float* __restrict__ bnv,
    float* __restrict__ out) {
  int s = blockIdx.x, b = blockIdx.y;
  int t = threadIdx.x;
#pragma unroll
  for (int e = 0; e < 4; ++e) {
    int c = t + (e << 8);
    float acc = 0.f;
#pragma unroll
    for (int kk = 0; kk < 31; ++kk) {
      int sr = s + kk - 15;
      if (sr >= 0 && sr < S_) acc += z[((size_t)(b * S_ + sr) << 10) + c] * w[c * 31 + kk];
    }
    acc += wb[c];
    float scale = bng[c] * rsqrtf(bnv[c] + 1e-5f);
    acc = (acc - bnm[c]) * scale + bnb[c];
    acc = acc * sigmoidf_(acc);
    out[((size_t)(b * S_ + s) << 10) + c] = acc;
  }
}

extern "C" void kernel_launch(void* const* d_in, const int* in_sizes, int n_in,
                              void* d_out, int out_size, void* d_ws, size_t ws_size,
                              hipStream_t stream) {
  const float* x_in = (const float*)d_in[0];
  const float* ff1_ln_g = (const float*)d_in[1];
  const float* ff1_ln_b = (const float*)d_in[2];
  const float* ff1_w1 = (const float*)d_in[3];
  const float* ff1_b1 = (const float*)d_in[4];
  const float* ff1_w2 = (const float*)d_in[5];
  const float* ff1_b2 = (const float*)d_in[6];
  const float* attn_ln_g = (const float*)d_in[7];
  const float* attn_ln_b = (const float*)d_in[8];
  const float* wq = (const float*)d_in[9];
  const float* bq = (const float*)d_in[10];
  const float* wk = (const float*)d_in[11];
  const float* bk = (const float*)d_in[12];
  const float* wv = (const float*)d_in[13];
  const float* bv = (const float*)d_in[14];
  const float* wpos = (const float*)d_in[15];
  const float* u_bias = (const float*)d_in[16];
  const float* v_bias = (const float*)d_in[17];
  const float* wo = (const float*)d_in[18];
  const float* bo = (const float*)d_in[19];
  const float* conv_ln_g = (const float*)d_in[20];
  const float* conv_ln_b = (const float*)d_in[21];
  const float* pw1_w = (const float*)d_in[22];
  const float* pw1_b = (const float*)d_in[23];
  const float* dw_w = (const float*)d_in[24];
  const float* dw_b = (const float*)d_in[25];
  const float* bn_g = (const float*)d_in[26];
  const float* bn_b = (const float*)d_in[27];
  const float* bn_mean = (const float*)d_in[28];
  const float* bn_var = (const float*)d_in[29];
  const float* pw2_w = (const float*)d_in[30];
  const float* pw2_b = (const float*)d_in[31];
  const float* ff2_ln_g = (const float*)d_in[32];
  const float* ff2_ln_b = (const float*)d_in[33];
  const float* ff2_w1 = (const float*)d_in[34];
  const float* ff2_b1 = (const float*)d_in[35];
  const float* ff2_w2 = (const float*)d_in[36];
  const float* ff2_b2 = (const float*)d_in[37];
  const float* norm_g = (const float*)d_in[38];
  const float* norm_b = (const float*)d_in[39];

  float* ws = (float*)d_ws;
  const size_t M1 = 1u << 22;  // 4M floats
  float* xb = ws;               // 4M  running residual
  float* yb = ws + M1;          // 4M  LN output
  float* hb = ws + 2 * M1;      // 16M hidden / P+S chunks / conv
  float* qb = ws + 6 * M1;      // 4M
  float* kb = ws + 7 * M1;      // 4M
  float* vb = ws + 8 * M1;      // 4M
  float* ctxb = ws + 9 * M1;    // 4M
  float* posb = ws + 10 * M1;   // 0.5M
  float* peb = hb;              // PE lives in hb (free at that point)
  float* zb = qb;               // GLU output (8M floats over q+k region, free post-attn)
  float* Pb = hb;               // 8M floats
  float* Sb = hb + 8 * M1 / 4;  // 8M floats  (hb + 8388608)

  dim3 blk(256);

  // ---- FF1 half-residual ----
  ln_kernel<<<NROWS, blk, 0, stream>>>(x_in, ff1_ln_g, ff1_ln_b, yb);
  gemm_kernel<1><<<dim3(FF_ / 64, NROWS / 64), blk, 0, stream>>>(yb, ff1_w1, ff1_b1, nullptr, hb, NROWS, FF_, D_);
  gemm_kernel<2><<<dim3(D_ / 64, NROWS / 64), blk, 0, stream>>>(hb, ff1_w2, ff1_b2, x_in, xb, NROWS, D_, FF_);

  // ---- attention ----
  ln_kernel<<<NROWS, blk, 0, stream>>>(xb, attn_ln_g, attn_ln_b, yb);
  gemm_kernel<0><<<dim3(D_ / 64, NROWS / 64), blk, 0, stream>>>(yb, wq, bq, nullptr, qb, NROWS, D_, D_);
  gemm_kernel<0><<<dim3(D_ / 64, NROWS / 64), blk, 0, stream>>>(yb, wk, bk, nullptr, kb, NROWS, D_, D_);
  gemm_kernel<0><<<dim3(D_ / 64, NROWS / 64), blk, 0, stream>>>(yb, wv, bv, nullptr, vb, NROWS, D_, D_);
  pe_kernel<<<S_, blk, 0, stream>>>(peb);
  gemm_kernel<0><<<dim3(D_ / 64, S_ / 64), blk, 0, stream>>>(peb, wpos, nullptr, nullptr, posb, S_, D_, D_);

  for (int c = 0; c < 8; ++c) {
    int bh0 = c * 8;
    attn_pos_kernel<<<dim3(16, 16, 8), blk, 0, stream>>>(qb, posb, v_bias, Pb, bh0);
    attn_score_kernel<<<dim3(16, 16, 8), blk, 0, stream>>>(qb, kb, u_bias, Pb, Sb, bh0);
    softmax_kernel<<<dim3(S_, 8), blk, 0, stream>>>(Sb);
    attn_ctx_kernel<<<dim3(S_ / 16, 8), blk, 0, stream>>>(Sb, vb, ctxb, bh0);
  }
  gemm_kernel<3><<<dim3(D_ / 64, NROWS / 64), blk, 0, stream>>>(ctxb, wo, bo, xb, xb, NROWS, D_, D_);

  // ---- conv module ----
  ln_kernel<<<NROWS, blk, 0, stream>>>(xb, conv_ln_g, conv_ln_b, yb);
  gemm_kernel<0><<<dim3(2 * INNER_ / 64, NROWS / 64), blk, 0, stream>>>(yb, pw1_w, pw1_b, nullptr, hb, NROWS, 2 * INNER_, D_);
  glu_kernel<<<NROWS * INNER_ / 256, blk, 0, stream>>>(hb, zb);
  dwconv_kernel<<<dim3(S_, B_), blk, 0, stream>>>(zb, dw_w, dw_b, bn_g, bn_b, bn_mean, bn_var, hb);
  gemm_kernel<3><<<dim3(D_ / 64, NROWS / 64), blk, 0, stream>>>(hb, pw2_w, pw2_b, xb, xb, NROWS, D_, INNER_);

  // ---- FF2 half-residual ----
  ln_kernel<<<NROWS, blk, 0, stream>>>(xb, ff2_ln_g, ff2_ln_b, yb);
  gemm_kernel<1><<<dim3(FF_ / 64, NROWS / 64), blk, 0, stream>>>(yb, ff2_w1, ff2_b1, nullptr, hb, NROWS, FF_, D_);
  gemm_kernel<2><<<dim3(D_ / 64, NROWS / 64), blk, 0, stream>>>(hb, ff2_w2, ff2_b2, xb, xb, NROWS, D_, FF_);

  // ---- final LN ----
  ln_kernel<<<NROWS, blk, 0, stream>>>(xb, norm_g, norm_b, (float*)d_out);
}

// Round 2
// 2393.903 us; speedup vs baseline: 1.3489x; 1.3489x over previous
//
#include <hip/hip_runtime.h>
#include <cstdint>
#include <cstddef>

#define B_ 8
#define S_ 1024
#define D_ 512
#define H_ 8
#define DH_ 64
#define FF_ 2048
#define INNER_ 1024
#define NROWS 8192
#define INV_SQRT_D 0.04419417382415922f  // 1/sqrt(512)

__device__ __forceinline__ float sigmoidf_(float x) { return 1.f / (1.f + expf(-x)); }

// ---------------- LayerNorm over D=512, one block (256 thr) per row ----------------
__global__ __launch_bounds__(256) void ln_kernel(const float* __restrict__ in,
    const float* __restrict__ g, const float* __restrict__ b,
    float* __restrict__ out) {
  int row = blockIdx.x;
  const float* x = in + (size_t)row * D_;
  float* o = out + (size_t)row * D_;
  int t = threadIdx.x;
  float v0 = x[t], v1 = x[t + 256];
  float s = v0 + v1, q = v0 * v0 + v1 * v1;
#pragma unroll
  for (int off = 32; off > 0; off >>= 1) {
    s += __shfl_down(s, off);
    q += __shfl_down(q, off);
  }
  __shared__ float red[8];
  int wid = t >> 6, lane = t & 63;
  if (lane == 0) { red[wid] = s; red[wid + 4] = q; }
  __syncthreads();
  if (t == 0) {
    float S = red[0] + red[1] + red[2] + red[3];
    float Q = red[4] + red[5] + red[6] + red[7];
    float mean = S * (1.f / D_);
    float var = Q * (1.f / D_) - mean * mean;
    red[0] = mean;
    red[1] = rsqrtf(var + 1e-5f);
  }
  __syncthreads();
  float mean = red[0], inv = red[1];
  o[t] = (v0 - mean) * inv * g[t] + b[t];
  o[t + 256] = (v1 - mean) * inv * g[t + 256] + b[t + 256];
}

// ---------------- Tiled fp32 GEMM: C[M,N] = epi(A[M,K] @ W[K,N] + bias) ----------------
// EPI: 0 = bias, 1 = bias+swish, 2 = 0.5*(bias'ed)+res, 3 = bias'ed+res
template <int EPI>
__global__ __launch_bounds__(256) void gemm_kernel(const float* __restrict__ A,
    const float* __restrict__ W, const float* __restrict__ bias,
    const float* __restrict__ res, float* __restrict__ C, int M, int N, int K) {
  __shared__ float As[16][68];
  __shared__ float Ws[16][68];
  int tid = threadIdx.x;
  int bm = blockIdx.y << 6, bn = blockIdx.x << 6;
  int tx = tid & 15, ty = tid >> 4;
  float acc[4][4] = {};
  int am = tid >> 2, ak4 = (tid & 3) << 2;
  int wk = tid >> 4, wn4 = (tid & 15) << 2;
  const float* Ap = A + (size_t)(bm + am) * K + ak4;
  const float* Wp = W + (size_t)wk * N + bn + wn4;
  for (int k0 = 0; k0 < K; k0 += 16) {
    float4 av = *(const float4*)(Ap + k0);
    float4 wv = *(const float4*)(Wp + (size_t)k0 * N);
    As[ak4 + 0][am] = av.x;
    As[ak4 + 1][am] = av.y;
    As[ak4 + 2][am] = av.z;
    As[ak4 + 3][am] = av.w;
    *(float4*)&Ws[wk][wn4] = wv;
    __syncthreads();
#pragma unroll
    for (int k = 0; k < 16; ++k) {
      float a0 = As[k][(ty << 2) + 0], a1 = As[k][(ty << 2) + 1];
      float a2 = As[k][(ty << 2) + 2], a3 = As[k][(ty << 2) + 3];
      float w0 = Ws[k][(tx << 2) + 0], w1 = Ws[k][(tx << 2) + 1];
      float w2 = Ws[k][(tx << 2) + 2], w3 = Ws[k][(tx << 2) + 3];
      acc[0][0] += a0 * w0; acc[0][1] += a0 * w1; acc[0][2] += a0 * w2; acc[0][3] += a0 * w3;
      acc[1][0] += a1 * w0; acc[1][1] += a1 * w1; acc[1][2] += a1 * w2; acc[1][3] += a1 * w3;
      acc[2][0] += a2 * w0; acc[2][1] += a2 * w1; acc[2][2] += a2 * w2; acc[2][3] += a2 * w3;
      acc[3][0] += a3 * w0; acc[3][1] += a3 * w1; acc[3][2] += a3 * w2; acc[3][3] += a3 * w3;
    }
    __syncthreads();
  }
#pragma unroll
  for (int i = 0; i < 4; ++i) {
    int m = bm + (ty << 2) + i;
#pragma unroll
    for (int j = 0; j < 4; ++j) {
      int n = bn + (tx << 2) + j;
      float v = acc[i][j] + (bias ? bias[n] : 0.f);
      size_t idx = (size_t)m * N + n;
      if (EPI == 1) v = v * sigmoidf_(v);
      else if (EPI == 2) v = 0.5f * v + res[idx];
      else if (EPI == 3) v = v + res[idx];
      C[idx] = v;
    }
  }
}

// ---------------- sinusoidal positional encoding (S=1024, D=512) ----------------
__global__ __launch_bounds__(256) void pe_kernel(float* __restrict__ pe) {
  int t = blockIdx.x, i = threadIdx.x;  // i in 0..255
  float freq = expf((float)(2 * i) * (-9.2103403719761836f / 512.f));  // ln(10000)
  float arg = (float)t * freq;
  pe[(size_t)t * D_ + 2 * i] = sinf(arg);
  pe[(size_t)t * D_ + 2 * i + 1] = cosf(arg);
}

// ---------------- attention: raw pos scores P[z,i,t] = (q+v_bias).pos  (64x64 tile) ----------------
__global__ __launch_bounds__(256) void attn_pos_kernel(const float* __restrict__ q,
    const float* __restrict__ pos, const float* __restrict__ vbias,
    float* __restrict__ P, int bh0) {
  int z = blockIdx.z;
  int bh = bh0 + z, b = bh >> 3, h = bh & 7;
  int i0 = blockIdx.y << 6, t0 = blockIdx.x << 6;
  __shared__ float Qs[64][68];  // [d][i]
  __shared__ float Ps[64][68];  // [d][t]
  int tid = threadIdx.x;
  int am = tid >> 2, ak4 = (tid & 3) << 2;
  const float* qp = q + ((size_t)((b * S_ + i0 + am) * H_ + h) << 6);
  const float* pp = pos + (size_t)(t0 + am) * D_ + h * DH_;
  const float* vb = vbias + h * DH_;
#pragma unroll
  for (int e = 0; e < 4; ++e) {
    int d = ak4 + (e << 4);
    float4 qv = *(const float4*)(qp + d);
    float4 bv = *(const float4*)(vb + d);
    Qs[d + 0][am] = qv.x + bv.x;
    Qs[d + 1][am] = qv.y + bv.y;
    Qs[d + 2][am] = qv.z + bv.z;
    Qs[d + 3][am] = qv.w + bv.w;
    float4 pv = *(const float4*)(pp + d);
    Ps[d + 0][am] = pv.x;
    Ps[d + 1][am] = pv.y;
    Ps[d + 2][am] = pv.z;
    Ps[d + 3][am] = pv.w;
  }
  __syncthreads();
  int tx = tid & 15, ty = tid >> 4;
  float acc[4][4] = {};
#pragma unroll 8
  for (int d = 0; d < 64; ++d) {
    float a0 = Qs[d][(ty << 2) + 0], a1 = Qs[d][(ty << 2) + 1];
    float a2 = Qs[d][(ty << 2) + 2], a3 = Qs[d][(ty << 2) + 3];
    float w0 = Ps[d][(tx << 2) + 0], w1 = Ps[d][(tx << 2) + 1];
    float w2 = Ps[d][(tx << 2) + 2], w3 = Ps[d][(tx << 2) + 3];
    acc[0][0] += a0 * w0; acc[0][1] += a0 * w1; acc[0][2] += a0 * w2; acc[0][3] += a0 * w3;
    acc[1][0] += a1 * w0; acc[1][1] += a1 * w1; acc[1][2] += a1 * w2; acc[1][3] += a1 * w3;
    acc[2][0] += a2 * w0; acc[2][1] += a2 * w1; acc[2][2] += a2 * w2; acc[2][3] += a2 * w3;
    acc[3][0] += a3 * w0; acc[3][1] += a3 * w1; acc[3][2] += a3 * w2; acc[3][3] += a3 * w3;
  }
#pragma unroll
  for (int i = 0; i < 4; ++i)
#pragma unroll
    for (int j = 0; j < 4; ++j)
      P[((size_t)z * S_ + i0 + (ty << 2) + i) * S_ + t0 + (tx << 2) + j] = acc[i][j];
}

// ---------------- attention scores with rel-shift gather ----------------
__global__ __launch_bounds__(256) void attn_score_kernel(const float* __restrict__ q,
    const float* __restrict__ k, const float* __restrict__ ubias,
    const float* __restrict__ P, float* __restrict__ Sout, int bh0) {
  int z = blockIdx.z;
  int bh = bh0 + z, b = bh >> 3, h = bh & 7;
  int i0 = blockIdx.y << 6, j0 = blockIdx.x << 6;
  __shared__ float Qs[64][68];
  __shared__ float Ks[64][68];
  int tid = threadIdx.x;
  int am = tid >> 2, ak4 = (tid & 3) << 2;
  const float* qp = q + ((size_t)((b * S_ + i0 + am) * H_ + h) << 6);
  const float* kp = k + ((size_t)((b * S_ + j0 + am) * H_ + h) << 6);
  const float* ub = ubias + h * DH_;
#pragma unroll
  for (int e = 0; e < 4; ++e) {
    int d = ak4 + (e << 4);
    float4 qv = *(const float4*)(qp + d);
    float4 bv = *(const float4*)(ub + d);
    Qs[d + 0][am] = qv.x + bv.x;
    Qs[d + 1][am] = qv.y + bv.y;
    Qs[d + 2][am] = qv.z + bv.z;
    Qs[d + 3][am] = qv.w + bv.w;
    float4 kv = *(const float4*)(kp + d);
    Ks[d + 0][am] = kv.x;
    Ks[d + 1][am] = kv.y;
    Ks[d + 2][am] = kv.z;
    Ks[d + 3][am] = kv.w;
  }
  __syncthreads();
  int tx = tid & 15, ty = tid >> 4;
  float acc[4][4] = {};
#pragma unroll 8
  for (int d = 0; d < 64; ++d) {
    float a0 = Qs[d][(ty << 2) + 0], a1 = Qs[d][(ty << 2) + 1];
    float a2 = Qs[d][(ty << 2) + 2], a3 = Qs[d][(ty << 2) + 3];
    float w0 = Ks[d][(tx << 2) + 0], w1 = Ks[d][(tx << 2) + 1];
    float w2 = Ks[d][(tx << 2) + 2], w3 = Ks[d][(tx << 2) + 3];
    acc[0][0] += a0 * w0; acc[0][1] += a0 * w1; acc[0][2] += a0 * w2; acc[0][3] += a0 * w3;
    acc[1][0] += a1 * w0; acc[1][1] += a1 * w1; acc[1][2] += a1 * w2; acc[1][3] += a1 * w3;
    acc[2][0] += a2 * w0; acc[2][1] += a2 * w1; acc[2][2] += a2 * w2; acc[2][3] += a2 * w3;
    acc[3][0] += a3 * w0; acc[3][1] += a3 * w1; acc[3][2] += a3 * w2; acc[3][3] += a3 * w3;
  }
#pragma unroll
  for (int i = 0; i < 4; ++i) {
    int iG = i0 + (ty << 2) + i;
#pragma unroll
    for (int j = 0; j < 4; ++j) {
      int jG = j0 + (tx << 2) + j;
      float pv;
      if (jG <= iG)
        pv = P[((size_t)z * S_ + iG) * S_ + (S_ - 1 - iG + jG)];
      else if (jG == iG + 1)
        pv = 0.f;
      else
        pv = P[((size_t)z * S_ + iG + 1) * S_ + (jG - iG - 2)];
      Sout[((size_t)z * S_ + iG) * S_ + jG] = (acc[i][j] + pv) * INV_SQRT_D;
    }
  }
}

// ---------------- row softmax over 1024 cols, in place ----------------
__global__ __launch_bounds__(256) void softmax_kernel(float* __restrict__ Sb) {
  float* p = Sb + ((size_t)blockIdx.y * S_ + blockIdx.x) * S_;
  int t = threadIdx.x;
  float v[4];
  float mx = -1e30f;
#pragma unroll
  for (int e = 0; e < 4; ++e) {
    v[e] = p[t + (e << 8)];
    mx = fmaxf(mx, v[e]);
  }
#pragma unroll
  for (int off = 32; off > 0; off >>= 1) mx = fmaxf(mx, __shfl_xor(mx, off));
  __shared__ float red[8];
  int wid = t >> 6, lane = t & 63;
  if (lane == 0) red[wid] = mx;
  __syncthreads();
  mx = fmaxf(fmaxf(red[0], red[1]), fmaxf(red[2], red[3]));
  float sum = 0.f;
#pragma unroll
  for (int e = 0; e < 4; ++e) {
    v[e] = expf(v[e] - mx);
    sum += v[e];
  }
#pragma unroll
  for (int off = 32; off > 0; off >>= 1) sum += __shfl_xor(sum, off);
  if (lane == 0) red[4 + wid] = sum;
  __syncthreads();
  sum = red[4] + red[5] + red[6] + red[7];
  float inv = 1.f / sum;
#pragma unroll
  for (int e = 0; e < 4; ++e) p[t + (e << 8)] = v[e] * inv;
}

// ---------------- ctx[b,i,h,:] = sum_j A[z,i,j] * v[b,j,h,:]  (i-tile 16 x d 64) ----------------
__global__ __launch_bounds__(256) void attn_ctx_kernel(const float* __restrict__ A,
    const float* __restrict__ v, float* __restrict__ ctx, int bh0) {
  int z = blockIdx.y;
  int bh = bh0 + z, b = bh >> 3, h = bh & 7;
  int i0 = blockIdx.x << 4;
  __shared__ float Asm[16][36];
  __shared__ float Vs[32][68];
  int tid = threadIdx.x;
  int ty = tid >> 4;  // i 0..15
  int tx = tid & 15;  // d = tx*4..
  float acc[4] = {};
  for (int j0 = 0; j0 < S_; j0 += 32) {
    {
      int flat = tid << 1, r = flat >> 5, c = flat & 31;
      float2 a2 = *(const float2*)(A + ((size_t)z * S_ + i0 + r) * S_ + j0 + c);
      Asm[r][c] = a2.x;
      Asm[r][c + 1] = a2.y;
    }
#pragma unroll
    for (int e = 0; e < 8; ++e) {
      int flat = tid + (e << 8), r = flat >> 6, c = flat & 63;
      Vs[r][c] = v[((size_t)((b * S_ + j0 + r) * H_ + h) << 6) + c];
    }
    __syncthreads();
#pragma unroll
    for (int jj = 0; jj < 32; ++jj) {
      float a = Asm[ty][jj];
      acc[0] += a * Vs[jj][(tx << 2) + 0];
      acc[1] += a * Vs[jj][(tx << 2) + 1];
      acc[2] += a * Vs[jj][(tx << 2) + 2];
      acc[3] += a * Vs[jj][(tx << 2) + 3];
    }
    __syncthreads();
  }
  float4 o = {acc[0], acc[1], acc[2], acc[3]};
  *(float4*)(ctx + ((size_t)((b * S_ + i0 + ty) * H_ + h) << 6) + (tx << 2)) = o;
}

// ---------------- GLU: z[r,c] = h[r,c] * sigmoid(h[r,1024+c]) ----------------
__global__ __launch_bounds__(256) void glu_kernel(const float* __restrict__ hbuf,
                                                  float* __restrict__ z) {
  size_t idx = (size_t)blockIdx.x * 256 + threadIdx.x;
  size_t row = idx >> 10, c = idx & 1023;
  float a = hbuf[row * 2048 + c];
  float g = hbuf[row * 2048 + 1024 + c];
  z[idx] = a * sigmoidf_(g);
}

// ---------------- depthwise conv k=31 (+BN+swish), layout (b,s,c) ----------------
// One thread per (channel, s-tile of 32). Input window (62 vals) + 31 weights
// live in registers; 62 independent coalesced loads give deep MLP, then
// 32x31 unrolled FMAs from registers. (Round-1 version had VGPR_Count=16 and
// ran as a dependent-load chain: VALUBusy 3.4%, 870us.)
#define CTS 32
__global__ __launch_bounds__(256) void dwconv_kernel(const float* __restrict__ z,
    const float* __restrict__ w, const float* __restrict__ wb,
    const float* __restrict__ bng, const float* __restrict__ bnb,
    const float* __restrict__ bnm, const float* __restrict__ bnv,
    float* __restrict__ out) {
  int c = (blockIdx.z << 8) + threadIdx.x;  // channel 0..1023
  int b = blockIdx.y;
  int s0 = blockIdx.x * CTS;
  float wr[31];
#pragma unroll
  for (int kk = 0; kk < 31; ++kk) wr[kk] = w[c * 31 + kk];
  float zv[CTS + 30];
#pragma unroll
  for (int e = 0; e < CTS + 30; ++e) {
    int sr = s0 - 15 + e;
    zv[e] = (sr >= 0 && sr < S_) ? z[((size_t)(b * S_ + sr) << 10) + c] : 0.f;
  }
  float scale = bng[c] * rsqrtf(bnv[c] + 1e-5f);
  float shift = bnb[c] - bnm[c] * scale;
  float bias = wb[c];
#pragma unroll
  for (int s = 0; s < CTS; ++s) {
    float acc = 0.f;
#pragma unroll
    for (int kk = 0; kk < 31; ++kk) acc += zv[s + kk] * wr[kk];
    float v = (acc + bias) * scale + shift;
    v = v * sigmoidf_(v);
    out[((size_t)(b * S_ + s0 + s) << 10) + c] = v;
  }
}

extern "C" void kernel_launch(void* const* d_in, const int* in_sizes, int n_in,
                              void* d_out, int out_size, void* d_ws, size_t ws_size,
                              hipStream_t stream) {
  const float* x_in = (const float*)d_in[0];
  const float* ff1_ln_g = (const float*)d_in[1];
  const float* ff1_ln_b = (const float*)d_in[2];
  const float* ff1_w1 = (const float*)d_in[3];
  const float* ff1_b1 = (const float*)d_in[4];
  const float* ff1_w2 = (const float*)d_in[5];
  const float* ff1_b2 = (const float*)d_in[6];
  const float* attn_ln_g = (const float*)d_in[7];
  const float* attn_ln_b = (const float*)d_in[8];
  const float* wq = (const float*)d_in[9];
  const float* bq = (const float*)d_in[10];
  const float* wk = (const float*)d_in[11];
  const float* bk = (const float*)d_in[12];
  const float* wv = (const float*)d_in[13];
  const float* bv = (const float*)d_in[14];
  const float* wpos = (const float*)d_in[15];
  const float* u_bias = (const float*)d_in[16];
  const float* v_bias = (const float*)d_in[17];
  const float* wo = (const float*)d_in[18];
  const float* bo = (const float*)d_in[19];
  const float* conv_ln_g = (const float*)d_in[20];
  const float* conv_ln_b = (const float*)d_in[21];
  const float* pw1_w = (const float*)d_in[22];
  const float* pw1_b = (const float*)d_in[23];
  const float* dw_w = (const float*)d_in[24];
  const float* dw_b = (const float*)d_in[25];
  const float* bn_g = (const float*)d_in[26];
  const float* bn_b = (const float*)d_in[27];
  const float* bn_mean = (const float*)d_in[28];
  const float* bn_var = (const float*)d_in[29];
  const float* pw2_w = (const float*)d_in[30];
  const float* pw2_b = (const float*)d_in[31];
  const float* ff2_ln_g = (const float*)d_in[32];
  const float* ff2_ln_b = (const float*)d_in[33];
  const float* ff2_w1 = (const float*)d_in[34];
  const float* ff2_b1 = (const float*)d_in[35];
  const float* ff2_w2 = (const float*)d_in[36];
  const float* ff2_b2 = (const float*)d_in[37];
  const float* norm_g = (const float*)d_in[38];
  const float* norm_b = (const float*)d_in[39];

  float* ws = (float*)d_ws;
  const size_t M1 = 1u << 22;  // 4M floats
  float* xb = ws;               // 4M  running residual
  float* yb = ws + M1;          // 4M  LN output
  float* hb = ws + 2 * M1;      // 16M hidden / P+S chunks / conv
  float* qb = ws + 6 * M1;      // 4M
  float* kb = ws + 7 * M1;      // 4M
  float* vb = ws + 8 * M1;      // 4M
  float* ctxb = ws + 9 * M1;    // 4M
  float* posb = ws + 10 * M1;   // 0.5M
  float* peb = hb;              // PE lives in hb (free at that point)
  float* zb = qb;               // GLU output (8M floats over q+k region, free post-attn)
  float* Pb = hb;               // 8M floats
  float* Sb = hb + 8 * M1 / 4;  // 8M floats  (hb + 8388608)

  dim3 blk(256);

  // ---- FF1 half-residual ----
  ln_kernel<<<NROWS, blk, 0, stream>>>(x_in, ff1_ln_g, ff1_ln_b, yb);
  gemm_kernel<1><<<dim3(FF_ / 64, NROWS / 64), blk, 0, stream>>>(yb, ff1_w1, ff1_b1, nullptr, hb, NROWS, FF_, D_);
  gemm_kernel<2><<<dim3(D_ / 64, NROWS / 64), blk, 0, stream>>>(hb, ff1_w2, ff1_b2, x_in, xb, NROWS, D_, FF_);

  // ---- attention ----
  ln_kernel<<<NROWS, blk, 0, stream>>>(xb, attn_ln_g, attn_ln_b, yb);
  gemm_kernel<0><<<dim3(D_ / 64, NROWS / 64), blk, 0, stream>>>(yb, wq, bq, nullptr, qb, NROWS, D_, D_);
  gemm_kernel<0><<<dim3(D_ / 64, NROWS / 64), blk, 0, stream>>>(yb, wk, bk, nullptr, kb, NROWS, D_, D_);
  gemm_kernel<0><<<dim3(D_ / 64, NROWS / 64), blk, 0, stream>>>(yb, wv, bv, nullptr, vb, NROWS, D_, D_);
  pe_kernel<<<S_, blk, 0, stream>>>(peb);
  gemm_kernel<0><<<dim3(D_ / 64, S_ / 64), blk, 0, stream>>>(peb, wpos, nullptr, nullptr, posb, S_, D_, D_);

  for (int c = 0; c < 8; ++c) {
    int bh0 = c * 8;
    attn_pos_kernel<<<dim3(16, 16, 8), blk, 0, stream>>>(qb, posb, v_bias, Pb, bh0);
    attn_score_kernel<<<dim3(16, 16, 8), blk, 0, stream>>>(qb, kb, u_bias, Pb, Sb, bh0);
    softmax_kernel<<<dim3(S_, 8), blk, 0, stream>>>(Sb);
    attn_ctx_kernel<<<dim3(S_ / 16, 8), blk, 0, stream>>>(Sb, vb, ctxb, bh0);
  }
  gemm_kernel<3><<<dim3(D_ / 64, NROWS / 64), blk, 0, stream>>>(ctxb, wo, bo, xb, xb, NROWS, D_, D_);

  // ---- conv module ----
  ln_kernel<<<NROWS, blk, 0, stream>>>(xb, conv_ln_g, conv_ln_b, yb);
  gemm_kernel<0><<<dim3(2 * INNER_ / 64, NROWS / 64), blk, 0, stream>>>(yb, pw1_w, pw1_b, nullptr, hb, NROWS, 2 * INNER_, D_);
  glu_kernel<<<NROWS * INNER_ / 256, blk, 0, stream>>>(hb, zb);
  dwconv_kernel<<<dim3(S_ / CTS, B_, 4), blk, 0, stream>>>(zb, dw_w, dw_b, bn_g, bn_b, bn_mean, bn_var, hb);
  gemm_kernel<3><<<dim3(D_ / 64, NROWS / 64), blk, 0, stream>>>(hb, pw2_w, pw2_b, xb, xb, NROWS, D_, INNER_);

  // ---- FF2 half-residual ----
  ln_kernel<<<NROWS, blk, 0, stream>>>(xb, ff2_ln_g, ff2_ln_b, yb);
  gemm_kernel<1><<<dim3(FF_ / 64, NROWS / 64), blk, 0, stream>>>(yb, ff2_w1, ff2_b1, nullptr, hb, NROWS, FF_, D_);
  gemm_kernel<2><<<dim3(D_ / 64, NROWS / 64), blk, 0, stream>>>(hb, ff2_w2, ff2_b2, xb, xb, NROWS, D_, FF_);

  // ---- final LN ----
  ln_kernel<<<NROWS, blk, 0, stream>>>(xb, norm_g, norm_b, (float*)d_out);
}

// Round 3
// 1176.049 us; speedup vs baseline: 2.7457x; 2.0355x over previous
//
#include <hip/hip_runtime.h>
#include <cstdint>
#include <cstddef>

#define B_ 8
#define S_ 1024
#define D_ 512
#define H_ 8
#define DH_ 64
#define FF_ 2048
#define INNER_ 1024
#define NROWS 8192
#define INV_SQRT_D 0.04419417382415922f  // 1/sqrt(512)

typedef __attribute__((ext_vector_type(8))) short bf16x8;
typedef __attribute__((ext_vector_type(4))) float f32x4;

__device__ __forceinline__ float sigmoidf_(float x) { return 1.f / (1.f + expf(-x)); }

__device__ __forceinline__ short f2bf(float f) {  // RNE float->bf16
  uint32_t u = __float_as_uint(f);
  u += 0x7fff + ((u >> 16) & 1);
  return (short)(u >> 16);
}

__device__ __forceinline__ void store_out(float* C, size_t i, float v) { C[i] = v; }
__device__ __forceinline__ void store_out(short* C, size_t i, float v) { C[i] = f2bf(v); }

__device__ __forceinline__ void gload_lds16(const void* g, void* lds) {
  __builtin_amdgcn_global_load_lds(
      (const __attribute__((address_space(1))) uint32_t*)g,
      (__attribute__((address_space(3))) uint32_t*)lds, 16, 0, 0);
}

// ---------------- LayerNorm over D=512, one block (256 thr) per row ----------------
template <typename OutT>
__global__ __launch_bounds__(256) void ln_kernel(const float* __restrict__ in,
    const float* __restrict__ g, const float* __restrict__ b,
    OutT* __restrict__ out) {
  int row = blockIdx.x;
  const float* x = in + (size_t)row * D_;
  OutT* o = out + (size_t)row * D_;
  int t = threadIdx.x;
  float v0 = x[t], v1 = x[t + 256];
  float s = v0 + v1, q = v0 * v0 + v1 * v1;
#pragma unroll
  for (int off = 32; off > 0; off >>= 1) {
    s += __shfl_down(s, off);
    q += __shfl_down(q, off);
  }
  __shared__ float red[8];
  int wid = t >> 6, lane = t & 63;
  if (lane == 0) { red[wid] = s; red[wid + 4] = q; }
  __syncthreads();
  if (t == 0) {
    float S = red[0] + red[1] + red[2] + red[3];
    float Q = red[4] + red[5] + red[6] + red[7];
    float mean = S * (1.f / D_);
    float var = Q * (1.f / D_) - mean * mean;
    red[0] = mean;
    red[1] = rsqrtf(var + 1e-5f);
  }
  __syncthreads();
  float mean = red[0], inv = red[1];
  store_out(o, t, (v0 - mean) * inv * g[t] + b[t]);
  store_out(o, t + 256, (v1 - mean) * inv * g[t + 256] + b[t + 256]);
}

// ---------------- weight transpose + bf16 convert: in[K,N] fp32 -> out[N,K] bf16 ----------------
__global__ __launch_bounds__(256) void transpose_bf16_kernel(const float* __restrict__ in,
    short* __restrict__ out, int K, int N) {
  __shared__ float t[32][33];
  int n0 = blockIdx.x << 5, k0 = blockIdx.y << 5;
  int tx = threadIdx.x & 31, ty = threadIdx.x >> 5;  // 32 x 8
#pragma unroll
  for (int e = 0; e < 4; ++e)
    t[ty + e * 8][tx] = in[(size_t)(k0 + ty + e * 8) * N + n0 + tx];
  __syncthreads();
#pragma unroll
  for (int e = 0; e < 4; ++e)
    out[(size_t)(n0 + ty + e * 8) * K + k0 + tx] = f2bf(t[tx][ty + e * 8]);
}

// ---------------- MFMA bf16 GEMM: C[M,N] = epi(A[M,K] @ Bt[N,K]^T + bias) ----------------
// m97 structure: 128x128 tile, BK=32, 4 waves (2x2), 16x16x32 MFMA, fp32 accum.
// LDS swizzle: chunk ^= (row>>1)&3 applied BOTH at stage (global source) and ds_read.
// EPI: 0 = bias(optional), 1 = bias+swish, 2 = 0.5*v+res, 3 = v+res
template <int EPI, typename OutT>
__global__ __launch_bounds__(256) void mfma_gemm(const short* __restrict__ A,
    const short* __restrict__ Bt, const float* __restrict__ bias,
    const float* __restrict__ res, OutT* __restrict__ C, int M, int N, int K) {
  __shared__ short As[128 * 32];
  __shared__ short Bs[128 * 32];
  int tid = threadIdx.x;
  int w = tid >> 6, l = tid & 63;
  int bm = blockIdx.y << 7, bn = blockIdx.x << 7;
  int wr = w >> 1, wc = w & 1;
  f32x4 acc[4][4] = {};

  // staging: wave w covers rows [w*32, w*32+32) in two 16-row calls
  int sr = l >> 2, sc = l & 3;
  int r0 = (w * 2 + 0) * 16 + sr;
  int r1 = (w * 2 + 1) * 16 + sr;
  int g0 = sc ^ ((r0 >> 1) & 3);
  int g1 = sc ^ ((r1 >> 1) & 3);
  const short* a0 = A + (size_t)(bm + r0) * K + g0 * 8;
  const short* a1 = A + (size_t)(bm + r1) * K + g1 * 8;
  const short* b0 = Bt + (size_t)(bn + r0) * K + g0 * 8;
  const short* b1 = Bt + (size_t)(bn + r1) * K + g1 * 8;
  short* asd0 = As + (w * 2 + 0) * 512;  // wave-uniform LDS dest (+lane*16B by HW)
  short* asd1 = As + (w * 2 + 1) * 512;
  short* bsd0 = Bs + (w * 2 + 0) * 512;
  short* bsd1 = Bs + (w * 2 + 1) * 512;

  // fragment ds_read offsets (shorts): row r, k-chunk (l>>4) swizzled
  int lcol = l & 15, lk = l >> 4;
  int aoff[4], boff[4];
#pragma unroll
  for (int m = 0; m < 4; ++m) {
    int r = wr * 64 + m * 16 + lcol;
    aoff[m] = r * 32 + ((lk ^ ((r >> 1) & 3)) << 3);
  }
#pragma unroll
  for (int n = 0; n < 4; ++n) {
    int r = wc * 64 + n * 16 + lcol;
    boff[n] = r * 32 + ((lk ^ ((r >> 1) & 3)) << 3);
  }

  for (int k0 = 0; k0 < K; k0 += 32) {
    gload_lds16(a0 + k0, asd0);
    gload_lds16(a1 + k0, asd1);
    gload_lds16(b0 + k0, bsd0);
    gload_lds16(b1 + k0, bsd1);
    __syncthreads();  // drains vmcnt (DMA) before reads
    bf16x8 af[4], bfr[4];
#pragma unroll
    for (int m = 0; m < 4; ++m) af[m] = *(const bf16x8*)(As + aoff[m]);
#pragma unroll
    for (int n = 0; n < 4; ++n) bfr[n] = *(const bf16x8*)(Bs + boff[n]);
#pragma unroll
    for (int m = 0; m < 4; ++m)
#pragma unroll
      for (int n = 0; n < 4; ++n)
        acc[m][n] = __builtin_amdgcn_mfma_f32_16x16x32_bf16(af[m], bfr[n], acc[m][n], 0, 0, 0);
    __syncthreads();  // all reads done before next stage overwrites
  }

  // epilogue: C/D layout col=lane&15, row=(lane>>4)*4+reg  [m89-verified]
  int lrow = (l >> 4) << 2;
#pragma unroll
  for (int n = 0; n < 4; ++n) {
    int col = bn + wc * 64 + n * 16 + lcol;
    float bv = bias ? bias[col] : 0.f;
#pragma unroll
    for (int m = 0; m < 4; ++m) {
#pragma unroll
      for (int r = 0; r < 4; ++r) {
        int row = bm + wr * 64 + m * 16 + lrow + r;
        size_t idx = (size_t)row * N + col;
        float v = acc[m][n][r] + bv;
        if (EPI == 1) v = v * sigmoidf_(v);
        else if (EPI == 2) v = 0.5f * v + res[idx];
        else if (EPI == 3) v = v + res[idx];
        store_out(C, idx, v);
      }
    }
  }
}

// ---------------- sinusoidal positional encoding (S=1024, D=512), bf16 out ----------------
__global__ __launch_bounds__(256) void pe_kernel(short* __restrict__ pe) {
  int t = blockIdx.x, i = threadIdx.x;  // i in 0..255
  float freq = expf((float)(2 * i) * (-9.2103403719761836f / 512.f));  // ln(10000)
  float arg = (float)t * freq;
  pe[(size_t)t * D_ + 2 * i] = f2bf(sinf(arg));
  pe[(size_t)t * D_ + 2 * i + 1] = f2bf(cosf(arg));
}

// ---------------- attention: raw pos scores P[z,i,t] = (q+v_bias).pos  (64x64 tile) ----------------
__global__ __launch_bounds__(256) void attn_pos_kernel(const float* __restrict__ q,
    const float* __restrict__ pos, const float* __restrict__ vbias,
    float* __restrict__ P, int bh0) {
  int z = blockIdx.z;
  int bh = bh0 + z, b = bh >> 3, h = bh & 7;
  int i0 = blockIdx.y << 6, t0 = blockIdx.x << 6;
  __shared__ float Qs[64][68];  // [d][i]
  __shared__ float Ps[64][68];  // [d][t]
  int tid = threadIdx.x;
  int am = tid >> 2, ak4 = (tid & 3) << 2;
  const float* qp = q + ((size_t)((b * S_ + i0 + am) * H_ + h) << 6);
  const float* pp = pos + (size_t)(t0 + am) * D_ + h * DH_;
  const float* vb = vbias + h * DH_;
#pragma unroll
  for (int e = 0; e < 4; ++e) {
    int d = ak4 + (e << 4);
    float4 qv = *(const float4*)(qp + d);
    float4 bv = *(const float4*)(vb + d);
    Qs[d + 0][am] = qv.x + bv.x;
    Qs[d + 1][am] = qv.y + bv.y;
    Qs[d + 2][am] = qv.z + bv.z;
    Qs[d + 3][am] = qv.w + bv.w;
    float4 pv = *(const float4*)(pp + d);
    Ps[d + 0][am] = pv.x;
    Ps[d + 1][am] = pv.y;
    Ps[d + 2][am] = pv.z;
    Ps[d + 3][am] = pv.w;
  }
  __syncthreads();
  int tx = tid & 15, ty = tid >> 4;
  float acc[4][4] = {};
#pragma unroll 8
  for (int d = 0; d < 64; ++d) {
    float a0 = Qs[d][(ty << 2) + 0], a1 = Qs[d][(ty << 2) + 1];
    float a2 = Qs[d][(ty << 2) + 2], a3 = Qs[d][(ty << 2) + 3];
    float w0 = Ps[d][(tx << 2) + 0], w1 = Ps[d][(tx << 2) + 1];
    float w2 = Ps[d][(tx << 2) + 2], w3 = Ps[d][(tx << 2) + 3];
    acc[0][0] += a0 * w0; acc[0][1] += a0 * w1; acc[0][2] += a0 * w2; acc[0][3] += a0 * w3;
    acc[1][0] += a1 * w0; acc[1][1] += a1 * w1; acc[1][2] += a1 * w2; acc[1][3] += a1 * w3;
    acc[2][0] += a2 * w0; acc[2][1] += a2 * w1; acc[2][2] += a2 * w2; acc[2][3] += a2 * w3;
    acc[3][0] += a3 * w0; acc[3][1] += a3 * w1; acc[3][2] += a3 * w2; acc[3][3] += a3 * w3;
  }
#pragma unroll
  for (int i = 0; i < 4; ++i)
#pragma unroll
    for (int j = 0; j < 4; ++j)
      P[((size_t)z * S_ + i0 + (ty << 2) + i) * S_ + t0 + (tx << 2) + j] = acc[i][j];
}

// ---------------- attention scores with rel-shift gather ----------------
__global__ __launch_bounds__(256) void attn_score_kernel(const float* __restrict__ q,
    const float* __restrict__ k, const float* __restrict__ ubias,
    const float* __restrict__ P, float* __restrict__ Sout, int bh0) {
  int z = blockIdx.z;
  int bh = bh0 + z, b = bh >> 3, h = bh & 7;
  int i0 = blockIdx.y << 6, j0 = blockIdx.x << 6;
  __shared__ float Qs[64][68];
  __shared__ float Ks[64][68];
  int tid = threadIdx.x;
  int am = tid >> 2, ak4 = (tid & 3) << 2;
  const float* qp = q + ((size_t)((b * S_ + i0 + am) * H_ + h) << 6);
  const float* kp = k + ((size_t)((b * S_ + j0 + am) * H_ + h) << 6);
  const float* ub = ubias + h * DH_;
#pragma unroll
  for (int e = 0; e < 4; ++e) {
    int d = ak4 + (e << 4);
    float4 qv = *(const float4*)(qp + d);
    float4 bv = *(const float4*)(ub + d);
    Qs[d + 0][am] = qv.x + bv.x;
    Qs[d + 1][am] = qv.y + bv.y;
    Qs[d + 2][am] = qv.z + bv.z;
    Qs[d + 3][am] = qv.w + bv.w;
    float4 kv = *(const float4*)(kp + d);
    Ks[d + 0][am] = kv.x;
    Ks[d + 1][am] = kv.y;
    Ks[d + 2][am] = kv.z;
    Ks[d + 3][am] = kv.w;
  }
  __syncthreads();
  int tx = tid & 15, ty = tid >> 4;
  float acc[4][4] = {};
#pragma unroll 8
  for (int d = 0; d < 64; ++d) {
    float a0 = Qs[d][(ty << 2) + 0], a1 = Qs[d][(ty << 2) + 1];
    float a2 = Qs[d][(ty << 2) + 2], a3 = Qs[d][(ty << 2) + 3];
    float w0 = Ks[d][(tx << 2) + 0], w1 = Ks[d][(tx << 2) + 1];
    float w2 = Ks[d][(tx << 2) + 2], w3 = Ks[d][(tx << 2) + 3];
    acc[0][0] += a0 * w0; acc[0][1] += a0 * w1; acc[0][2] += a0 * w2; acc[0][3] += a0 * w3;
    acc[1][0] += a1 * w0; acc[1][1] += a1 * w1; acc[1][2] += a1 * w2; acc[1][3] += a1 * w3;
    acc[2][0] += a2 * w0; acc[2][1] += a2 * w1; acc[2][2] += a2 * w2; acc[2][3] += a2 * w3;
    acc[3][0] += a3 * w0; acc[3][1] += a3 * w1; acc[3][2] += a3 * w2; acc[3][3] += a3 * w3;
  }
#pragma unroll
  for (int i = 0; i < 4; ++i) {
    int iG = i0 + (ty << 2) + i;
#pragma unroll
    for (int j = 0; j < 4; ++j) {
      int jG = j0 + (tx << 2) + j;
      float pv;
      if (jG <= iG)
        pv = P[((size_t)z * S_ + iG) * S_ + (S_ - 1 - iG + jG)];
      else if (jG == iG + 1)
        pv = 0.f;
      else
        pv = P[((size_t)z * S_ + iG + 1) * S_ + (jG - iG - 2)];
      Sout[((size_t)z * S_ + iG) * S_ + jG] = (acc[i][j] + pv) * INV_SQRT_D;
    }
  }
}

// ---------------- row softmax over 1024 cols, in place ----------------
__global__ __launch_bounds__(256) void softmax_kernel(float* __restrict__ Sb) {
  float* p = Sb + ((size_t)blockIdx.y * S_ + blockIdx.x) * S_;
  int t = threadIdx.x;
  float v[4];
  float mx = -1e30f;
#pragma unroll
  for (int e = 0; e < 4; ++e) {
    v[e] = p[t + (e << 8)];
    mx = fmaxf(mx, v[e]);
  }
#pragma unroll
  for (int off = 32; off > 0; off >>= 1) mx = fmaxf(mx, __shfl_xor(mx, off));
  __shared__ float red[8];
  int wid = t >> 6, lane = t & 63;
  if (lane == 0) red[wid] = mx;
  __syncthreads();
  mx = fmaxf(fmaxf(red[0], red[1]), fmaxf(red[2], red[3]));
  float sum = 0.f;
#pragma unroll
  for (int e = 0; e < 4; ++e) {
    v[e] = expf(v[e] - mx);
    sum += v[e];
  }
#pragma unroll
  for (int off = 32; off > 0; off >>= 1) sum += __shfl_xor(sum, off);
  if (lane == 0) red[4 + wid] = sum;
  __syncthreads();
  sum = red[4] + red[5] + red[6] + red[7];
  float inv = 1.f / sum;
#pragma unroll
  for (int e = 0; e < 4; ++e) p[t + (e << 8)] = v[e] * inv;
}

// ---------------- ctx[b,i,h,:] = sum_j A[z,i,j] * v[b,j,h,:]  -> bf16 out ----------------
struct alignas(8) short4x { short x, y, z, w; };
__global__ __launch_bounds__(256) void attn_ctx_kernel(const float* __restrict__ A,
    const float* __restrict__ v, short* __restrict__ ctx, int bh0) {
  int z = blockIdx.y;
  int bh = bh0 + z, b = bh >> 3, h = bh & 7;
  int i0 = blockIdx.x << 4;
  __shared__ float Asm[16][36];
  __shared__ float Vs[32][68];
  int tid = threadIdx.x;
  int ty = tid >> 4;  // i 0..15
  int tx = tid & 15;  // d = tx*4..
  float acc[4] = {};
  for (int j0 = 0; j0 < S_; j0 += 32) {
    {
      int flat = tid << 1, r = flat >> 5, c = flat & 31;
      float2 a2 = *(const float2*)(A + ((size_t)z * S_ + i0 + r) * S_ + j0 + c);
      Asm[r][c] = a2.x;
      Asm[r][c + 1] = a2.y;
    }
#pragma unroll
    for (int e = 0; e < 8; ++e) {
      int flat = tid + (e << 8), r = flat >> 6, c = flat & 63;
      Vs[r][c] = v[((size_t)((b * S_ + j0 + r) * H_ + h) << 6) + c];
    }
    __syncthreads();
#pragma unroll
    for (int jj = 0; jj < 32; ++jj) {
      float a = Asm[ty][jj];
      acc[0] += a * Vs[jj][(tx << 2) + 0];
      acc[1] += a * Vs[jj][(tx << 2) + 1];
      acc[2] += a * Vs[jj][(tx << 2) + 2];
      acc[3] += a * Vs[jj][(tx << 2) + 3];
    }
    __syncthreads();
  }
  short4x o = {f2bf(acc[0]), f2bf(acc[1]), f2bf(acc[2]), f2bf(acc[3])};
  *(short4x*)(ctx + ((size_t)((b * S_ + i0 + ty) * H_ + h) << 6) + (tx << 2)) = o;
}

// ---------------- GLU: z[r,c] = h[r,c] * sigmoid(h[r,1024+c]) ----------------
__global__ __launch_bounds__(256) void glu_kernel(const float* __restrict__ hbuf,
                                                  float* __restrict__ z) {
  size_t idx = (size_t)blockIdx.x * 256 + threadIdx.x;
  size_t row = idx >> 10, c = idx & 1023;
  float a = hbuf[row * 2048 + c];
  float g = hbuf[row * 2048 + 1024 + c];
  z[idx] = a * sigmoidf_(g);
}

// ---------------- depthwise conv k=31 (+BN+swish), (b,s,c), bf16 out ----------------
#define CTS 32
__global__ __launch_bounds__(256) void dwconv_kernel(const float* __restrict__ z,
    const float* __restrict__ w, const float* __restrict__ wb,
    const float* __restrict__ bng, const float* __restrict__ bnb,
    const float* __restrict__ bnm, const float* __restrict__ bnv,
    short* __restrict__ out) {
  int c = (blockIdx.z << 8) + threadIdx.x;  // channel 0..1023
  int b = blockIdx.y;
  int s0 = blockIdx.x * CTS;
  float wr[31];
#pragma unroll
  for (int kk = 0; kk < 31; ++kk) wr[kk] = w[c * 31 + kk];
  float zv[CTS + 30];
#pragma unroll
  for (int e = 0; e < CTS + 30; ++e) {
    int sr = s0 - 15 + e;
    zv[e] = (sr >= 0 && sr < S_) ? z[((size_t)(b * S_ + sr) << 10) + c] : 0.f;
  }
  float scale = bng[c] * rsqrtf(bnv[c] + 1e-5f);
  float shift = bnb[c] - bnm[c] * scale;
  float bias = wb[c];
#pragma unroll
  for (int s = 0; s < CTS; ++s) {
    float acc = 0.f;
#pragma unroll
    for (int kk = 0; kk < 31; ++kk) acc += zv[s + kk] * wr[kk];
    float v = (acc + bias) * scale + shift;
    v = v * sigmoidf_(v);
    out[((size_t)(b * S_ + s0 + s) << 10) + c] = f2bf(v);
  }
}

extern "C" void kernel_launch(void* const* d_in, const int* in_sizes, int n_in,
                              void* d_out, int out_size, void* d_ws, size_t ws_size,
                              hipStream_t stream) {
  const float* x_in = (const float*)d_in[0];
  const float* ff1_ln_g = (const float*)d_in[1];
  const float* ff1_ln_b = (const float*)d_in[2];
  const float* ff1_w1 = (const float*)d_in[3];
  const float* ff1_b1 = (const float*)d_in[4];
  const float* ff1_w2 = (const float*)d_in[5];
  const float* ff1_b2 = (const float*)d_in[6];
  const float* attn_ln_g = (const float*)d_in[7];
  const float* attn_ln_b = (const float*)d_in[8];
  const float* wq = (const float*)d_in[9];
  const float* bq = (const float*)d_in[10];
  const float* wk = (const float*)d_in[11];
  const float* bk = (const float*)d_in[12];
  const float* wv = (const float*)d_in[13];
  const float* bv = (const float*)d_in[14];
  const float* wpos = (const float*)d_in[15];
  const float* u_bias = (const float*)d_in[16];
  const float* v_bias = (const float*)d_in[17];
  const float* wo = (const float*)d_in[18];
  const float* bo = (const float*)d_in[19];
  const float* conv_ln_g = (const float*)d_in[20];
  const float* conv_ln_b = (const float*)d_in[21];
  const float* pw1_w = (const float*)d_in[22];
  const float* pw1_b = (const float*)d_in[23];
  const float* dw_w = (const float*)d_in[24];
  const float* dw_b = (const float*)d_in[25];
  const float* bn_g = (const float*)d_in[26];
  const float* bn_b = (const float*)d_in[27];
  const float* bn_mean = (const float*)d_in[28];
  const float* bn_var = (const float*)d_in[29];
  const float* pw2_w = (const float*)d_in[30];
  const float* pw2_b = (const float*)d_in[31];
  const float* ff2_ln_g = (const float*)d_in[32];
  const float* ff2_ln_b = (const float*)d_in[33];
  const float* ff2_w1 = (const float*)d_in[34];
  const float* ff2_b1 = (const float*)d_in[35];
  const float* ff2_w2 = (const float*)d_in[36];
  const float* ff2_b2 = (const float*)d_in[37];
  const float* norm_g = (const float*)d_in[38];
  const float* norm_b = (const float*)d_in[39];

  char* wsb = (char*)d_ws;
  float* xb = (float*)(wsb);                       // 16 MB  residual
  float* hb = (float*)(wsb + (16ull << 20));       // 64 MB  pw1-out / P,S / FF-hidden(bf16)
  float* qb = (float*)(wsb + (80ull << 20));       // 16 MB
  float* kb = (float*)(wsb + (96ull << 20));       // 16 MB
  float* vb = (float*)(wsb + (112ull << 20));      // 16 MB
  float* posb = (float*)(wsb + (128ull << 20));    // 2 MB
  short* yb16 = (short*)(wsb + (130ull << 20));    // 8 MB   LN out bf16
  short* ctx16 = (short*)(wsb + (138ull << 20));   // 8 MB
  short* peb16 = (short*)(wsb + (146ull << 20));   // 1 MB
  short* wt = (short*)(wsb + (147ull << 20));      // 13.5 MB transposed weights
  short* hb16 = (short*)hb;
  float* Pb = hb;
  float* Sb = hb + (8ull << 20);                   // 8M floats in
  float* zb = qb;                                  // GLU out (qb+kb region, post-attn)
  short* cb16 = (short*)vb;                        // dwconv out bf16 (post-attn)

  short* ff1w1t = wt;
  short* ff1w2t = ff1w1t + 2048 * 512;
  short* wqt = ff1w2t + 512 * 2048;
  short* wkt = wqt + 512 * 512;
  short* wvt = wkt + 512 * 512;
  short* wot = wvt + 512 * 512;
  short* wpost = wot + 512 * 512;
  short* pw1t = wpost + 512 * 512;
  short* pw2t = pw1t + 2048 * 512;
  short* ff2w1t = pw2t + 512 * 1024;
  short* ff2w2t = ff2w1t + 2048 * 512;

  dim3 blk(256);

  // ---- weight transposes (fp32 [K,N] -> bf16 [N,K]) ----
  transpose_bf16_kernel<<<dim3(64, 16), blk, 0, stream>>>(ff1_w1, ff1w1t, 512, 2048);
  transpose_bf16_kernel<<<dim3(16, 64), blk, 0, stream>>>(ff1_w2, ff1w2t, 2048, 512);
  transpose_bf16_kernel<<<dim3(16, 16), blk, 0, stream>>>(wq, wqt, 512, 512);
  transpose_bf16_kernel<<<dim3(16, 16), blk, 0, stream>>>(wk, wkt, 512, 512);
  transpose_bf16_kernel<<<dim3(16, 16), blk, 0, stream>>>(wv, wvt, 512, 512);
  transpose_bf16_kernel<<<dim3(16, 16), blk, 0, stream>>>(wo, wot, 512, 512);
  transpose_bf16_kernel<<<dim3(16, 16), blk, 0, stream>>>(wpos, wpost, 512, 512);
  transpose_bf16_kernel<<<dim3(64, 16), blk, 0, stream>>>(pw1_w, pw1t, 512, 2048);
  transpose_bf16_kernel<<<dim3(16, 32), blk, 0, stream>>>(pw2_w, pw2t, 1024, 512);
  transpose_bf16_kernel<<<dim3(64, 16), blk, 0, stream>>>(ff2_w1, ff2w1t, 512, 2048);
  transpose_bf16_kernel<<<dim3(16, 64), blk, 0, stream>>>(ff2_w2, ff2w2t, 2048, 512);

  // ---- FF1 half-residual ----
  ln_kernel<short><<<NROWS, blk, 0, stream>>>(x_in, ff1_ln_g, ff1_ln_b, yb16);
  mfma_gemm<1, short><<<dim3(FF_ / 128, NROWS / 128), blk, 0, stream>>>(yb16, ff1w1t, ff1_b1, nullptr, hb16, NROWS, FF_, D_);
  mfma_gemm<2, float><<<dim3(D_ / 128, NROWS / 128), blk, 0, stream>>>(hb16, ff1w2t, ff1_b2, x_in, xb, NROWS, D_, FF_);

  // ---- attention ----
  ln_kernel<short><<<NROWS, blk, 0, stream>>>(xb, attn_ln_g, attn_ln_b, yb16);
  mfma_gemm<0, float><<<dim3(D_ / 128, NROWS / 128), blk, 0, stream>>>(yb16, wqt, bq, nullptr, qb, NROWS, D_, D_);
  mfma_gemm<0, float><<<dim3(D_ / 128, NROWS / 128), blk, 0, stream>>>(yb16, wkt, bk, nullptr, kb, NROWS, D_, D_);
  mfma_gemm<0, float><<<dim3(D_ / 128, NROWS / 128), blk, 0, stream>>>(yb16, wvt, bv, nullptr, vb, NROWS, D_, D_);
  pe_kernel<<<S_, blk, 0, stream>>>(peb16);
  mfma_gemm<0, float><<<dim3(D_ / 128, S_ / 128), blk, 0, stream>>>(peb16, wpost, nullptr, nullptr, posb, S_, D_, D_);

  for (int c = 0; c < 8; ++c) {
    int bh0 = c * 8;
    attn_pos_kernel<<<dim3(16, 16, 8), blk, 0, stream>>>(qb, posb, v_bias, Pb, bh0);
    attn_score_kernel<<<dim3(16, 16, 8), blk, 0, stream>>>(qb, kb, u_bias, Pb, Sb, bh0);
    softmax_kernel<<<dim3(S_, 8), blk, 0, stream>>>(Sb);
    attn_ctx_kernel<<<dim3(S_ / 16, 8), blk, 0, stream>>>(Sb, vb, ctx16, bh0);
  }
  mfma_gemm<3, float><<<dim3(D_ / 128, NROWS / 128), blk, 0, stream>>>(ctx16, wot, bo, xb, xb, NROWS, D_, D_);

  // ---- conv module ----
  ln_kernel<short><<<NROWS, blk, 0, stream>>>(xb, conv_ln_g, conv_ln_b, yb16);
  mfma_gemm<0, float><<<dim3(2 * INNER_ / 128, NROWS / 128), blk, 0, stream>>>(yb16, pw1t, pw1_b, nullptr, hb, NROWS, 2 * INNER_, D_);
  glu_kernel<<<NROWS * INNER_ / 256, blk, 0, stream>>>(hb, zb);
  dwconv_kernel<<<dim3(S_ / CTS, B_, 4), blk, 0, stream>>>(zb, dw_w, dw_b, bn_g, bn_b, bn_mean, bn_var, cb16);
  mfma_gemm<3, float><<<dim3(D_ / 128, NROWS / 128), blk, 0, stream>>>(cb16, pw2t, pw2_b, xb, xb, NROWS, D_, INNER_);

  // ---- FF2 half-residual ----
  ln_kernel<short><<<NROWS, blk, 0, stream>>>(xb, ff2_ln_g, ff2_ln_b, yb16);
  mfma_gemm<1, short><<<dim3(FF_ / 128, NROWS / 128), blk, 0, stream>>>(yb16, ff2w1t, ff2_b1, nullptr, hb16, NROWS, FF_, D_);
  mfma_gemm<2, float><<<dim3(D_ / 128, NROWS / 128), blk, 0, stream>>>(hb16, ff2w2t, ff2_b2, xb, xb, NROWS, D_, FF_);

  // ---- final LN ----
  ln_kernel<float><<<NROWS, blk, 0, stream>>>(xb, norm_g, norm_b, (float*)d_out);
}

// Round 4
// 955.437 us; speedup vs baseline: 3.3797x; 1.2309x over previous
//
#include <hip/hip_runtime.h>
#include <cstdint>
#include <cstddef>

#define B_ 8
#define S_ 1024
#define D_ 512
#define H_ 8
#define DH_ 64
#define FF_ 2048
#define INNER_ 1024
#define NROWS 8192
#define INV_SQRT_D 0.04419417382415922f  // 1/sqrt(512)

typedef __attribute__((ext_vector_type(8))) short bf16x8;
typedef __attribute__((ext_vector_type(4))) float f32x4;
struct alignas(8) short4x { short x, y, z, w; };

__device__ __forceinline__ float sigmoidf_(float x) { return 1.f / (1.f + expf(-x)); }

__device__ __forceinline__ short f2bf(float f) {  // RNE float->bf16
  uint32_t u = __float_as_uint(f);
  u += 0x7fff + ((u >> 16) & 1);
  return (short)(u >> 16);
}
__device__ __forceinline__ float bf2f(short s) {
  return __uint_as_float(((uint32_t)(uint16_t)s) << 16);
}

__device__ __forceinline__ void store_out(float* C, size_t i, float v) { C[i] = v; }
__device__ __forceinline__ void store_out(short* C, size_t i, float v) { C[i] = f2bf(v); }

__device__ __forceinline__ void gload_lds16(const void* g, void* lds) {
  __builtin_amdgcn_global_load_lds(
      (const __attribute__((address_space(1))) uint32_t*)g,
      (__attribute__((address_space(3))) uint32_t*)lds, 16, 0, 0);
}

// ---------------- LayerNorm over D=512, one block (256 thr) per row ----------------
template <typename OutT>
__global__ __launch_bounds__(256) void ln_kernel(const float* __restrict__ in,
    const float* __restrict__ g, const float* __restrict__ b,
    OutT* __restrict__ out) {
  int row = blockIdx.x;
  const float* x = in + (size_t)row * D_;
  OutT* o = out + (size_t)row * D_;
  int t = threadIdx.x;
  float v0 = x[t], v1 = x[t + 256];
  float s = v0 + v1, q = v0 * v0 + v1 * v1;
#pragma unroll
  for (int off = 32; off > 0; off >>= 1) {
    s += __shfl_down(s, off);
    q += __shfl_down(q, off);
  }
  __shared__ float red[8];
  int wid = t >> 6, lane = t & 63;
  if (lane == 0) { red[wid] = s; red[wid + 4] = q; }
  __syncthreads();
  if (t == 0) {
    float S = red[0] + red[1] + red[2] + red[3];
    float Q = red[4] + red[5] + red[6] + red[7];
    float mean = S * (1.f / D_);
    float var = Q * (1.f / D_) - mean * mean;
    red[0] = mean;
    red[1] = rsqrtf(var + 1e-5f);
  }
  __syncthreads();
  float mean = red[0], inv = red[1];
  store_out(o, t, (v0 - mean) * inv * g[t] + b[t]);
  store_out(o, t + 256, (v1 - mean) * inv * g[t + 256] + b[t + 256]);
}

// ---------------- weight transpose + bf16 convert: in[K,N] fp32 -> out[N,K] bf16 ----------------
__global__ __launch_bounds__(256) void transpose_bf16_kernel(const float* __restrict__ in,
    short* __restrict__ out, int K, int N) {
  __shared__ float t[32][33];
  int n0 = blockIdx.x << 5, k0 = blockIdx.y << 5;
  int tx = threadIdx.x & 31, ty = threadIdx.x >> 5;  // 32 x 8
#pragma unroll
  for (int e = 0; e < 4; ++e)
    t[ty + e * 8][tx] = in[(size_t)(k0 + ty + e * 8) * N + n0 + tx];
  __syncthreads();
#pragma unroll
  for (int e = 0; e < 4; ++e)
    out[(size_t)(n0 + ty + e * 8) * K + k0 + tx] = f2bf(t[tx][ty + e * 8]);
}

// ---------------- MFMA bf16 GEMM: C[M,N] = epi(A[M,K] @ Bt[N,K]^T + bias) ----------------
// 128x128 tile, BK=32, 4 waves (2x2), 16x16x32 MFMA, fp32 accum.
// LDS swizzle: chunk ^= (row>>1)&3 applied BOTH at stage (global source) and ds_read.
// EPI: 0=bias, 1=bias+swish, 2=0.5*v+res, 3=v+res,
//      4=q-path (write C=v+bias2, C2=v+bias3, both bf16), 5=v-transpose (vT[b,hd,s])
template <int EPI, typename OutT>
__global__ __launch_bounds__(256) void mfma_gemm(const short* __restrict__ A,
    const short* __restrict__ Bt, const float* __restrict__ bias,
    const float* __restrict__ res, OutT* __restrict__ C, short* __restrict__ C2,
    const float* __restrict__ bias2, const float* __restrict__ bias3,
    int M, int N, int K) {
  __shared__ short As[128 * 32];
  __shared__ short Bs[128 * 32];
  int tid = threadIdx.x;
  int w = tid >> 6, l = tid & 63;
  int bm = blockIdx.y << 7, bn = blockIdx.x << 7;
  int wr = w >> 1, wc = w & 1;
  f32x4 acc[4][4] = {};

  int sr = l >> 2, sc = l & 3;
  int r0 = (w * 2 + 0) * 16 + sr;
  int r1 = (w * 2 + 1) * 16 + sr;
  int g0 = sc ^ ((r0 >> 1) & 3);
  int g1 = sc ^ ((r1 >> 1) & 3);
  const short* a0 = A + (size_t)(bm + r0) * K + g0 * 8;
  const short* a1 = A + (size_t)(bm + r1) * K + g1 * 8;
  const short* b0 = Bt + (size_t)(bn + r0) * K + g0 * 8;
  const short* b1 = Bt + (size_t)(bn + r1) * K + g1 * 8;
  short* asd0 = As + (w * 2 + 0) * 512;
  short* asd1 = As + (w * 2 + 1) * 512;
  short* bsd0 = Bs + (w * 2 + 0) * 512;
  short* bsd1 = Bs + (w * 2 + 1) * 512;

  int lcol = l & 15, lk = l >> 4;
  int aoff[4], boff[4];
#pragma unroll
  for (int m = 0; m < 4; ++m) {
    int r = wr * 64 + m * 16 + lcol;
    aoff[m] = r * 32 + ((lk ^ ((r >> 1) & 3)) << 3);
  }
#pragma unroll
  for (int n = 0; n < 4; ++n) {
    int r = wc * 64 + n * 16 + lcol;
    boff[n] = r * 32 + ((lk ^ ((r >> 1) & 3)) << 3);
  }

  for (int k0 = 0; k0 < K; k0 += 32) {
    gload_lds16(a0 + k0, asd0);
    gload_lds16(a1 + k0, asd1);
    gload_lds16(b0 + k0, bsd0);
    gload_lds16(b1 + k0, bsd1);
    __syncthreads();
    bf16x8 af[4], bfr[4];
#pragma unroll
    for (int m = 0; m < 4; ++m) af[m] = *(const bf16x8*)(As + aoff[m]);
#pragma unroll
    for (int n = 0; n < 4; ++n) bfr[n] = *(const bf16x8*)(Bs + boff[n]);
#pragma unroll
    for (int m = 0; m < 4; ++m)
#pragma unroll
      for (int n = 0; n < 4; ++n)
        acc[m][n] = __builtin_amdgcn_mfma_f32_16x16x32_bf16(af[m], bfr[n], acc[m][n], 0, 0, 0);
    __syncthreads();
  }

  // epilogue: C/D layout col=lane&15, row=(lane>>4)*4+reg
  int lrow = (l >> 4) << 2;
#pragma unroll
  for (int m = 0; m < 4; ++m) {
    int row0 = bm + wr * 64 + m * 16 + lrow;
#pragma unroll
    for (int n = 0; n < 4; ++n) {
      int col = bn + wc * 64 + n * 16 + lcol;
      float bv = bias ? bias[col] : 0.f;
      if (EPI == 5) {
        short4x o;
        o.x = f2bf(acc[m][n][0] + bv);
        o.y = f2bf(acc[m][n][1] + bv);
        o.z = f2bf(acc[m][n][2] + bv);
        o.w = f2bf(acc[m][n][3] + bv);
        size_t tidx = ((size_t)(row0 >> 10) * 512 + col) * 1024 + (row0 & 1023);
        *(short4x*)((short*)C + tidx) = o;
      } else if (EPI == 4) {
#pragma unroll
        for (int r = 0; r < 4; ++r) {
          size_t idx = (size_t)(row0 + r) * N + col;
          float v = acc[m][n][r] + bv;
          ((short*)C)[idx] = f2bf(v + bias2[col]);
          C2[idx] = f2bf(v + bias3[col]);
        }
      } else {
#pragma unroll
        for (int r = 0; r < 4; ++r) {
          size_t idx = (size_t)(row0 + r) * N + col;
          float v = acc[m][n][r] + bv;
          if (EPI == 1) v = v * sigmoidf_(v);
          else if (EPI == 2) v = 0.5f * v + res[idx];
          else if (EPI == 3) v = v + res[idx];
          store_out(C, idx, v);
        }
      }
    }
  }
}

// ---------------- sinusoidal positional encoding (S=1024, D=512), bf16 out ----------------
__global__ __launch_bounds__(256) void pe_kernel(short* __restrict__ pe) {
  int t = blockIdx.x, i = threadIdx.x;  // i in 0..255
  float freq = expf((float)(2 * i) * (-9.2103403719761836f / 512.f));  // ln(10000)
  float arg = (float)t * freq;
  pe[(size_t)t * D_ + 2 * i] = f2bf(sinf(arg));
  pe[(size_t)t * D_ + 2 * i + 1] = f2bf(cosf(arg));
}

// ---------------- QK^T / Q.pos^T via MFMA: 128x128 tile, K=64 single stage ----------------
// POS=1: Out[z,i,t] = qv.pos (raw fp32).  POS=0: Out[z,i,j] = (qu.k + shift(P))*inv_sqrt_d.
template <int POS>
__global__ __launch_bounds__(256) void attn_qk_mfma(const short* __restrict__ Qb,
    const short* __restrict__ Kb, const float* __restrict__ P,
    float* __restrict__ Out, int bh0) {
  __shared__ short Qs[128 * 64];
  __shared__ short Ks[128 * 64];
  int tid = threadIdx.x;
  int w = tid >> 6, l = tid & 63;
  int z = blockIdx.z;
  int bh = bh0 + z, b = bh >> 3, h = bh & 7;
  int bi = blockIdx.y << 7, bj = blockIdx.x << 7;
  int srow = w * 8 + (l >> 3);  // 0..31 per chunk-call
  int sch = l & 7;
#pragma unroll
  for (int cc = 0; cc < 4; ++cc) {
    int r = cc * 32 + srow;
    int g = sch ^ (r & 7);
    const short* qsrc = Qb + (size_t)(b * S_ + bi + r) * D_ + h * DH_ + g * 8;
    const short* ksrc = POS ? Kb + (size_t)(bj + r) * D_ + h * DH_ + g * 8
                            : Kb + (size_t)(b * S_ + bj + r) * D_ + h * DH_ + g * 8;
    gload_lds16(qsrc, Qs + (cc * 32 + w * 8) * 64);
    gload_lds16(ksrc, Ks + (cc * 32 + w * 8) * 64);
  }
  __syncthreads();
  int wr = w >> 1, wc = w & 1;
  int lcol = l & 15, lk = l >> 4;
  bf16x8 qf[4][2], kf[4][2];
#pragma unroll
  for (int m = 0; m < 4; ++m)
#pragma unroll
    for (int ks = 0; ks < 2; ++ks) {
      int r = wr * 64 + m * 16 + lcol;
      int c = ks * 4 + lk;
      qf[m][ks] = *(const bf16x8*)(Qs + r * 64 + ((c ^ (r & 7)) << 3));
    }
#pragma unroll
  for (int n = 0; n < 4; ++n)
#pragma unroll
    for (int ks = 0; ks < 2; ++ks) {
      int r = wc * 64 + n * 16 + lcol;
      int c = ks * 4 + lk;
      kf[n][ks] = *(const bf16x8*)(Ks + r * 64 + ((c ^ (r & 7)) << 3));
    }
  f32x4 acc[4][4] = {};
#pragma unroll
  for (int ks = 0; ks < 2; ++ks)
#pragma unroll
    for (int m = 0; m < 4; ++m)
#pragma unroll
      for (int n = 0; n < 4; ++n)
        acc[m][n] = __builtin_amdgcn_mfma_f32_16x16x32_bf16(qf[m][ks], kf[n][ks], acc[m][n], 0, 0, 0);
  int lrow = (l >> 4) << 2;
#pragma unroll
  for (int m = 0; m < 4; ++m) {
#pragma unroll
    for (int r = 0; r < 4; ++r) {
      int iG = bi + wr * 64 + m * 16 + lrow + r;
#pragma unroll
      for (int n = 0; n < 4; ++n) {
        int jG = bj + wc * 64 + n * 16 + lcol;
        if (POS) {
          Out[((size_t)z * S_ + iG) * S_ + jG] = acc[m][n][r];
        } else {
          float pv;
          if (jG <= iG)
            pv = P[((size_t)z * S_ + iG) * S_ + (S_ - 1 - iG + jG)];
          else if (jG == iG + 1)
            pv = 0.f;
          else
            pv = P[((size_t)z * S_ + iG + 1) * S_ + (jG - iG - 2)];
          Out[((size_t)z * S_ + iG) * S_ + jG] = (acc[m][n][r] + pv) * INV_SQRT_D;
        }
      }
    }
  }
}

// ---------------- row softmax over 1024 cols, fp32 in -> bf16 out ----------------
__global__ __launch_bounds__(256) void softmax_kernel(const float* __restrict__ Sb,
                                                      short* __restrict__ attn) {
  size_t base = ((size_t)blockIdx.y * S_ + blockIdx.x) * S_;
  const float* p = Sb + base;
  int t = threadIdx.x;
  float4 v = *(const float4*)(p + (t << 2));
  float mx = fmaxf(fmaxf(v.x, v.y), fmaxf(v.z, v.w));
#pragma unroll
  for (int off = 32; off > 0; off >>= 1) mx = fmaxf(mx, __shfl_xor(mx, off));
  __shared__ float red[8];
  int wid = t >> 6, lane = t & 63;
  if (lane == 0) red[wid] = mx;
  __syncthreads();
  mx = fmaxf(fmaxf(red[0], red[1]), fmaxf(red[2], red[3]));
  v.x = expf(v.x - mx); v.y = expf(v.y - mx); v.z = expf(v.z - mx); v.w = expf(v.w - mx);
  float sum = v.x + v.y + v.z + v.w;
#pragma unroll
  for (int off = 32; off > 0; off >>= 1) sum += __shfl_xor(sum, off);
  if (lane == 0) red[4 + wid] = sum;
  __syncthreads();
  sum = red[4] + red[5] + red[6] + red[7];
  float inv = 1.f / sum;
  short4x o = {f2bf(v.x * inv), f2bf(v.y * inv), f2bf(v.z * inv), f2bf(v.w * inv)};
  *(short4x*)(attn + base + (t << 2)) = o;
}

// ---------------- ctx = attn @ v via MFMA: tile 128(i) x 64(d), K=1024 ----------------
// attn[z,i,j] bf16 row-major; vT[b, h*64+d, j] bf16; out ctx16[b,i,h,d] bf16.
__global__ __launch_bounds__(256) void attn_ctx_mfma(const short* __restrict__ attn,
    const short* __restrict__ vT, short* __restrict__ ctx, int bh0) {
  __shared__ short As[128 * 32];
  __shared__ short Bs[64 * 32];
  int tid = threadIdx.x;
  int w = tid >> 6, l = tid & 63;
  int z = blockIdx.y;
  int bh = bh0 + z, b = bh >> 3, h = bh & 7;
  int bm = blockIdx.x << 7;
  const short* Az = attn + (size_t)z * S_ * S_;
  const short* Bz = vT + (size_t)(b * 512 + h * 64) * 1024;
  int wr = w >> 1, wc = w & 1;
  f32x4 acc[4][2] = {};
  int sr = l >> 2, sc = l & 3;
  int ra0 = (w * 2 + 0) * 16 + sr;
  int ra1 = (w * 2 + 1) * 16 + sr;
  int ga0 = sc ^ ((ra0 >> 1) & 3);
  int ga1 = sc ^ ((ra1 >> 1) & 3);
  const short* a0 = Az + (size_t)(bm + ra0) * 1024 + ga0 * 8;
  const short* a1 = Az + (size_t)(bm + ra1) * 1024 + ga1 * 8;
  int rb = w * 16 + sr;
  int gb = sc ^ ((rb >> 1) & 3);
  const short* b0 = Bz + (size_t)rb * 1024 + gb * 8;
  short* asd0 = As + (w * 2 + 0) * 512;
  short* asd1 = As + (w * 2 + 1) * 512;
  short* bsd0 = Bs + w * 512;
  int lcol = l & 15, lk = l >> 4;
  int aoff[4], boff[2];
#pragma unroll
  for (int m = 0; m < 4; ++m) {
    int r = wr * 64 + m * 16 + lcol;
    aoff[m] = r * 32 + ((lk ^ ((r >> 1) & 3)) << 3);
  }
#pragma unroll
  for (int n = 0; n < 2; ++n) {
    int r = wc * 32 + n * 16 + lcol;
    boff[n] = r * 32 + ((lk ^ ((r >> 1) & 3)) << 3);
  }
  for (int k0 = 0; k0 < S_; k0 += 32) {
    gload_lds16(a0 + k0, asd0);
    gload_lds16(a1 + k0, asd1);
    gload_lds16(b0 + k0, bsd0);
    __syncthreads();
    bf16x8 af[4], bfr[2];
#pragma unroll
    for (int m = 0; m < 4; ++m) af[m] = *(const bf16x8*)(As + aoff[m]);
#pragma unroll
    for (int n = 0; n < 2; ++n) bfr[n] = *(const bf16x8*)(Bs + boff[n]);
#pragma unroll
    for (int m = 0; m < 4; ++m)
#pragma unroll
      for (int n = 0; n < 2; ++n)
        acc[m][n] = __builtin_amdgcn_mfma_f32_16x16x32_bf16(af[m], bfr[n], acc[m][n], 0, 0, 0);
    __syncthreads();
  }
  int lrow = (l >> 4) << 2;
  short* Cz = ctx + (size_t)b * S_ * D_ + h * DH_;
#pragma unroll
  for (int m = 0; m < 4; ++m) {
    int row0 = bm + wr * 64 + m * 16 + lrow;
#pragma unroll
    for (int n = 0; n < 2; ++n) {
      int col = wc * 32 + n * 16 + lcol;
#pragma unroll
      for (int r = 0; r < 4; ++r)
        Cz[(size_t)(row0 + r) * D_ + col] = f2bf(acc[m][n][r]);
    }
  }
}

// ---------------- GLU bf16: z[r,c] = a * sigmoid(g) ----------------
__global__ __launch_bounds__(256) void glu_kernel(const short* __restrict__ hbuf,
                                                  short* __restrict__ z) {
  size_t idx4 = ((size_t)blockIdx.x * 256 + threadIdx.x) << 2;
  size_t row = idx4 >> 10, c = idx4 & 1023;
  short4x a4 = *(const short4x*)(hbuf + row * 2048 + c);
  short4x g4 = *(const short4x*)(hbuf + row * 2048 + 1024 + c);
  short4x o;
  o.x = f2bf(bf2f(a4.x) * sigmoidf_(bf2f(g4.x)));
  o.y = f2bf(bf2f(a4.y) * sigmoidf_(bf2f(g4.y)));
  o.z = f2bf(bf2f(a4.z) * sigmoidf_(bf2f(g4.z)));
  o.w = f2bf(bf2f(a4.w) * sigmoidf_(bf2f(g4.w)));
  *(short4x*)(z + idx4) = o;
}

// ---------------- depthwise conv k=31 (+BN+swish), (b,s,c) bf16 in/out ----------------
#define CTS 32
__global__ __launch_bounds__(256) void dwconv_kernel(const short* __restrict__ z,
    const float* __restrict__ w, const float* __restrict__ wb,
    const float* __restrict__ bng, const float* __restrict__ bnb,
    const float* __restrict__ bnm, const float* __restrict__ bnv,
    short* __restrict__ out) {
  int c = (blockIdx.z << 8) + threadIdx.x;  // channel 0..1023
  int b = blockIdx.y;
  int s0 = blockIdx.x * CTS;
  float wr[31];
#pragma unroll
  for (int kk = 0; kk < 31; ++kk) wr[kk] = w[c * 31 + kk];
  float zv[CTS + 30];
#pragma unroll
  for (int e = 0; e < CTS + 30; ++e) {
    int sr = s0 - 15 + e;
    zv[e] = (sr >= 0 && sr < S_) ? bf2f(z[((size_t)(b * S_ + sr) << 10) + c]) : 0.f;
  }
  float scale = bng[c] * rsqrtf(bnv[c] + 1e-5f);
  float shift = bnb[c] - bnm[c] * scale;
  float bias = wb[c];
#pragma unroll
  for (int s = 0; s < CTS; ++s) {
    float acc = 0.f;
#pragma unroll
    for (int kk = 0; kk < 31; ++kk) acc += zv[s + kk] * wr[kk];
    float v = (acc + bias) * scale + shift;
    v = v * sigmoidf_(v);
    out[((size_t)(b * S_ + s0 + s) << 10) + c] = f2bf(v);
  }
}

extern "C" void kernel_launch(void* const* d_in, const int* in_sizes, int n_in,
                              void* d_out, int out_size, void* d_ws, size_t ws_size,
                              hipStream_t stream) {
  const float* x_in = (const float*)d_in[0];
  const float* ff1_ln_g = (const float*)d_in[1];
  const float* ff1_ln_b = (const float*)d_in[2];
  const float* ff1_w1 = (const float*)d_in[3];
  const float* ff1_b1 = (const float*)d_in[4];
  const float* ff1_w2 = (const float*)d_in[5];
  const float* ff1_b2 = (const float*)d_in[6];
  const float* attn_ln_g = (const float*)d_in[7];
  const float* attn_ln_b = (const float*)d_in[8];
  const float* wq = (const float*)d_in[9];
  const float* bq = (const float*)d_in[10];
  const float* wk = (const float*)d_in[11];
  const float* bk = (const float*)d_in[12];
  const float* wv = (const float*)d_in[13];
  const float* bv = (const float*)d_in[14];
  const float* wpos = (const float*)d_in[15];
  const float* u_bias = (const float*)d_in[16];
  const float* v_bias = (const float*)d_in[17];
  const float* wo = (const float*)d_in[18];
  const float* bo = (const float*)d_in[19];
  const float* conv_ln_g = (const float*)d_in[20];
  const float* conv_ln_b = (const float*)d_in[21];
  const float* pw1_w = (const float*)d_in[22];
  const float* pw1_b = (const float*)d_in[23];
  const float* dw_w = (const float*)d_in[24];
  const float* dw_b = (const float*)d_in[25];
  const float* bn_g = (const float*)d_in[26];
  const float* bn_b = (const float*)d_in[27];
  const float* bn_mean = (const float*)d_in[28];
  const float* bn_var = (const float*)d_in[29];
  const float* pw2_w = (const float*)d_in[30];
  const float* pw2_b = (const float*)d_in[31];
  const float* ff2_ln_g = (const float*)d_in[32];
  const float* ff2_ln_b = (const float*)d_in[33];
  const float* ff2_w1 = (const float*)d_in[34];
  const float* ff2_b1 = (const float*)d_in[35];
  const float* ff2_w2 = (const float*)d_in[36];
  const float* ff2_b2 = (const float*)d_in[37];
  const float* norm_g = (const float*)d_in[38];
  const float* norm_b = (const float*)d_in[39];

  char* wsb = (char*)d_ws;
  float* xb = (float*)(wsb);                       // 16 MiB fp32 residual
  short* yb16 = (short*)(wsb + (16ull << 20));     // 8 MiB  LN out
  float* Pb = (float*)(wsb + (24ull << 20));       // 32 MiB (chunk)
  float* Sb = (float*)(wsb + (56ull << 20));       // 32 MiB (chunk)
  short* attn16 = (short*)(wsb + (88ull << 20));   // 16 MiB (chunk)
  short* qu16 = (short*)(wsb + (104ull << 20));    // 8 MiB
  short* qv16 = (short*)(wsb + (112ull << 20));    // 8 MiB
  short* k16 = (short*)(wsb + (120ull << 20));     // 8 MiB
  short* vT16 = (short*)(wsb + (128ull << 20));    // 8 MiB
  short* ctx16 = (short*)(wsb + (136ull << 20));   // 8 MiB
  short* pos16 = (short*)(wsb + (144ull << 20));   // 1 MiB
  short* wt = (short*)(wsb + (145ull << 20));      // 13.5 MiB
  short* hb16 = (short*)Pb;                        // FF hidden / pw1-out (32 MiB, temporally disjoint)
  short* zb16 = (short*)Sb;                        // GLU out 16 MiB
  short* cb16 = (short*)(wsb + (72ull << 20));     // dwconv out 8 MiB
  short* peb16 = attn16;                           // PE scratch (free then)

  short* ff1w1t = wt;
  short* ff1w2t = ff1w1t + 2048 * 512;
  short* wqt = ff1w2t + 512 * 2048;
  short* wkt = wqt + 512 * 512;
  short* wvt = wkt + 512 * 512;
  short* wot = wvt + 512 * 512;
  short* wpost = wot + 512 * 512;
  short* pw1t = wpost + 512 * 512;
  short* pw2t = pw1t + 2048 * 512;
  short* ff2w1t = pw2t + 512 * 1024;
  short* ff2w2t = ff2w1t + 2048 * 512;

  dim3 blk(256);

  // ---- weight transposes (fp32 [K,N] -> bf16 [N,K]) ----
  transpose_bf16_kernel<<<dim3(64, 16), blk, 0, stream>>>(ff1_w1, ff1w1t, 512, 2048);
  transpose_bf16_kernel<<<dim3(16, 64), blk, 0, stream>>>(ff1_w2, ff1w2t, 2048, 512);
  transpose_bf16_kernel<<<dim3(16, 16), blk, 0, stream>>>(wq, wqt, 512, 512);
  transpose_bf16_kernel<<<dim3(16, 16), blk, 0, stream>>>(wk, wkt, 512, 512);
  transpose_bf16_kernel<<<dim3(16, 16), blk, 0, stream>>>(wv, wvt, 512, 512);
  transpose_bf16_kernel<<<dim3(16, 16), blk, 0, stream>>>(wo, wot, 512, 512);
  transpose_bf16_kernel<<<dim3(16, 16), blk, 0, stream>>>(wpos, wpost, 512, 512);
  transpose_bf16_kernel<<<dim3(64, 16), blk, 0, stream>>>(pw1_w, pw1t, 512, 2048);
  transpose_bf16_kernel<<<dim3(16, 32), blk, 0, stream>>>(pw2_w, pw2t, 1024, 512);
  transpose_bf16_kernel<<<dim3(64, 16), blk, 0, stream>>>(ff2_w1, ff2w1t, 512, 2048);
  transpose_bf16_kernel<<<dim3(16, 64), blk, 0, stream>>>(ff2_w2, ff2w2t, 2048, 512);

  // ---- FF1 half-residual ----
  ln_kernel<short><<<NROWS, blk, 0, stream>>>(x_in, ff1_ln_g, ff1_ln_b, yb16);
  mfma_gemm<1, short><<<dim3(FF_ / 128, NROWS / 128), blk, 0, stream>>>(yb16, ff1w1t, ff1_b1, nullptr, hb16, nullptr, nullptr, nullptr, NROWS, FF_, D_);
  mfma_gemm<2, float><<<dim3(D_ / 128, NROWS / 128), blk, 0, stream>>>(hb16, ff1w2t, ff1_b2, x_in, xb, nullptr, nullptr, nullptr, NROWS, D_, FF_);

  // ---- attention ----
  ln_kernel<short><<<NROWS, blk, 0, stream>>>(xb, attn_ln_g, attn_ln_b, yb16);
  mfma_gemm<4, short><<<dim3(D_ / 128, NROWS / 128), blk, 0, stream>>>(yb16, wqt, bq, nullptr, qu16, qv16, u_bias, v_bias, NROWS, D_, D_);
  mfma_gemm<0, short><<<dim3(D_ / 128, NROWS / 128), blk, 0, stream>>>(yb16, wkt, bk, nullptr, k16, nullptr, nullptr, nullptr, NROWS, D_, D_);
  mfma_gemm<5, short><<<dim3(D_ / 128, NROWS / 128), blk, 0, stream>>>(yb16, wvt, bv, nullptr, vT16, nullptr, nullptr, nullptr, NROWS, D_, D_);
  pe_kernel<<<S_, blk, 0, stream>>>(peb16);
  mfma_gemm<0, short><<<dim3(D_ / 128, S_ / 128), blk, 0, stream>>>(peb16, wpost, nullptr, nullptr, pos16, nullptr, nullptr, nullptr, S_, D_, D_);

  for (int c = 0; c < 8; ++c) {
    int bh0 = c * 8;
    attn_qk_mfma<1><<<dim3(8, 8, 8), blk, 0, stream>>>(qv16, pos16, nullptr, Pb, bh0);
    attn_qk_mfma<0><<<dim3(8, 8, 8), blk, 0, stream>>>(qu16, k16, Pb, Sb, bh0);
    softmax_kernel<<<dim3(S_, 8), blk, 0, stream>>>(Sb, attn16);
    attn_ctx_mfma<<<dim3(8, 8), blk, 0, stream>>>(attn16, vT16, ctx16, bh0);
  }
  mfma_gemm<3, float><<<dim3(D_ / 128, NROWS / 128), blk, 0, stream>>>(ctx16, wot, bo, xb, xb, nullptr, nullptr, nullptr, NROWS, D_, D_);

  // ---- conv module ----
  ln_kernel<short><<<NROWS, blk, 0, stream>>>(xb, conv_ln_g, conv_ln_b, yb16);
  mfma_gemm<0, short><<<dim3(2 * INNER_ / 128, NROWS / 128), blk, 0, stream>>>(yb16, pw1t, pw1_b, nullptr, hb16, nullptr, nullptr, nullptr, NROWS, 2 * INNER_, D_);
  glu_kernel<<<NROWS * INNER_ / 1024, blk, 0, stream>>>(hb16, zb16);
  dwconv_kernel<<<dim3(S_ / CTS, B_, 4), blk, 0, stream>>>(zb16, dw_w, dw_b, bn_g, bn_b, bn_mean, bn_var, cb16);
  mfma_gemm<3, float><<<dim3(D_ / 128, NROWS / 128), blk, 0, stream>>>(cb16, pw2t, pw2_b, xb, xb, nullptr, nullptr, nullptr, NROWS, D_, INNER_);

  // ---- FF2 half-residual ----
  ln_kernel<short><<<NROWS, blk, 0, stream>>>(xb, ff2_ln_g, ff2_ln_b, yb16);
  mfma_gemm<1, short><<<dim3(FF_ / 128, NROWS / 128), blk, 0, stream>>>(yb16, ff2w1t, ff2_b1, nullptr, hb16, nullptr, nullptr, nullptr, NROWS, FF_, D_);
  mfma_gemm<2, float><<<dim3(D_ / 128, NROWS / 128), blk, 0, stream>>>(hb16, ff2w2t, ff2_b2, xb, xb, nullptr, nullptr, nullptr, NROWS, D_, FF_);

  // ---- final LN ----
  ln_kernel<float><<<NROWS, blk, 0, stream>>>(xb, norm_g, norm_b, (float*)d_out);
}

// Round 5
// 717.572 us; speedup vs baseline: 4.5001x; 1.3315x over previous
//
#include <hip/hip_runtime.h>
#include <cstdint>
#include <cstddef>

#define B_ 8
#define S_ 1024
#define D_ 512
#define H_ 8
#define DH_ 64
#define FF_ 2048
#define INNER_ 1024
#define NROWS 8192
#define INV_SQRT_D 0.04419417382415922f  // 1/sqrt(512)

typedef __attribute__((ext_vector_type(8))) short bf16x8;
typedef __attribute__((ext_vector_type(4))) float f32x4;
struct alignas(8) short4x { short x, y, z, w; };

__device__ __forceinline__ float sigmoidf_(float x) { return 1.f / (1.f + expf(-x)); }

__device__ __forceinline__ short f2bf(float f) {  // RNE float->bf16
  uint32_t u = __float_as_uint(f);
  u += 0x7fff + ((u >> 16) & 1);
  return (short)(u >> 16);
}
__device__ __forceinline__ float bf2f(short s) {
  return __uint_as_float(((uint32_t)(uint16_t)s) << 16);
}

__device__ __forceinline__ void store_out(float* C, size_t i, float v) { C[i] = v; }
__device__ __forceinline__ void store_out(short* C, size_t i, float v) { C[i] = f2bf(v); }

__device__ __forceinline__ void gload_lds16(const void* g, void* lds) {
  __builtin_amdgcn_global_load_lds(
      (const __attribute__((address_space(1))) uint32_t*)g,
      (__attribute__((address_space(3))) uint32_t*)lds, 16, 0, 0);
}

// ---------------- LayerNorm over D=512, one block (256 thr) per row ----------------
template <typename OutT>
__global__ __launch_bounds__(256) void ln_kernel(const float* __restrict__ in,
    const float* __restrict__ g, const float* __restrict__ b,
    OutT* __restrict__ out) {
  int row = blockIdx.x;
  const float* x = in + (size_t)row * D_;
  OutT* o = out + (size_t)row * D_;
  int t = threadIdx.x;
  float v0 = x[t], v1 = x[t + 256];
  float s = v0 + v1, q = v0 * v0 + v1 * v1;
#pragma unroll
  for (int off = 32; off > 0; off >>= 1) {
    s += __shfl_down(s, off);
    q += __shfl_down(q, off);
  }
  __shared__ float red[8];
  int wid = t >> 6, lane = t & 63;
  if (lane == 0) { red[wid] = s; red[wid + 4] = q; }
  __syncthreads();
  if (t == 0) {
    float S = red[0] + red[1] + red[2] + red[3];
    float Q = red[4] + red[5] + red[6] + red[7];
    float mean = S * (1.f / D_);
    float var = Q * (1.f / D_) - mean * mean;
    red[0] = mean;
    red[1] = rsqrtf(var + 1e-5f);
  }
  __syncthreads();
  float mean = red[0], inv = red[1];
  store_out(o, t, (v0 - mean) * inv * g[t] + b[t]);
  store_out(o, t + 256, (v1 - mean) * inv * g[t + 256] + b[t + 256]);
}

// ---------------- weight transpose + bf16 convert: in[K,N] fp32 -> out[N,K] bf16 ----------------
__global__ __launch_bounds__(256) void transpose_bf16_kernel(const float* __restrict__ in,
    short* __restrict__ out, int K, int N) {
  __shared__ float t[32][33];
  int n0 = blockIdx.x << 5, k0 = blockIdx.y << 5;
  int tx = threadIdx.x & 31, ty = threadIdx.x >> 5;  // 32 x 8
#pragma unroll
  for (int e = 0; e < 4; ++e)
    t[ty + e * 8][tx] = in[(size_t)(k0 + ty + e * 8) * N + n0 + tx];
  __syncthreads();
#pragma unroll
  for (int e = 0; e < 4; ++e)
    out[(size_t)(n0 + ty + e * 8) * K + k0 + tx] = f2bf(t[tx][ty + e * 8]);
}

// ---------------- MFMA bf16 GEMM: C[M,N] = epi(A[M,K] @ Bt[N,K]^T + bias) ----------------
// 128x128 tile, BK=32, 4 waves (2x2), 16x16x32 MFMA, fp32 accum.
// EPI: 0=bias, 1=bias+swish, 2=0.5*v+res, 3=v+res,
//      4=q-path (C=v+bias2, C2=v+bias3, both bf16), 5=v-transpose (vT[b,hd,s])
template <int EPI, typename OutT>
__global__ __launch_bounds__(256) void mfma_gemm(const short* __restrict__ A,
    const short* __restrict__ Bt, const float* __restrict__ bias,
    const float* __restrict__ res, OutT* __restrict__ C, short* __restrict__ C2,
    const float* __restrict__ bias2, const float* __restrict__ bias3,
    int M, int N, int K) {
  __shared__ short As[128 * 32];
  __shared__ short Bs[128 * 32];
  int tid = threadIdx.x;
  int w = tid >> 6, l = tid & 63;
  int bm = blockIdx.y << 7, bn = blockIdx.x << 7;
  int wr = w >> 1, wc = w & 1;
  f32x4 acc[4][4] = {};

  int sr = l >> 2, sc = l & 3;
  int r0 = (w * 2 + 0) * 16 + sr;
  int r1 = (w * 2 + 1) * 16 + sr;
  int g0 = sc ^ ((r0 >> 1) & 3);
  int g1 = sc ^ ((r1 >> 1) & 3);
  const short* a0 = A + (size_t)(bm + r0) * K + g0 * 8;
  const short* a1 = A + (size_t)(bm + r1) * K + g1 * 8;
  const short* b0 = Bt + (size_t)(bn + r0) * K + g0 * 8;
  const short* b1 = Bt + (size_t)(bn + r1) * K + g1 * 8;
  short* asd0 = As + (w * 2 + 0) * 512;
  short* asd1 = As + (w * 2 + 1) * 512;
  short* bsd0 = Bs + (w * 2 + 0) * 512;
  short* bsd1 = Bs + (w * 2 + 1) * 512;

  int lcol = l & 15, lk = l >> 4;
  int aoff[4], boff[4];
#pragma unroll
  for (int m = 0; m < 4; ++m) {
    int r = wr * 64 + m * 16 + lcol;
    aoff[m] = r * 32 + ((lk ^ ((r >> 1) & 3)) << 3);
  }
#pragma unroll
  for (int n = 0; n < 4; ++n) {
    int r = wc * 64 + n * 16 + lcol;
    boff[n] = r * 32 + ((lk ^ ((r >> 1) & 3)) << 3);
  }

  for (int k0 = 0; k0 < K; k0 += 32) {
    gload_lds16(a0 + k0, asd0);
    gload_lds16(a1 + k0, asd1);
    gload_lds16(b0 + k0, bsd0);
    gload_lds16(b1 + k0, bsd1);
    __syncthreads();
    bf16x8 af[4], bfr[4];
#pragma unroll
    for (int m = 0; m < 4; ++m) af[m] = *(const bf16x8*)(As + aoff[m]);
#pragma unroll
    for (int n = 0; n < 4; ++n) bfr[n] = *(const bf16x8*)(Bs + boff[n]);
#pragma unroll
    for (int m = 0; m < 4; ++m)
#pragma unroll
      for (int n = 0; n < 4; ++n)
        acc[m][n] = __builtin_amdgcn_mfma_f32_16x16x32_bf16(af[m], bfr[n], acc[m][n], 0, 0, 0);
    __syncthreads();
  }

  // epilogue: C/D layout col=lane&15, row=(lane>>4)*4+reg
  int lrow = (l >> 4) << 2;
#pragma unroll
  for (int m = 0; m < 4; ++m) {
    int row0 = bm + wr * 64 + m * 16 + lrow;
#pragma unroll
    for (int n = 0; n < 4; ++n) {
      int col = bn + wc * 64 + n * 16 + lcol;
      float bv = bias ? bias[col] : 0.f;
      if (EPI == 5) {
        short4x o;
        o.x = f2bf(acc[m][n][0] + bv);
        o.y = f2bf(acc[m][n][1] + bv);
        o.z = f2bf(acc[m][n][2] + bv);
        o.w = f2bf(acc[m][n][3] + bv);
        size_t tidx = ((size_t)(row0 >> 10) * 512 + col) * 1024 + (row0 & 1023);
        *(short4x*)((short*)C + tidx) = o;
      } else if (EPI == 4) {
#pragma unroll
        for (int r = 0; r < 4; ++r) {
          size_t idx = (size_t)(row0 + r) * N + col;
          float v = acc[m][n][r] + bv;
          ((short*)C)[idx] = f2bf(v + bias2[col]);
          C2[idx] = f2bf(v + bias3[col]);
        }
      } else {
#pragma unroll
        for (int r = 0; r < 4; ++r) {
          size_t idx = (size_t)(row0 + r) * N + col;
          float v = acc[m][n][r] + bv;
          if (EPI == 1) v = v * sigmoidf_(v);
          else if (EPI == 2) v = 0.5f * v + res[idx];
          else if (EPI == 3) v = v + res[idx];
          store_out(C, idx, v);
        }
      }
    }
  }
}

// ---------------- sinusoidal positional encoding (S=1024, D=512), bf16 out ----------------
__global__ __launch_bounds__(256) void pe_kernel(short* __restrict__ pe) {
  int t = blockIdx.x, i = threadIdx.x;  // i in 0..255
  float freq = expf((float)(2 * i) * (-9.2103403719761836f / 512.f));  // ln(10000)
  float arg = (float)t * freq;
  pe[(size_t)t * D_ + 2 * i] = f2bf(sinf(arg));
  pe[(size_t)t * D_ + 2 * i + 1] = f2bf(cosf(arg));
}

// ---------------- raw pos scores P[z,i,t] = qv . pos  (bf16 out, 128x128 tile) ----------------
__global__ __launch_bounds__(256) void attn_pos_mfma(const short* __restrict__ Qb,
    const short* __restrict__ Pos, short* __restrict__ Out, int bh0) {
  __shared__ short Qs[128 * 64];
  __shared__ short Ks[128 * 64];
  int tid = threadIdx.x;
  int w = tid >> 6, l = tid & 63;
  int z = blockIdx.z;
  int bh = bh0 + z, b = bh >> 3, h = bh & 7;
  int bi = blockIdx.y << 7, bj = blockIdx.x << 7;
  int srow = w * 8 + (l >> 3);
  int sch = l & 7;
#pragma unroll
  for (int cc = 0; cc < 4; ++cc) {
    int r = cc * 32 + srow;
    int g = sch ^ (r & 7);
    gload_lds16(Qb + (size_t)(b * S_ + bi + r) * D_ + h * DH_ + g * 8, Qs + (cc * 32 + w * 8) * 64);
    gload_lds16(Pos + (size_t)(bj + r) * D_ + h * DH_ + g * 8, Ks + (cc * 32 + w * 8) * 64);
  }
  __syncthreads();
  int wr = w >> 1, wc = w & 1;
  int lcol = l & 15, lk = l >> 4;
  bf16x8 qf[4][2], kf[4][2];
#pragma unroll
  for (int m = 0; m < 4; ++m)
#pragma unroll
    for (int ks = 0; ks < 2; ++ks) {
      int r = wr * 64 + m * 16 + lcol;
      int c = ks * 4 + lk;
      qf[m][ks] = *(const bf16x8*)(Qs + r * 64 + ((c ^ (r & 7)) << 3));
    }
#pragma unroll
  for (int n = 0; n < 4; ++n)
#pragma unroll
    for (int ks = 0; ks < 2; ++ks) {
      int r = wc * 64 + n * 16 + lcol;
      int c = ks * 4 + lk;
      kf[n][ks] = *(const bf16x8*)(Ks + r * 64 + ((c ^ (r & 7)) << 3));
    }
  f32x4 acc[4][4] = {};
#pragma unroll
  for (int ks = 0; ks < 2; ++ks)
#pragma unroll
    for (int m = 0; m < 4; ++m)
#pragma unroll
      for (int n = 0; n < 4; ++n)
        acc[m][n] = __builtin_amdgcn_mfma_f32_16x16x32_bf16(qf[m][ks], kf[n][ks], acc[m][n], 0, 0, 0);
  int lrow = (l >> 4) << 2;
#pragma unroll
  for (int m = 0; m < 4; ++m)
#pragma unroll
    for (int r = 0; r < 4; ++r) {
      int iG = bi + wr * 64 + m * 16 + lrow + r;
#pragma unroll
      for (int n = 0; n < 4; ++n) {
        int jG = bj + wc * 64 + n * 16 + lcol;
        Out[((size_t)z * S_ + iG) * S_ + jG] = f2bf(acc[m][n][r]);
      }
    }
}

// ---------------- fused attention: S=qu.k^T + shift(P); online softmax; O=P.V ----------------
// Block: 4 waves, 64 Q-rows (wave w owns rows i0+w*16..+16). 16 j-steps of 64.
// K,V staged to XOR-swizzled LDS via global_load_lds; P relayout through wave-private LDS.
__global__ __launch_bounds__(256) void attn_fused(const short* __restrict__ qu,
    const short* __restrict__ kk, const short* __restrict__ vT,
    const short* __restrict__ P16, short* __restrict__ ctx, int bh0) {
  __shared__ short Ks[64 * 64];
  __shared__ short Vs[64 * 64];
  __shared__ short Ps[64 * 64];
  int tid = threadIdx.x;
  int w = tid >> 6, l = tid & 63;
  int z = blockIdx.y;
  int bh = bh0 + z, b = bh >> 3, h = bh & 7;
  int i0 = blockIdx.x << 6;
  const short* Pz = P16 + (size_t)z * S_ * S_;
  // Q A-fragments: row = i0 + w*16 + (l&15), k-slice d = ks*32 + (l>>4)*8
  bf16x8 qf[2];
  {
    const short* qrow = qu + (size_t)(b * S_ + i0 + w * 16 + (l & 15)) * D_ + h * DH_ + ((l >> 4) << 3);
    qf[0] = *(const bf16x8*)(qrow);
    qf[1] = *(const bf16x8*)(qrow + 32);
  }
  f32x4 po[4] = {};             // O acc: row=(l>>4)*4+r, col d = n*16+(l&15)
  float mrow[4], lrow[4];
  int gi[4];
#pragma unroll
  for (int r = 0; r < 4; ++r) {
    mrow[r] = -1e30f;
    lrow[r] = 0.f;
    gi[r] = i0 + w * 16 + ((l >> 4) << 2) + r;
  }

  for (int jt = 0; jt < 16; ++jt) {
    int j0 = jt << 6;
    // stage K (rows j, cols d) and V^T (rows d, cols j) tiles
    {
      int srow = (w << 3) + (l >> 3);  // 0..31
      int sch = l & 7;
#pragma unroll
      for (int cc = 0; cc < 2; ++cc) {
        int r = (cc << 5) + srow;
        int g = sch ^ (r & 7);
        gload_lds16(kk + (size_t)(b * S_ + j0 + r) * D_ + h * DH_ + (g << 3), Ks + ((cc << 5) + (w << 3)) * 64);
        gload_lds16(vT + (size_t)(b * 512 + h * DH_ + r) * 1024 + j0 + (g << 3), Vs + ((cc << 5) + (w << 3)) * 64);
      }
    }
    __syncthreads();
    // S tile = qu . K^T
    f32x4 sc[4] = {};
#pragma unroll
    for (int ks = 0; ks < 2; ++ks)
#pragma unroll
      for (int n = 0; n < 4; ++n) {
        int rj = (n << 4) + (l & 15);
        int ck = (ks << 2) + (l >> 4);
        bf16x8 kf = *(const bf16x8*)(Ks + rj * 64 + ((ck ^ (rj & 7)) << 3));
        sc[n] = __builtin_amdgcn_mfma_f32_16x16x32_bf16(qf[ks], kf, sc[n], 0, 0, 0);
      }
    // add rel-shifted pos score, scale, find tile max
    float pm[4];
#pragma unroll
    for (int r = 0; r < 4; ++r) pm[r] = -1e30f;
#pragma unroll
    for (int n = 0; n < 4; ++n)
#pragma unroll
      for (int r = 0; r < 4; ++r) {
        int i = gi[r];
        int j = j0 + (n << 4) + (l & 15);
        float pv;
        if (j <= i) pv = bf2f(Pz[(size_t)i * S_ + (S_ - 1) - i + j]);
        else if (j == i + 1) pv = 0.f;
        else pv = bf2f(Pz[(size_t)(i + 1) * S_ + j - i - 2]);
        float v = (sc[n][r] + pv) * INV_SQRT_D;
        sc[n][r] = v;
        pm[r] = fmaxf(pm[r], v);
      }
#pragma unroll
    for (int r = 0; r < 4; ++r)
#pragma unroll
      for (int off = 1; off < 16; off <<= 1) pm[r] = fmaxf(pm[r], __shfl_xor(pm[r], off));
    // online-softmax update
    float psum[4];
#pragma unroll
    for (int r = 0; r < 4; ++r) {
      float mn = fmaxf(mrow[r], pm[r]);
      float f = __expf(mrow[r] - mn);
      mrow[r] = mn;
      lrow[r] *= f;
#pragma unroll
      for (int n = 0; n < 4; ++n) po[n][r] *= f;
      psum[r] = 0.f;
    }
#pragma unroll
    for (int n = 0; n < 4; ++n)
#pragma unroll
      for (int r = 0; r < 4; ++r) {
        float p = __expf(sc[n][r] - mrow[r]);
        psum[r] += p;
        int rr = (w << 4) + ((l >> 4) << 2) + r;
        int c = (n << 4) + (l & 15);
        Ps[rr * 64 + ((((c >> 3)) ^ (rr & 7)) << 3) + (c & 7)] = f2bf(p);
      }
#pragma unroll
    for (int r = 0; r < 4; ++r) {
#pragma unroll
      for (int off = 1; off < 16; off <<= 1) psum[r] += __shfl_xor(psum[r], off);
      lrow[r] += psum[r];
    }
    __syncthreads();
    // O += P . V  (Ps strip is wave-private; Vs is block-shared)
    int rr2 = (w << 4) + (l & 15);
    bf16x8 pa[2];
#pragma unroll
    for (int ks = 0; ks < 2; ++ks) {
      int ck = (ks << 2) + (l >> 4);
      pa[ks] = *(const bf16x8*)(Ps + rr2 * 64 + ((ck ^ (rr2 & 7)) << 3));
    }
#pragma unroll
    for (int ks = 0; ks < 2; ++ks)
#pragma unroll
      for (int n = 0; n < 4; ++n) {
        int rd = (n << 4) + (l & 15);
        int ck = (ks << 2) + (l >> 4);
        bf16x8 vf = *(const bf16x8*)(Vs + rd * 64 + ((ck ^ (rd & 7)) << 3));
        po[n] = __builtin_amdgcn_mfma_f32_16x16x32_bf16(pa[ks], vf, po[n], 0, 0, 0);
      }
    __syncthreads();
  }
  short* Cz = ctx + (size_t)b * S_ * D_ + h * DH_;
#pragma unroll
  for (int r = 0; r < 4; ++r) {
    float inv = 1.f / lrow[r];
#pragma unroll
    for (int n = 0; n < 4; ++n)
      Cz[(size_t)gi[r] * D_ + (n << 4) + (l & 15)] = f2bf(po[n][r] * inv);
  }
}

// ---------------- GLU bf16: z[r,c] = a * sigmoid(g) ----------------
__global__ __launch_bounds__(256) void glu_kernel(const short* __restrict__ hbuf,
                                                  short* __restrict__ z) {
  size_t idx4 = ((size_t)blockIdx.x * 256 + threadIdx.x) << 2;
  size_t row = idx4 >> 10, c = idx4 & 1023;
  short4x a4 = *(const short4x*)(hbuf + row * 2048 + c);
  short4x g4 = *(const short4x*)(hbuf + row * 2048 + 1024 + c);
  short4x o;
  o.x = f2bf(bf2f(a4.x) * sigmoidf_(bf2f(g4.x)));
  o.y = f2bf(bf2f(a4.y) * sigmoidf_(bf2f(g4.y)));
  o.z = f2bf(bf2f(a4.z) * sigmoidf_(bf2f(g4.z)));
  o.w = f2bf(bf2f(a4.w) * sigmoidf_(bf2f(g4.w)));
  *(short4x*)(z + idx4) = o;
}

// ---------------- depthwise conv k=31 (+BN+swish), (b,s,c) bf16 in/out ----------------
#define CTS 32
__global__ __launch_bounds__(256) void dwconv_kernel(const short* __restrict__ z,
    const float* __restrict__ w, const float* __restrict__ wb,
    const float* __restrict__ bng, const float* __restrict__ bnb,
    const float* __restrict__ bnm, const float* __restrict__ bnv,
    short* __restrict__ out) {
  int c = (blockIdx.z << 8) + threadIdx.x;  // channel 0..1023
  int b = blockIdx.y;
  int s0 = blockIdx.x * CTS;
  float wr[31];
#pragma unroll
  for (int kk = 0; kk < 31; ++kk) wr[kk] = w[c * 31 + kk];
  float zv[CTS + 30];
#pragma unroll
  for (int e = 0; e < CTS + 30; ++e) {
    int sr = s0 - 15 + e;
    zv[e] = (sr >= 0 && sr < S_) ? bf2f(z[((size_t)(b * S_ + sr) << 10) + c]) : 0.f;
  }
  float scale = bng[c] * rsqrtf(bnv[c] + 1e-5f);
  float shift = bnb[c] - bnm[c] * scale;
  float bias = wb[c];
#pragma unroll
  for (int s = 0; s < CTS; ++s) {
    float acc = 0.f;
#pragma unroll
    for (int kk = 0; kk < 31; ++kk) acc += zv[s + kk] * wr[kk];
    float v = (acc + bias) * scale + shift;
    v = v * sigmoidf_(v);
    out[((size_t)(b * S_ + s0 + s) << 10) + c] = f2bf(v);
  }
}

extern "C" void kernel_launch(void* const* d_in, const int* in_sizes, int n_in,
                              void* d_out, int out_size, void* d_ws, size_t ws_size,
                              hipStream_t stream) {
  const float* x_in = (const float*)d_in[0];
  const float* ff1_ln_g = (const float*)d_in[1];
  const float* ff1_ln_b = (const float*)d_in[2];
  const float* ff1_w1 = (const float*)d_in[3];
  const float* ff1_b1 = (const float*)d_in[4];
  const float* ff1_w2 = (const float*)d_in[5];
  const float* ff1_b2 = (const float*)d_in[6];
  const float* attn_ln_g = (const float*)d_in[7];
  const float* attn_ln_b = (const float*)d_in[8];
  const float* wq = (const float*)d_in[9];
  const float* bq = (const float*)d_in[10];
  const float* wk = (const float*)d_in[11];
  const float* bk = (const float*)d_in[12];
  const float* wv = (const float*)d_in[13];
  const float* bv = (const float*)d_in[14];
  const float* wpos = (const float*)d_in[15];
  const float* u_bias = (const float*)d_in[16];
  const float* v_bias = (const float*)d_in[17];
  const float* wo = (const float*)d_in[18];
  const float* bo = (const float*)d_in[19];
  const float* conv_ln_g = (const float*)d_in[20];
  const float* conv_ln_b = (const float*)d_in[21];
  const float* pw1_w = (const float*)d_in[22];
  const float* pw1_b = (const float*)d_in[23];
  const float* dw_w = (const float*)d_in[24];
  const float* dw_b = (const float*)d_in[25];
  const float* bn_g = (const float*)d_in[26];
  const float* bn_b = (const float*)d_in[27];
  const float* bn_mean = (const float*)d_in[28];
  const float* bn_var = (const float*)d_in[29];
  const float* pw2_w = (const float*)d_in[30];
  const float* pw2_b = (const float*)d_in[31];
  const float* ff2_ln_g = (const float*)d_in[32];
  const float* ff2_ln_b = (const float*)d_in[33];
  const float* ff2_w1 = (const float*)d_in[34];
  const float* ff2_b1 = (const float*)d_in[35];
  const float* ff2_w2 = (const float*)d_in[36];
  const float* ff2_b2 = (const float*)d_in[37];
  const float* norm_g = (const float*)d_in[38];
  const float* norm_b = (const float*)d_in[39];

  char* wsb = (char*)d_ws;
  float* xb = (float*)(wsb);                      // 16 MiB fp32 residual
  short* yb16 = (short*)(wsb + (16ull << 20));    // 8 MiB  LN out
  short* qu16 = (short*)(wsb + (24ull << 20));    // 8 MiB
  short* qv16 = (short*)(wsb + (32ull << 20));    // 8 MiB
  short* k16 = (short*)(wsb + (40ull << 20));     // 8 MiB
  short* vT16 = (short*)(wsb + (48ull << 20));    // 8 MiB
  short* ctx16 = (short*)(wsb + (56ull << 20));   // 8 MiB
  short* pos16 = (short*)(wsb + (64ull << 20));   // 1 MiB
  short* wt = (short*)(wsb + (65ull << 20));      // 13.5 MiB
  short* Pb16 = (short*)(wsb + (80ull << 20));    // 64 MiB (32-bh chunk), attn phase only
  short* hb16 = (short*)(wsb + (80ull << 20));    // 32 MiB FF hidden / pw1-out (non-attn phases)
  short* zb16 = (short*)(wsb + (112ull << 20));   // 16 MiB GLU out
  short* cb16 = (short*)(wsb + (128ull << 20));   // 16 MiB dwconv out
  short* peb16 = ctx16;                           // PE scratch (free at that point)

  short* ff1w1t = wt;
  short* ff1w2t = ff1w1t + 2048 * 512;
  short* wqt = ff1w2t + 512 * 2048;
  short* wkt = wqt + 512 * 512;
  short* wvt = wkt + 512 * 512;
  short* wot = wvt + 512 * 512;
  short* wpost = wot + 512 * 512;
  short* pw1t = wpost + 512 * 512;
  short* pw2t = pw1t + 2048 * 512;
  short* ff2w1t = pw2t + 512 * 1024;
  short* ff2w2t = ff2w1t + 2048 * 512;

  dim3 blk(256);

  // ---- weight transposes (fp32 [K,N] -> bf16 [N,K]) ----
  transpose_bf16_kernel<<<dim3(64, 16), blk, 0, stream>>>(ff1_w1, ff1w1t, 512, 2048);
  transpose_bf16_kernel<<<dim3(16, 64), blk, 0, stream>>>(ff1_w2, ff1w2t, 2048, 512);
  transpose_bf16_kernel<<<dim3(16, 16), blk, 0, stream>>>(wq, wqt, 512, 512);
  transpose_bf16_kernel<<<dim3(16, 16), blk, 0, stream>>>(wk, wkt, 512, 512);
  transpose_bf16_kernel<<<dim3(16, 16), blk, 0, stream>>>(wv, wvt, 512, 512);
  transpose_bf16_kernel<<<dim3(16, 16), blk, 0, stream>>>(wo, wot, 512, 512);
  transpose_bf16_kernel<<<dim3(16, 16), blk, 0, stream>>>(wpos, wpost, 512, 512);
  transpose_bf16_kernel<<<dim3(64, 16), blk, 0, stream>>>(pw1_w, pw1t, 512, 2048);
  transpose_bf16_kernel<<<dim3(16, 32), blk, 0, stream>>>(pw2_w, pw2t, 1024, 512);
  transpose_bf16_kernel<<<dim3(64, 16), blk, 0, stream>>>(ff2_w1, ff2w1t, 512, 2048);
  transpose_bf16_kernel<<<dim3(16, 64), blk, 0, stream>>>(ff2_w2, ff2w2t, 2048, 512);

  // ---- FF1 half-residual ----
  ln_kernel<short><<<NROWS, blk, 0, stream>>>(x_in, ff1_ln_g, ff1_ln_b, yb16);
  mfma_gemm<1, short><<<dim3(FF_ / 128, NROWS / 128), blk, 0, stream>>>(yb16, ff1w1t, ff1_b1, nullptr, hb16, nullptr, nullptr, nullptr, NROWS, FF_, D_);
  mfma_gemm<2, float><<<dim3(D_ / 128, NROWS / 128), blk, 0, stream>>>(hb16, ff1w2t, ff1_b2, x_in, xb, nullptr, nullptr, nullptr, NROWS, D_, FF_);

  // ---- attention ----
  ln_kernel<short><<<NROWS, blk, 0, stream>>>(xb, attn_ln_g, attn_ln_b, yb16);
  mfma_gemm<4, short><<<dim3(D_ / 128, NROWS / 128), blk, 0, stream>>>(yb16, wqt, bq, nullptr, qu16, qv16, u_bias, v_bias, NROWS, D_, D_);
  mfma_gemm<0, short><<<dim3(D_ / 128, NROWS / 128), blk, 0, stream>>>(yb16, wkt, bk, nullptr, k16, nullptr, nullptr, nullptr, NROWS, D_, D_);
  mfma_gemm<5, short><<<dim3(D_ / 128, NROWS / 128), blk, 0, stream>>>(yb16, wvt, bv, nullptr, vT16, nullptr, nullptr, nullptr, NROWS, D_, D_);
  pe_kernel<<<S_, blk, 0, stream>>>(peb16);
  mfma_gemm<0, short><<<dim3(D_ / 128, S_ / 128), blk, 0, stream>>>(peb16, wpost, nullptr, nullptr, pos16, nullptr, nullptr, nullptr, S_, D_, D_);

  const int CH = 32;  // bh per chunk (P chunk = 64 MiB bf16)
  for (int c = 0; c < 64 / CH; ++c) {
    int bh0 = c * CH;
    attn_pos_mfma<<<dim3(8, 8, CH), blk, 0, stream>>>(qv16, pos16, Pb16, bh0);
    attn_fused<<<dim3(S_ / 64, CH), blk, 0, stream>>>(qu16, k16, vT16, Pb16, ctx16, bh0);
  }
  mfma_gemm<3, float><<<dim3(D_ / 128, NROWS / 128), blk, 0, stream>>>(ctx16, wot, bo, xb, xb, nullptr, nullptr, nullptr, NROWS, D_, D_);

  // ---- conv module ----
  ln_kernel<short><<<NROWS, blk, 0, stream>>>(xb, conv_ln_g, conv_ln_b, yb16);
  mfma_gemm<0, short><<<dim3(2 * INNER_ / 128, NROWS / 128), blk, 0, stream>>>(yb16, pw1t, pw1_b, nullptr, hb16, nullptr, nullptr, nullptr, NROWS, 2 * INNER_, D_);
  glu_kernel<<<NROWS * INNER_ / 1024, blk, 0, stream>>>(hb16, zb16);
  dwconv_kernel<<<dim3(S_ / CTS, B_, 4), blk, 0, stream>>>(zb16, dw_w, dw_b, bn_g, bn_b, bn_mean, bn_var, cb16);
  mfma_gemm<3, float><<<dim3(D_ / 128, NROWS / 128), blk, 0, stream>>>(cb16, pw2t, pw2_b, xb, xb, nullptr, nullptr, nullptr, NROWS, D_, INNER_);

  // ---- FF2 half-residual ----
  ln_kernel<short><<<NROWS, blk, 0, stream>>>(xb, ff2_ln_g, ff2_ln_b, yb16);
  mfma_gemm<1, short><<<dim3(FF_ / 128, NROWS / 128), blk, 0, stream>>>(yb16, ff2w1t, ff2_b1, nullptr, hb16, nullptr, nullptr, nullptr, NROWS, FF_, D_);
  mfma_gemm<2, float><<<dim3(D_ / 128, NROWS / 128), blk, 0, stream>>>(hb16, ff2w2t, ff2_b2, xb, xb, nullptr, nullptr, nullptr, NROWS, D_, FF_);

  // ---- final LN ----
  ln_kernel<float><<<NROWS, blk, 0, stream>>>(xb, norm_g, norm_b, (float*)d_out);
}

// Round 6
// 698.394 us; speedup vs baseline: 4.6236x; 1.0275x over previous
//
#include <hip/hip_runtime.h>
#include <cstdint>
#include <cstddef>

#define B_ 8
#define S_ 1024
#define D_ 512
#define H_ 8
#define DH_ 64
#define FF_ 2048
#define INNER_ 1024
#define NROWS 8192
#define INV_SQRT_D 0.04419417382415922f  // 1/sqrt(512)

typedef __attribute__((ext_vector_type(8))) short bf16x8;
typedef __attribute__((ext_vector_type(4))) float f32x4;
struct alignas(8) short4x { short x, y, z, w; };

__device__ __forceinline__ float sigmoidf_(float x) { return 1.f / (1.f + expf(-x)); }

__device__ __forceinline__ short f2bf(float f) {  // RNE float->bf16
  uint32_t u = __float_as_uint(f);
  u += 0x7fff + ((u >> 16) & 1);
  return (short)(u >> 16);
}
__device__ __forceinline__ float bf2f(short s) {
  return __uint_as_float(((uint32_t)(uint16_t)s) << 16);
}

__device__ __forceinline__ void store_out(float* C, size_t i, float v) { C[i] = v; }
__device__ __forceinline__ void store_out(short* C, size_t i, float v) { C[i] = f2bf(v); }

__device__ __forceinline__ void gload_lds16(const void* g, void* lds) {
  __builtin_amdgcn_global_load_lds(
      (const __attribute__((address_space(1))) uint32_t*)g,
      (__attribute__((address_space(3))) uint32_t*)lds, 16, 0, 0);
}

// ---------------- LayerNorm over D=512, one block (256 thr) per row ----------------
template <typename OutT>
__global__ __launch_bounds__(256) void ln_kernel(const float* __restrict__ in,
    const float* __restrict__ g, const float* __restrict__ b,
    OutT* __restrict__ out) {
  int row = blockIdx.x;
  const float* x = in + (size_t)row * D_;
  OutT* o = out + (size_t)row * D_;
  int t = threadIdx.x;
  float v0 = x[t], v1 = x[t + 256];
  float s = v0 + v1, q = v0 * v0 + v1 * v1;
#pragma unroll
  for (int off = 32; off > 0; off >>= 1) {
    s += __shfl_down(s, off);
    q += __shfl_down(q, off);
  }
  __shared__ float red[8];
  int wid = t >> 6, lane = t & 63;
  if (lane == 0) { red[wid] = s; red[wid + 4] = q; }
  __syncthreads();
  if (t == 0) {
    float S = red[0] + red[1] + red[2] + red[3];
    float Q = red[4] + red[5] + red[6] + red[7];
    float mean = S * (1.f / D_);
    float var = Q * (1.f / D_) - mean * mean;
    red[0] = mean;
    red[1] = rsqrtf(var + 1e-5f);
  }
  __syncthreads();
  float mean = red[0], inv = red[1];
  store_out(o, t, (v0 - mean) * inv * g[t] + b[t]);
  store_out(o, t + 256, (v1 - mean) * inv * g[t + 256] + b[t + 256]);
}

// ---------------- weight transpose + bf16 convert: in[K,N] fp32 -> out[N,K] bf16 ----------------
__global__ __launch_bounds__(256) void transpose_bf16_kernel(const float* __restrict__ in,
    short* __restrict__ out, int K, int N) {
  __shared__ float t[32][33];
  int n0 = blockIdx.x << 5, k0 = blockIdx.y << 5;
  int tx = threadIdx.x & 31, ty = threadIdx.x >> 5;  // 32 x 8
#pragma unroll
  for (int e = 0; e < 4; ++e)
    t[ty + e * 8][tx] = in[(size_t)(k0 + ty + e * 8) * N + n0 + tx];
  __syncthreads();
#pragma unroll
  for (int e = 0; e < 4; ++e)
    out[(size_t)(n0 + ty + e * 8) * K + k0 + tx] = f2bf(t[tx][ty + e * 8]);
}

// ---------------- MFMA bf16 GEMM: C[M,N] = epi(A[M,K] @ Bt[N,K]^T + bias) ----------------
// 128x128 tile, BK=32, 4 waves (2x2), 16x16x32 MFMA, fp32 accum.
// XCD-aware block swizzle (T1): each XCD gets a contiguous band of tiles -> A-panel L2 reuse.
// EPI: 0=bias, 1=bias+swish, 2=0.5*v+res, 3=v+res,
//      4=q-path (C=v+bias2, C2=v+bias3, both bf16), 5=v-transpose (vT[b,hd,s])
template <int EPI, typename OutT>
__global__ __launch_bounds__(256) void mfma_gemm(const short* __restrict__ A,
    const short* __restrict__ Bt, const float* __restrict__ bias,
    const float* __restrict__ res, OutT* __restrict__ C, short* __restrict__ C2,
    const float* __restrict__ bias2, const float* __restrict__ bias3,
    int M, int N, int K) {
  __shared__ short As[128 * 32];
  __shared__ short Bs[128 * 32];
  int tid = threadIdx.x;
  int w = tid >> 6, l = tid & 63;
  // XCD swizzle (grids here are always a multiple of 8 blocks)
  int nwg = gridDim.x * gridDim.y;
  int flat = blockIdx.y * gridDim.x + blockIdx.x;
  int W = (flat & 7) * (nwg >> 3) + (flat >> 3);
  int bm = (W / gridDim.x) << 7, bn = (W % gridDim.x) << 7;
  int wr = w >> 1, wc = w & 1;
  f32x4 acc[4][4] = {};

  int sr = l >> 2, sc = l & 3;
  int r0 = (w * 2 + 0) * 16 + sr;
  int r1 = (w * 2 + 1) * 16 + sr;
  int g0 = sc ^ ((r0 >> 1) & 3);
  int g1 = sc ^ ((r1 >> 1) & 3);
  const short* a0 = A + (size_t)(bm + r0) * K + g0 * 8;
  const short* a1 = A + (size_t)(bm + r1) * K + g1 * 8;
  const short* b0 = Bt + (size_t)(bn + r0) * K + g0 * 8;
  const short* b1 = Bt + (size_t)(bn + r1) * K + g1 * 8;
  short* asd0 = As + (w * 2 + 0) * 512;
  short* asd1 = As + (w * 2 + 1) * 512;
  short* bsd0 = Bs + (w * 2 + 0) * 512;
  short* bsd1 = Bs + (w * 2 + 1) * 512;

  int lcol = l & 15, lk = l >> 4;
  int aoff[4], boff[4];
#pragma unroll
  for (int m = 0; m < 4; ++m) {
    int r = wr * 64 + m * 16 + lcol;
    aoff[m] = r * 32 + ((lk ^ ((r >> 1) & 3)) << 3);
  }
#pragma unroll
  for (int n = 0; n < 4; ++n) {
    int r = wc * 64 + n * 16 + lcol;
    boff[n] = r * 32 + ((lk ^ ((r >> 1) & 3)) << 3);
  }

  for (int k0 = 0; k0 < K; k0 += 32) {
    gload_lds16(a0 + k0, asd0);
    gload_lds16(a1 + k0, asd1);
    gload_lds16(b0 + k0, bsd0);
    gload_lds16(b1 + k0, bsd1);
    __syncthreads();
    bf16x8 af[4], bfr[4];
#pragma unroll
    for (int m = 0; m < 4; ++m) af[m] = *(const bf16x8*)(As + aoff[m]);
#pragma unroll
    for (int n = 0; n < 4; ++n) bfr[n] = *(const bf16x8*)(Bs + boff[n]);
#pragma unroll
    for (int m = 0; m < 4; ++m)
#pragma unroll
      for (int n = 0; n < 4; ++n)
        acc[m][n] = __builtin_amdgcn_mfma_f32_16x16x32_bf16(af[m], bfr[n], acc[m][n], 0, 0, 0);
    __syncthreads();
  }

  // epilogue: C/D layout col=lane&15, row=(lane>>4)*4+reg
  int lrow = (l >> 4) << 2;
#pragma unroll
  for (int m = 0; m < 4; ++m) {
    int row0 = bm + wr * 64 + m * 16 + lrow;
#pragma unroll
    for (int n = 0; n < 4; ++n) {
      int col = bn + wc * 64 + n * 16 + lcol;
      float bv = bias ? bias[col] : 0.f;
      if (EPI == 5) {
        short4x o;
        o.x = f2bf(acc[m][n][0] + bv);
        o.y = f2bf(acc[m][n][1] + bv);
        o.z = f2bf(acc[m][n][2] + bv);
        o.w = f2bf(acc[m][n][3] + bv);
        size_t tidx = ((size_t)(row0 >> 10) * 512 + col) * 1024 + (row0 & 1023);
        *(short4x*)((short*)C + tidx) = o;
      } else if (EPI == 4) {
#pragma unroll
        for (int r = 0; r < 4; ++r) {
          size_t idx = (size_t)(row0 + r) * N + col;
          float v = acc[m][n][r] + bv;
          ((short*)C)[idx] = f2bf(v + bias2[col]);
          C2[idx] = f2bf(v + bias3[col]);
        }
      } else {
#pragma unroll
        for (int r = 0; r < 4; ++r) {
          size_t idx = (size_t)(row0 + r) * N + col;
          float v = acc[m][n][r] + bv;
          if (EPI == 1) v = v * sigmoidf_(v);
          else if (EPI == 2) v = 0.5f * v + res[idx];
          else if (EPI == 3) v = v + res[idx];
          store_out(C, idx, v);
        }
      }
    }
  }
}

// ---------------- sinusoidal positional encoding (S=1024, D=512), bf16 out ----------------
__global__ __launch_bounds__(256) void pe_kernel(short* __restrict__ pe) {
  int t = blockIdx.x, i = threadIdx.x;  // i in 0..255
  float freq = expf((float)(2 * i) * (-9.2103403719761836f / 512.f));  // ln(10000)
  float arg = (float)t * freq;
  pe[(size_t)t * D_ + 2 * i] = f2bf(sinf(arg));
  pe[(size_t)t * D_ + 2 * i + 1] = f2bf(cosf(arg));
}

// ---------------- raw pos scores P[z,i,t] = qv . pos  (bf16 out, 128x128 tile) ----------------
__global__ __launch_bounds__(256) void attn_pos_mfma(const short* __restrict__ Qb,
    const short* __restrict__ Pos, short* __restrict__ Out, int bh0) {
  __shared__ short Qs[128 * 64];
  __shared__ short Ks[128 * 64];
  int tid = threadIdx.x;
  int w = tid >> 6, l = tid & 63;
  int z = blockIdx.z;
  int bh = bh0 + z, b = bh >> 3, h = bh & 7;
  int bi = blockIdx.y << 7, bj = blockIdx.x << 7;
  int srow = w * 8 + (l >> 3);
  int sch = l & 7;
#pragma unroll
  for (int cc = 0; cc < 4; ++cc) {
    int r = cc * 32 + srow;
    int g = sch ^ (r & 7);
    gload_lds16(Qb + (size_t)(b * S_ + bi + r) * D_ + h * DH_ + g * 8, Qs + (cc * 32 + w * 8) * 64);
    gload_lds16(Pos + (size_t)(bj + r) * D_ + h * DH_ + g * 8, Ks + (cc * 32 + w * 8) * 64);
  }
  __syncthreads();
  int wr = w >> 1, wc = w & 1;
  int lcol = l & 15, lk = l >> 4;
  bf16x8 qf[4][2], kf[4][2];
#pragma unroll
  for (int m = 0; m < 4; ++m)
#pragma unroll
    for (int ks = 0; ks < 2; ++ks) {
      int r = wr * 64 + m * 16 + lcol;
      int c = ks * 4 + lk;
      qf[m][ks] = *(const bf16x8*)(Qs + r * 64 + ((c ^ (r & 7)) << 3));
    }
#pragma unroll
  for (int n = 0; n < 4; ++n)
#pragma unroll
    for (int ks = 0; ks < 2; ++ks) {
      int r = wc * 64 + n * 16 + lcol;
      int c = ks * 4 + lk;
      kf[n][ks] = *(const bf16x8*)(Ks + r * 64 + ((c ^ (r & 7)) << 3));
    }
  f32x4 acc[4][4] = {};
#pragma unroll
  for (int ks = 0; ks < 2; ++ks)
#pragma unroll
    for (int m = 0; m < 4; ++m)
#pragma unroll
      for (int n = 0; n < 4; ++n)
        acc[m][n] = __builtin_amdgcn_mfma_f32_16x16x32_bf16(qf[m][ks], kf[n][ks], acc[m][n], 0, 0, 0);
  int lrow = (l >> 4) << 2;
#pragma unroll
  for (int m = 0; m < 4; ++m)
#pragma unroll
    for (int r = 0; r < 4; ++r) {
      int iG = bi + wr * 64 + m * 16 + lrow + r;
#pragma unroll
      for (int n = 0; n < 4; ++n) {
        int jG = bj + wc * 64 + n * 16 + lcol;
        Out[((size_t)z * S_ + iG) * S_ + jG] = f2bf(acc[m][n][r]);
      }
    }
}

// ---------------- fused attention: S=qu.k^T + shift(P); online softmax; O=P.V ----------------
// 512 thr / 8 waves; Q-strip 128 rows (wave w owns 16). 16 j-steps of 64.
// Double-buffered K/V LDS (DMA for step jt+1 issued before step jt's compute) and
// P-gather prefetched one step ahead into registers -> latency hides under QK/softmax/PV.
__global__ __launch_bounds__(512) void attn_fused(const short* __restrict__ qu,
    const short* __restrict__ kk, const short* __restrict__ vT,
    const short* __restrict__ P16, short* __restrict__ ctx, int bh0) {
  __shared__ short Ks[2][64 * 64];
  __shared__ short Vs[2][64 * 64];
  __shared__ short Ps[128 * 64];
  int tid = threadIdx.x;
  int w = tid >> 6, l = tid & 63;
  int z = blockIdx.y;
  int bh = bh0 + z, b = bh >> 3, h = bh & 7;
  int i0 = blockIdx.x << 7;
  const short* Pz = P16 + (size_t)z * S_ * S_;
  // Q A-fragments: row = i0 + w*16 + (l&15), k-slice d = ks*32 + (l>>4)*8
  bf16x8 qf0, qf1;
  {
    const short* qrow = qu + (size_t)(b * S_ + i0 + w * 16 + (l & 15)) * D_ + h * DH_ + ((l >> 4) << 3);
    qf0 = *(const bf16x8*)(qrow);
    qf1 = *(const bf16x8*)(qrow + 32);
  }
  f32x4 po[4] = {};
  float mrow[4], lrw[4];
  int gi[4];
#pragma unroll
  for (int r = 0; r < 4; ++r) {
    mrow[r] = -1e30f;
    lrw[r] = 0.f;
    gi[r] = i0 + w * 16 + ((l >> 4) << 2) + r;
  }

  // staging geometry: wave w stages rows w*8..w*8+8 of the 64-row tile
  int srw = (w << 3) + (l >> 3);      // 0..63
  int sg = (l & 7) ^ (srw & 7);       // swizzled source chunk
  const short* ksrc = kk + (size_t)(b * S_) * D_ + h * DH_ + (sg << 3);
  const short* vsrc = vT + (size_t)(b * 512 + h * DH_ + srw) * 1024 + (sg << 3);
  int sdst = (w << 3) * 64;

  auto STAGE = [&](int jt, int buf) {
    int j0 = jt << 6;
    gload_lds16(ksrc + (size_t)(j0 + srw) * D_, &Ks[buf][sdst]);
    gload_lds16(vsrc + j0, &Vs[buf][sdst]);
  };

  float pvc[4][4], pvn[4][4];
  auto PLOAD = [&](int jt, float pv[4][4]) {
#pragma unroll
    for (int n = 0; n < 4; ++n)
#pragma unroll
      for (int r = 0; r < 4; ++r) {
        int i = gi[r];
        int j = (jt << 6) + (n << 4) + (l & 15);
        float v;
        if (j <= i) v = bf2f(Pz[(size_t)i * S_ + (S_ - 1) - i + j]);
        else if (j == i + 1) v = 0.f;
        else v = bf2f(Pz[(size_t)(i + 1) * S_ + j - i - 2]);
        pv[n][r] = v;
      }
  };

  STAGE(0, 0);
  PLOAD(0, pvc);
  __syncthreads();

  for (int jt = 0; jt < 16; ++jt) {
    int buf = jt & 1;
    if (jt < 15) {
      STAGE(jt + 1, buf ^ 1);   // DMA into other buffer, completes by end-of-step barrier
      PLOAD(jt + 1, pvn);       // register prefetch, latency hidden under this step
    }
    // S tile = qu . K^T
    f32x4 sc[4] = {};
#pragma unroll
    for (int ks = 0; ks < 2; ++ks)
#pragma unroll
      for (int n = 0; n < 4; ++n) {
        int rj = (n << 4) + (l & 15);
        int ck = (ks << 2) + (l >> 4);
        bf16x8 kf = *(const bf16x8*)(&Ks[buf][rj * 64 + ((ck ^ (rj & 7)) << 3)]);
        sc[n] = __builtin_amdgcn_mfma_f32_16x16x32_bf16(ks == 0 ? qf0 : qf1, kf, sc[n], 0, 0, 0);
      }
    // add pos score (prefetched), scale, tile max
    float pm[4];
#pragma unroll
    for (int r = 0; r < 4; ++r) pm[r] = -1e30f;
#pragma unroll
    for (int n = 0; n < 4; ++n)
#pragma unroll
      for (int r = 0; r < 4; ++r) {
        float v = (sc[n][r] + pvc[n][r]) * INV_SQRT_D;
        sc[n][r] = v;
        pm[r] = fmaxf(pm[r], v);
      }
#pragma unroll
    for (int r = 0; r < 4; ++r)
#pragma unroll
      for (int off = 1; off < 16; off <<= 1) pm[r] = fmaxf(pm[r], __shfl_xor(pm[r], off));
    // online-softmax update
    float psum[4];
#pragma unroll
    for (int r = 0; r < 4; ++r) {
      float mn = fmaxf(mrow[r], pm[r]);
      float f = __expf(mrow[r] - mn);
      mrow[r] = mn;
      lrw[r] *= f;
#pragma unroll
      for (int n = 0; n < 4; ++n) po[n][r] *= f;
      psum[r] = 0.f;
    }
#pragma unroll
    for (int n = 0; n < 4; ++n)
#pragma unroll
      for (int r = 0; r < 4; ++r) {
        float p = __expf(sc[n][r] - mrow[r]);
        psum[r] += p;
        int rr = (w << 4) + ((l >> 4) << 2) + r;
        int c = (n << 4) + (l & 15);
        Ps[rr * 64 + (((c >> 3) ^ (rr & 7)) << 3) + (c & 7)] = f2bf(p);
      }
#pragma unroll
    for (int r = 0; r < 4; ++r) {
#pragma unroll
      for (int off = 1; off < 16; off <<= 1) psum[r] += __shfl_xor(psum[r], off);
      lrw[r] += psum[r];
    }
    // O += P . V  (Ps strip is wave-private -> no cross-wave barrier needed before PV)
    int rr2 = (w << 4) + (l & 15);
    bf16x8 pa[2];
#pragma unroll
    for (int ks = 0; ks < 2; ++ks) {
      int ck = (ks << 2) + (l >> 4);
      pa[ks] = *(const bf16x8*)(&Ps[rr2 * 64 + ((ck ^ (rr2 & 7)) << 3)]);
    }
#pragma unroll
    for (int ks = 0; ks < 2; ++ks)
#pragma unroll
      for (int n = 0; n < 4; ++n) {
        int rd = (n << 4) + (l & 15);
        int ck = (ks << 2) + (l >> 4);
        bf16x8 vf = *(const bf16x8*)(&Vs[buf][rd * 64 + ((ck ^ (rd & 7)) << 3)]);
        po[n] = __builtin_amdgcn_mfma_f32_16x16x32_bf16(pa[ks], vf, po[n], 0, 0, 0);
      }
    __syncthreads();  // drains DMA + prefetch loads; protects K/V buffers and Ps
    if (jt < 15) {
#pragma unroll
      for (int n = 0; n < 4; ++n)
#pragma unroll
        for (int r = 0; r < 4; ++r) pvc[n][r] = pvn[n][r];
    }
  }
  short* Cz = ctx + (size_t)b * S_ * D_ + h * DH_;
#pragma unroll
  for (int r = 0; r < 4; ++r) {
    float inv = 1.f / lrw[r];
#pragma unroll
    for (int n = 0; n < 4; ++n)
      Cz[(size_t)gi[r] * D_ + (n << 4) + (l & 15)] = f2bf(po[n][r] * inv);
  }
}

// ---------------- GLU bf16: z[r,c] = a * sigmoid(g) ----------------
__global__ __launch_bounds__(256) void glu_kernel(const short* __restrict__ hbuf,
                                                  short* __restrict__ z) {
  size_t idx4 = ((size_t)blockIdx.x * 256 + threadIdx.x) << 2;
  size_t row = idx4 >> 10, c = idx4 & 1023;
  short4x a4 = *(const short4x*)(hbuf + row * 2048 + c);
  short4x g4 = *(const short4x*)(hbuf + row * 2048 + 1024 + c);
  short4x o;
  o.x = f2bf(bf2f(a4.x) * sigmoidf_(bf2f(g4.x)));
  o.y = f2bf(bf2f(a4.y) * sigmoidf_(bf2f(g4.y)));
  o.z = f2bf(bf2f(a4.z) * sigmoidf_(bf2f(g4.z)));
  o.w = f2bf(bf2f(a4.w) * sigmoidf_(bf2f(g4.w)));
  *(short4x*)(z + idx4) = o;
}

// ---------------- depthwise conv k=31 (+BN+swish), (b,s,c) bf16 in/out ----------------
#define CTS 32
__global__ __launch_bounds__(256) void dwconv_kernel(const short* __restrict__ z,
    const float* __restrict__ w, const float* __restrict__ wb,
    const float* __restrict__ bng, const float* __restrict__ bnb,
    const float* __restrict__ bnm, const float* __restrict__ bnv,
    short* __restrict__ out) {
  int c = (blockIdx.z << 8) + threadIdx.x;  // channel 0..1023
  int b = blockIdx.y;
  int s0 = blockIdx.x * CTS;
  float wr[31];
#pragma unroll
  for (int kk = 0; kk < 31; ++kk) wr[kk] = w[c * 31 + kk];
  float zv[CTS + 30];
#pragma unroll
  for (int e = 0; e < CTS + 30; ++e) {
    int sr = s0 - 15 + e;
    zv[e] = (sr >= 0 && sr < S_) ? bf2f(z[((size_t)(b * S_ + sr) << 10) + c]) : 0.f;
  }
  float scale = bng[c] * rsqrtf(bnv[c] + 1e-5f);
  float shift = bnb[c] - bnm[c] * scale;
  float bias = wb[c];
#pragma unroll
  for (int s = 0; s < CTS; ++s) {
    float acc = 0.f;
#pragma unroll
    for (int kk = 0; kk < 31; ++kk) acc += zv[s + kk] * wr[kk];
    float v = (acc + bias) * scale + shift;
    v = v * sigmoidf_(v);
    out[((size_t)(b * S_ + s0 + s) << 10) + c] = f2bf(v);
  }
}

extern "C" void kernel_launch(void* const* d_in, const int* in_sizes, int n_in,
                              void* d_out, int out_size, void* d_ws, size_t ws_size,
                              hipStream_t stream) {
  const float* x_in = (const float*)d_in[0];
  const float* ff1_ln_g = (const float*)d_in[1];
  const float* ff1_ln_b = (const float*)d_in[2];
  const float* ff1_w1 = (const float*)d_in[3];
  const float* ff1_b1 = (const float*)d_in[4];
  const float* ff1_w2 = (const float*)d_in[5];
  const float* ff1_b2 = (const float*)d_in[6];
  const float* attn_ln_g = (const float*)d_in[7];
  const float* attn_ln_b = (const float*)d_in[8];
  const float* wq = (const float*)d_in[9];
  const float* bq = (const float*)d_in[10];
  const float* wk = (const float*)d_in[11];
  const float* bk = (const float*)d_in[12];
  const float* wv = (const float*)d_in[13];
  const float* bv = (const float*)d_in[14];
  const float* wpos = (const float*)d_in[15];
  const float* u_bias = (const float*)d_in[16];
  const float* v_bias = (const float*)d_in[17];
  const float* wo = (const float*)d_in[18];
  const float* bo = (const float*)d_in[19];
  const float* conv_ln_g = (const float*)d_in[20];
  const float* conv_ln_b = (const float*)d_in[21];
  const float* pw1_w = (const float*)d_in[22];
  const float* pw1_b = (const float*)d_in[23];
  const float* dw_w = (const float*)d_in[24];
  const float* dw_b = (const float*)d_in[25];
  const float* bn_g = (const float*)d_in[26];
  const float* bn_b = (const float*)d_in[27];
  const float* bn_mean = (const float*)d_in[28];
  const float* bn_var = (const float*)d_in[29];
  const float* pw2_w = (const float*)d_in[30];
  const float* pw2_b = (const float*)d_in[31];
  const float* ff2_ln_g = (const float*)d_in[32];
  const float* ff2_ln_b = (const float*)d_in[33];
  const float* ff2_w1 = (const float*)d_in[34];
  const float* ff2_b1 = (const float*)d_in[35];
  const float* ff2_w2 = (const float*)d_in[36];
  const float* ff2_b2 = (const float*)d_in[37];
  const float* norm_g = (const float*)d_in[38];
  const float* norm_b = (const float*)d_in[39];

  char* wsb = (char*)d_ws;
  float* xb = (float*)(wsb);                      // 16 MiB fp32 residual
  short* yb16 = (short*)(wsb + (16ull << 20));    // 8 MiB  LN out
  short* qu16 = (short*)(wsb + (24ull << 20));    // 8 MiB
  short* qv16 = (short*)(wsb + (32ull << 20));    // 8 MiB
  short* k16 = (short*)(wsb + (40ull << 20));     // 8 MiB
  short* vT16 = (short*)(wsb + (48ull << 20));    // 8 MiB
  short* ctx16 = (short*)(wsb + (56ull << 20));   // 8 MiB
  short* pos16 = (short*)(wsb + (64ull << 20));   // 1 MiB
  short* wt = (short*)(wsb + (65ull << 20));      // 13.5 MiB
  short* Pb16 = (short*)(wsb + (80ull << 20));    // 64 MiB (32-bh chunk), attn phase only
  short* hb16 = (short*)(wsb + (80ull << 20));    // 32 MiB FF hidden / pw1-out (non-attn phases)
  short* zb16 = (short*)(wsb + (112ull << 20));   // 16 MiB GLU out
  short* cb16 = (short*)(wsb + (128ull << 20));   // 16 MiB dwconv out
  short* peb16 = ctx16;                           // PE scratch (free at that point)

  short* ff1w1t = wt;
  short* ff1w2t = ff1w1t + 2048 * 512;
  short* wqt = ff1w2t + 512 * 2048;
  short* wkt = wqt + 512 * 512;
  short* wvt = wkt + 512 * 512;
  short* wot = wvt + 512 * 512;
  short* wpost = wot + 512 * 512;
  short* pw1t = wpost + 512 * 512;
  short* pw2t = pw1t + 2048 * 512;
  short* ff2w1t = pw2t + 512 * 1024;
  short* ff2w2t = ff2w1t + 2048 * 512;

  dim3 blk(256);

  // ---- weight transposes (fp32 [K,N] -> bf16 [N,K]) ----
  transpose_bf16_kernel<<<dim3(64, 16), blk, 0, stream>>>(ff1_w1, ff1w1t, 512, 2048);
  transpose_bf16_kernel<<<dim3(16, 64), blk, 0, stream>>>(ff1_w2, ff1w2t, 2048, 512);
  transpose_bf16_kernel<<<dim3(16, 16), blk, 0, stream>>>(wq, wqt, 512, 512);
  transpose_bf16_kernel<<<dim3(16, 16), blk, 0, stream>>>(wk, wkt, 512, 512);
  transpose_bf16_kernel<<<dim3(16, 16), blk, 0, stream>>>(wv, wvt, 512, 512);
  transpose_bf16_kernel<<<dim3(16, 16), blk, 0, stream>>>(wo, wot, 512, 512);
  transpose_bf16_kernel<<<dim3(16, 16), blk, 0, stream>>>(wpos, wpost, 512, 512);
  transpose_bf16_kernel<<<dim3(64, 16), blk, 0, stream>>>(pw1_w, pw1t, 512, 2048);
  transpose_bf16_kernel<<<dim3(16, 32), blk, 0, stream>>>(pw2_w, pw2t, 1024, 512);
  transpose_bf16_kernel<<<dim3(64, 16), blk, 0, stream>>>(ff2_w1, ff2w1t, 512, 2048);
  transpose_bf16_kernel<<<dim3(16, 64), blk, 0, stream>>>(ff2_w2, ff2w2t, 2048, 512);

  // ---- FF1 half-residual ----
  ln_kernel<short><<<NROWS, blk, 0, stream>>>(x_in, ff1_ln_g, ff1_ln_b, yb16);
  mfma_gemm<1, short><<<dim3(FF_ / 128, NROWS / 128), blk, 0, stream>>>(yb16, ff1w1t, ff1_b1, nullptr, hb16, nullptr, nullptr, nullptr, NROWS, FF_, D_);
  mfma_gemm<2, float><<<dim3(D_ / 128, NROWS / 128), blk, 0, stream>>>(hb16, ff1w2t, ff1_b2, x_in, xb, nullptr, nullptr, nullptr, NROWS, D_, FF_);

  // ---- attention ----
  ln_kernel<short><<<NROWS, blk, 0, stream>>>(xb, attn_ln_g, attn_ln_b, yb16);
  mfma_gemm<4, short><<<dim3(D_ / 128, NROWS / 128), blk, 0, stream>>>(yb16, wqt, bq, nullptr, qu16, qv16, u_bias, v_bias, NROWS, D_, D_);
  mfma_gemm<0, short><<<dim3(D_ / 128, NROWS / 128), blk, 0, stream>>>(yb16, wkt, bk, nullptr, k16, nullptr, nullptr, nullptr, NROWS, D_, D_);
  mfma_gemm<5, short><<<dim3(D_ / 128, NROWS / 128), blk, 0, stream>>>(yb16, wvt, bv, nullptr, vT16, nullptr, nullptr, nullptr, NROWS, D_, D_);
  pe_kernel<<<S_, blk, 0, stream>>>(peb16);
  mfma_gemm<0, short><<<dim3(D_ / 128, S_ / 128), blk, 0, stream>>>(peb16, wpost, nullptr, nullptr, pos16, nullptr, nullptr, nullptr, S_, D_, D_);

  const int CH = 32;  // bh per chunk (P chunk = 64 MiB bf16)
  for (int c = 0; c < 64 / CH; ++c) {
    int bh0 = c * CH;
    attn_pos_mfma<<<dim3(8, 8, CH), blk, 0, stream>>>(qv16, pos16, Pb16, bh0);
    attn_fused<<<dim3(S_ / 128, CH), dim3(512), 0, stream>>>(qu16, k16, vT16, Pb16, ctx16, bh0);
  }
  mfma_gemm<3, float><<<dim3(D_ / 128, NROWS / 128), blk, 0, stream>>>(ctx16, wot, bo, xb, xb, nullptr, nullptr, nullptr, NROWS, D_, D_);

  // ---- conv module ----
  ln_kernel<short><<<NROWS, blk, 0, stream>>>(xb, conv_ln_g, conv_ln_b, yb16);
  mfma_gemm<0, short><<<dim3(2 * INNER_ / 128, NROWS / 128), blk, 0, stream>>>(yb16, pw1t, pw1_b, nullptr, hb16, nullptr, nullptr, nullptr, NROWS, 2 * INNER_, D_);
  glu_kernel<<<NROWS * INNER_ / 1024, blk, 0, stream>>>(hb16, zb16);
  dwconv_kernel<<<dim3(S_ / CTS, B_, 4), blk, 0, stream>>>(zb16, dw_w, dw_b, bn_g, bn_b, bn_mean, bn_var, cb16);
  mfma_gemm<3, float><<<dim3(D_ / 128, NROWS / 128), blk, 0, stream>>>(cb16, pw2t, pw2_b, xb, xb, nullptr, nullptr, nullptr, NROWS, D_, INNER_);

  // ---- FF2 half-residual ----
  ln_kernel<short><<<NROWS, blk, 0, stream>>>(xb, ff2_ln_g, ff2_ln_b, yb16);
  mfma_gemm<1, short><<<dim3(FF_ / 128, NROWS / 128), blk, 0, stream>>>(yb16, ff2w1t, ff2_b1, nullptr, hb16, nullptr, nullptr, nullptr, NROWS, FF_, D_);
  mfma_gemm<2, float><<<dim3(D_ / 128, NROWS / 128), blk, 0, stream>>>(hb16, ff2w2t, ff2_b2, xb, xb, nullptr, nullptr, nullptr, NROWS, D_, FF_);

  // ---- final LN ----
  ln_kernel<float><<<NROWS, blk, 0, stream>>>(xb, norm_g, norm_b, (float*)d_out);
}

// Round 7
// 571.522 us; speedup vs baseline: 5.6500x; 1.2220x over previous
//
#include <hip/hip_runtime.h>
#include <cstdint>
#include <cstddef>

#define B_ 8
#define S_ 1024
#define D_ 512
#define H_ 8
#define DH_ 64
#define FF_ 2048
#define INNER_ 1024
#define NROWS 8192
#define INV_SQRT_D 0.04419417382415922f  // 1/sqrt(512)

typedef __attribute__((ext_vector_type(8))) short bf16x8;
typedef __attribute__((ext_vector_type(4))) float f32x4;
struct alignas(8) short4x { short x, y, z, w; };

__device__ __forceinline__ float sigmoidf_(float x) { return 1.f / (1.f + expf(-x)); }

__device__ __forceinline__ short f2bf(float f) {  // RNE float->bf16
  uint32_t u = __float_as_uint(f);
  u += 0x7fff + ((u >> 16) & 1);
  return (short)(u >> 16);
}
__device__ __forceinline__ float bf2f(short s) {
  return __uint_as_float(((uint32_t)(uint16_t)s) << 16);
}

__device__ __forceinline__ void store_out(float* C, size_t i, float v) { C[i] = v; }
__device__ __forceinline__ void store_out(short* C, size_t i, float v) { C[i] = f2bf(v); }

__device__ __forceinline__ void gload_lds16(const void* g, void* lds) {
  __builtin_amdgcn_global_load_lds(
      (const __attribute__((address_space(1))) uint32_t*)g,
      (__attribute__((address_space(3))) uint32_t*)lds, 16, 0, 0);
}

// ---------------- LayerNorm over D=512, one block (256 thr) per row ----------------
template <typename OutT>
__global__ __launch_bounds__(256) void ln_kernel(const float* __restrict__ in,
    const float* __restrict__ g, const float* __restrict__ b,
    OutT* __restrict__ out) {
  int row = blockIdx.x;
  const float* x = in + (size_t)row * D_;
  OutT* o = out + (size_t)row * D_;
  int t = threadIdx.x;
  float v0 = x[t], v1 = x[t + 256];
  float s = v0 + v1, q = v0 * v0 + v1 * v1;
#pragma unroll
  for (int off = 32; off > 0; off >>= 1) {
    s += __shfl_down(s, off);
    q += __shfl_down(q, off);
  }
  __shared__ float red[8];
  int wid = t >> 6, lane = t & 63;
  if (lane == 0) { red[wid] = s; red[wid + 4] = q; }
  __syncthreads();
  if (t == 0) {
    float S = red[0] + red[1] + red[2] + red[3];
    float Q = red[4] + red[5] + red[6] + red[7];
    float mean = S * (1.f / D_);
    float var = Q * (1.f / D_) - mean * mean;
    red[0] = mean;
    red[1] = rsqrtf(var + 1e-5f);
  }
  __syncthreads();
  float mean = red[0], inv = red[1];
  store_out(o, t, (v0 - mean) * inv * g[t] + b[t]);
  store_out(o, t + 256, (v1 - mean) * inv * g[t + 256] + b[t + 256]);
}

// ---------------- weight transpose + bf16 convert: in[K,N] fp32 -> out[N,K] bf16 ----------------
__global__ __launch_bounds__(256) void transpose_bf16_kernel(const float* __restrict__ in,
    short* __restrict__ out, int K, int N) {
  __shared__ float t[32][33];
  int n0 = blockIdx.x << 5, k0 = blockIdx.y << 5;
  int tx = threadIdx.x & 31, ty = threadIdx.x >> 5;  // 32 x 8
#pragma unroll
  for (int e = 0; e < 4; ++e)
    t[ty + e * 8][tx] = in[(size_t)(k0 + ty + e * 8) * N + n0 + tx];
  __syncthreads();
#pragma unroll
  for (int e = 0; e < 4; ++e)
    out[(size_t)(n0 + ty + e * 8) * K + k0 + tx] = f2bf(t[tx][ty + e * 8]);
}

// ---------------- MFMA bf16 GEMM: C[M,N] = epi(A[M,K] @ Bt[N,K]^T + bias) ----------------
// 128x128 tile, BK=32, 4 waves (2x2), 16x16x32 MFMA, fp32 accum. XCD-aware swizzle (T1).
// EPI: 0=bias, 1=bias+swish, 2=0.5*v+res, 3=v+res,
//      4=q-path (C=v+bias2, C2=v+bias3, both bf16), 5=v-transpose (vT[b,hd,s])
template <int EPI, typename OutT>
__global__ __launch_bounds__(256) void mfma_gemm(const short* __restrict__ A,
    const short* __restrict__ Bt, const float* __restrict__ bias,
    const float* __restrict__ res, OutT* __restrict__ C, short* __restrict__ C2,
    const float* __restrict__ bias2, const float* __restrict__ bias3,
    int M, int N, int K) {
  __shared__ short As[128 * 32];
  __shared__ short Bs[128 * 32];
  int tid = threadIdx.x;
  int w = tid >> 6, l = tid & 63;
  int nwg = gridDim.x * gridDim.y;
  int flat = blockIdx.y * gridDim.x + blockIdx.x;
  int W = (flat & 7) * (nwg >> 3) + (flat >> 3);
  int bm = (W / gridDim.x) << 7, bn = (W % gridDim.x) << 7;
  int wr = w >> 1, wc = w & 1;
  f32x4 acc[4][4] = {};

  int sr = l >> 2, sc = l & 3;
  int r0 = (w * 2 + 0) * 16 + sr;
  int r1 = (w * 2 + 1) * 16 + sr;
  int g0 = sc ^ ((r0 >> 1) & 3);
  int g1 = sc ^ ((r1 >> 1) & 3);
  const short* a0 = A + (size_t)(bm + r0) * K + g0 * 8;
  const short* a1 = A + (size_t)(bm + r1) * K + g1 * 8;
  const short* b0 = Bt + (size_t)(bn + r0) * K + g0 * 8;
  const short* b1 = Bt + (size_t)(bn + r1) * K + g1 * 8;
  short* asd0 = As + (w * 2 + 0) * 512;
  short* asd1 = As + (w * 2 + 1) * 512;
  short* bsd0 = Bs + (w * 2 + 0) * 512;
  short* bsd1 = Bs + (w * 2 + 1) * 512;

  int lcol = l & 15, lk = l >> 4;
  int aoff[4], boff[4];
#pragma unroll
  for (int m = 0; m < 4; ++m) {
    int r = wr * 64 + m * 16 + lcol;
    aoff[m] = r * 32 + ((lk ^ ((r >> 1) & 3)) << 3);
  }
#pragma unroll
  for (int n = 0; n < 4; ++n) {
    int r = wc * 64 + n * 16 + lcol;
    boff[n] = r * 32 + ((lk ^ ((r >> 1) & 3)) << 3);
  }

  for (int k0 = 0; k0 < K; k0 += 32) {
    gload_lds16(a0 + k0, asd0);
    gload_lds16(a1 + k0, asd1);
    gload_lds16(b0 + k0, bsd0);
    gload_lds16(b1 + k0, bsd1);
    __syncthreads();
    bf16x8 af[4], bfr[4];
#pragma unroll
    for (int m = 0; m < 4; ++m) af[m] = *(const bf16x8*)(As + aoff[m]);
#pragma unroll
    for (int n = 0; n < 4; ++n) bfr[n] = *(const bf16x8*)(Bs + boff[n]);
#pragma unroll
    for (int m = 0; m < 4; ++m)
#pragma unroll
      for (int n = 0; n < 4; ++n)
        acc[m][n] = __builtin_amdgcn_mfma_f32_16x16x32_bf16(af[m], bfr[n], acc[m][n], 0, 0, 0);
    __syncthreads();
  }

  int lrow = (l >> 4) << 2;
#pragma unroll
  for (int m = 0; m < 4; ++m) {
    int row0 = bm + wr * 64 + m * 16 + lrow;
#pragma unroll
    for (int n = 0; n < 4; ++n) {
      int col = bn + wc * 64 + n * 16 + lcol;
      float bv = bias ? bias[col] : 0.f;
      if (EPI == 5) {
        short4x o;
        o.x = f2bf(acc[m][n][0] + bv);
        o.y = f2bf(acc[m][n][1] + bv);
        o.z = f2bf(acc[m][n][2] + bv);
        o.w = f2bf(acc[m][n][3] + bv);
        size_t tidx = ((size_t)(row0 >> 10) * 512 + col) * 1024 + (row0 & 1023);
        *(short4x*)((short*)C + tidx) = o;
      } else if (EPI == 4) {
#pragma unroll
        for (int r = 0; r < 4; ++r) {
          size_t idx = (size_t)(row0 + r) * N + col;
          float v = acc[m][n][r] + bv;
          ((short*)C)[idx] = f2bf(v + bias2[col]);
          C2[idx] = f2bf(v + bias3[col]);
        }
      } else {
#pragma unroll
        for (int r = 0; r < 4; ++r) {
          size_t idx = (size_t)(row0 + r) * N + col;
          float v = acc[m][n][r] + bv;
          if (EPI == 1) v = v * sigmoidf_(v);
          else if (EPI == 2) v = 0.5f * v + res[idx];
          else if (EPI == 3) v = v + res[idx];
          store_out(C, idx, v);
        }
      }
    }
  }
}

// ---------------- sinusoidal positional encoding (S=1024, D=512), bf16 out ----------------
__global__ __launch_bounds__(256) void pe_kernel(short* __restrict__ pe) {
  int t = blockIdx.x, i = threadIdx.x;  // i in 0..255
  float freq = expf((float)(2 * i) * (-9.2103403719761836f / 512.f));  // ln(10000)
  float arg = (float)t * freq;
  pe[(size_t)t * D_ + 2 * i] = f2bf(sinf(arg));
  pe[(size_t)t * D_ + 2 * i + 1] = f2bf(cosf(arg));
}

// ---------------- pos scores, PRE-SHIFTED: Pshift[z,i,j] = rel_shift(qv.pos)[i,j] ----------------
// P_raw[i,t] -> Pshift[i, t-(S-1-i)] if t >= S-1-i ; Pshift[i-1, t+i+1] if t < S-1-i (i>=1).
// Column j=i+1 is zeroed explicitly (rel_shift inserts it). i=0 low-t values are dropped.
__global__ __launch_bounds__(256) void attn_pos_mfma(const short* __restrict__ Qb,
    const short* __restrict__ Pos, short* __restrict__ Out, int bh0) {
  __shared__ short Qs[128 * 64];
  __shared__ short Ks[128 * 64];
  int tid = threadIdx.x;
  int w = tid >> 6, l = tid & 63;
  int z = blockIdx.z;
  int bh = bh0 + z, b = bh >> 3, h = bh & 7;
  int bi = blockIdx.y << 7, bj = blockIdx.x << 7;
  int srow = w * 8 + (l >> 3);
  int sch = l & 7;
#pragma unroll
  for (int cc = 0; cc < 4; ++cc) {
    int r = cc * 32 + srow;
    int g = sch ^ (r & 7);
    gload_lds16(Qb + (size_t)(b * S_ + bi + r) * D_ + h * DH_ + g * 8, Qs + (cc * 32 + w * 8) * 64);
    gload_lds16(Pos + (size_t)(bj + r) * D_ + h * DH_ + g * 8, Ks + (cc * 32 + w * 8) * 64);
  }
  __syncthreads();
  int wr = w >> 1, wc = w & 1;
  int lcol = l & 15, lk = l >> 4;
  bf16x8 qf[4][2], kf[4][2];
#pragma unroll
  for (int m = 0; m < 4; ++m)
#pragma unroll
    for (int ks = 0; ks < 2; ++ks) {
      int r = wr * 64 + m * 16 + lcol;
      int c = ks * 4 + lk;
      qf[m][ks] = *(const bf16x8*)(Qs + r * 64 + ((c ^ (r & 7)) << 3));
    }
#pragma unroll
  for (int n = 0; n < 4; ++n)
#pragma unroll
    for (int ks = 0; ks < 2; ++ks) {
      int r = wc * 64 + n * 16 + lcol;
      int c = ks * 4 + lk;
      kf[n][ks] = *(const bf16x8*)(Ks + r * 64 + ((c ^ (r & 7)) << 3));
    }
  f32x4 acc[4][4] = {};
#pragma unroll
  for (int ks = 0; ks < 2; ++ks)
#pragma unroll
    for (int m = 0; m < 4; ++m)
#pragma unroll
      for (int n = 0; n < 4; ++n)
        acc[m][n] = __builtin_amdgcn_mfma_f32_16x16x32_bf16(qf[m][ks], kf[n][ks], acc[m][n], 0, 0, 0);
  int lrow = (l >> 4) << 2;
  short* Oz = Out + (size_t)z * S_ * S_;
#pragma unroll
  for (int m = 0; m < 4; ++m)
#pragma unroll
    for (int r = 0; r < 4; ++r) {
      int iG = bi + wr * 64 + m * 16 + lrow + r;
#pragma unroll
      for (int n = 0; n < 4; ++n) {
        int tG = bj + wc * 64 + n * 16 + lcol;
        short val = f2bf(acc[m][n][r]);
        if (tG >= S_ - 1 - iG)
          Oz[(size_t)iG * S_ + (tG - (S_ - 1 - iG))] = val;
        else if (iG >= 1)
          Oz[(size_t)(iG - 1) * S_ + (tG + iG + 1)] = val;
        if (tG == 0 && iG < S_ - 1)
          Oz[(size_t)iG * S_ + iG + 1] = 0;
      }
    }
}

// ---------------- fused attention: S=qu.k^T + Pshift; online softmax; O=P.V ----------------
// 512 thr / 8 waves; Q-strip 128 rows. 16 j-steps of 64. K/V double-buffered via
// global_load_lds; Pshift rows streamed COALESCED, prefetched one step ahead into
// registers (macro with literal indices only -- no pointer decay, no scratch).
__global__ __launch_bounds__(512) void attn_fused(const short* __restrict__ qu,
    const short* __restrict__ kk, const short* __restrict__ vT,
    const short* __restrict__ Psh, short* __restrict__ ctx, int bh0) {
  __shared__ short Ks[2][64 * 64];
  __shared__ short Vs[2][64 * 64];
  __shared__ short Ps[128 * 64];
  int tid = threadIdx.x;
  int w = tid >> 6, l = tid & 63;
  int z = blockIdx.y;
  int bh = bh0 + z, b = bh >> 3, h = bh & 7;
  int i0 = blockIdx.x << 7;
  bf16x8 qf0, qf1;
  {
    const short* qrow = qu + (size_t)(b * S_ + i0 + w * 16 + (l & 15)) * D_ + h * DH_ + ((l >> 4) << 3);
    qf0 = *(const bf16x8*)(qrow);
    qf1 = *(const bf16x8*)(qrow + 32);
  }
  f32x4 po[4] = {};
  float mrow[4], lrw[4];
  int gi[4];
#pragma unroll
  for (int r = 0; r < 4; ++r) {
    mrow[r] = -1e30f;
    lrw[r] = 0.f;
    gi[r] = i0 + w * 16 + ((l >> 4) << 2) + r;
  }
  // coalesced Pshift row base pointers (lane jcol = consecutive j)
  const short* prow0 = Psh + (size_t)z * S_ * S_ + (size_t)gi[0] * S_ + (l & 15);
  const short* prow1 = prow0 + S_;
  const short* prow2 = prow1 + S_;
  const short* prow3 = prow2 + S_;

  int srw = (w << 3) + (l >> 3);      // 0..63
  int sg = (l & 7) ^ (srw & 7);       // swizzled source chunk
  const short* ksrc = kk + (size_t)(b * S_) * D_ + h * DH_ + (sg << 3);
  const short* vsrc = vT + (size_t)(b * 512 + h * DH_ + srw) * 1024 + (sg << 3);
  int sdst = (w << 3) * 64;

#define STAGE_KV(jt, buf)                                                  \
  {                                                                        \
    int j0_ = (jt) << 6;                                                   \
    gload_lds16(ksrc + (size_t)(j0_ + srw) * D_, &Ks[buf][sdst]);          \
    gload_lds16(vsrc + j0_, &Vs[buf][sdst]);                               \
  }

  float pvc[4][4], pvn[4][4];
#define PLOADF(jt, dst)                                                    \
  {                                                                        \
    int j0_ = (jt) << 6;                                                   \
    _Pragma("unroll") for (int n_ = 0; n_ < 4; ++n_) {                     \
      dst[n_][0] = bf2f(prow0[j0_ + (n_ << 4)]);                           \
      dst[n_][1] = bf2f(prow1[j0_ + (n_ << 4)]);                           \
      dst[n_][2] = bf2f(prow2[j0_ + (n_ << 4)]);                           \
      dst[n_][3] = bf2f(prow3[j0_ + (n_ << 4)]);                           \
    }                                                                      \
  }

  STAGE_KV(0, 0);
  PLOADF(0, pvc);
  __syncthreads();

  for (int jt = 0; jt < 16; ++jt) {
    int buf = jt & 1;
    if (jt < 15) {
      STAGE_KV(jt + 1, buf ^ 1);  // DMA into other buffer; completes by end-of-step barrier
      PLOADF(jt + 1, pvn);        // register prefetch, hides under this step's compute
    }
    // S tile = qu . K^T
    f32x4 sc[4] = {};
#pragma unroll
    for (int ks = 0; ks < 2; ++ks)
#pragma unroll
      for (int n = 0; n < 4; ++n) {
        int rj = (n << 4) + (l & 15);
        int ck = (ks << 2) + (l >> 4);
        bf16x8 kf = *(const bf16x8*)(&Ks[buf][rj * 64 + ((ck ^ (rj & 7)) << 3)]);
        sc[n] = __builtin_amdgcn_mfma_f32_16x16x32_bf16(ks == 0 ? qf0 : qf1, kf, sc[n], 0, 0, 0);
      }
    float pm[4];
#pragma unroll
    for (int r = 0; r < 4; ++r) pm[r] = -1e30f;
#pragma unroll
    for (int n = 0; n < 4; ++n)
#pragma unroll
      for (int r = 0; r < 4; ++r) {
        float v = (sc[n][r] + pvc[n][r]) * INV_SQRT_D;
        sc[n][r] = v;
        pm[r] = fmaxf(pm[r], v);
      }
#pragma unroll
    for (int r = 0; r < 4; ++r)
#pragma unroll
      for (int off = 1; off < 16; off <<= 1) pm[r] = fmaxf(pm[r], __shfl_xor(pm[r], off));
    float psum[4];
#pragma unroll
    for (int r = 0; r < 4; ++r) {
      float mn = fmaxf(mrow[r], pm[r]);
      float f = __expf(mrow[r] - mn);
      mrow[r] = mn;
      lrw[r] *= f;
#pragma unroll
      for (int n = 0; n < 4; ++n) po[n][r] *= f;
      psum[r] = 0.f;
    }
#pragma unroll
    for (int n = 0; n < 4; ++n)
#pragma unroll
      for (int r = 0; r < 4; ++r) {
        float p = __expf(sc[n][r] - mrow[r]);
        psum[r] += p;
        int rr = (w << 4) + ((l >> 4) << 2) + r;
        int c = (n << 4) + (l & 15);
        Ps[rr * 64 + (((c >> 3) ^ (rr & 7)) << 3) + (c & 7)] = f2bf(p);
      }
#pragma unroll
    for (int r = 0; r < 4; ++r) {
#pragma unroll
      for (int off = 1; off < 16; off <<= 1) psum[r] += __shfl_xor(psum[r], off);
      lrw[r] += psum[r];
    }
    // O += P . V  (Ps strip is wave-private)
    int rr2 = (w << 4) + (l & 15);
    bf16x8 pa[2];
#pragma unroll
    for (int ks = 0; ks < 2; ++ks) {
      int ck = (ks << 2) + (l >> 4);
      pa[ks] = *(const bf16x8*)(&Ps[rr2 * 64 + ((ck ^ (rr2 & 7)) << 3)]);
    }
#pragma unroll
    for (int ks = 0; ks < 2; ++ks)
#pragma unroll
      for (int n = 0; n < 4; ++n) {
        int rd = (n << 4) + (l & 15);
        int ck = (ks << 2) + (l >> 4);
        bf16x8 vf = *(const bf16x8*)(&Vs[buf][rd * 64 + ((ck ^ (rd & 7)) << 3)]);
        po[n] = __builtin_amdgcn_mfma_f32_16x16x32_bf16(pa[ks], vf, po[n], 0, 0, 0);
      }
    __syncthreads();  // drains DMA; protects K/V buffers and Ps
    if (jt < 15) {
#pragma unroll
      for (int n = 0; n < 4; ++n)
#pragma unroll
        for (int r = 0; r < 4; ++r) pvc[n][r] = pvn[n][r];
    }
  }
  short* Cz = ctx + (size_t)b * S_ * D_ + h * DH_;
#pragma unroll
  for (int r = 0; r < 4; ++r) {
    float inv = 1.f / lrw[r];
#pragma unroll
    for (int n = 0; n < 4; ++n)
      Cz[(size_t)gi[r] * D_ + (n << 4) + (l & 15)] = f2bf(po[n][r] * inv);
  }
#undef STAGE_KV
#undef PLOADF
}

// ---------------- GLU bf16: z[r,c] = a * sigmoid(g) ----------------
__global__ __launch_bounds__(256) void glu_kernel(const short* __restrict__ hbuf,
                                                  short* __restrict__ z) {
  size_t idx4 = ((size_t)blockIdx.x * 256 + threadIdx.x) << 2;
  size_t row = idx4 >> 10, c = idx4 & 1023;
  short4x a4 = *(const short4x*)(hbuf + row * 2048 + c);
  short4x g4 = *(const short4x*)(hbuf + row * 2048 + 1024 + c);
  short4x o;
  o.x = f2bf(bf2f(a4.x) * sigmoidf_(bf2f(g4.x)));
  o.y = f2bf(bf2f(a4.y) * sigmoidf_(bf2f(g4.y)));
  o.z = f2bf(bf2f(a4.z) * sigmoidf_(bf2f(g4.z)));
  o.w = f2bf(bf2f(a4.w) * sigmoidf_(bf2f(g4.w)));
  *(short4x*)(z + idx4) = o;
}

// ---------------- depthwise conv k=31 (+BN+swish), (b,s,c) bf16 in/out ----------------
#define CTS 32
__global__ __launch_bounds__(256) void dwconv_kernel(const short* __restrict__ z,
    const float* __restrict__ w, const float* __restrict__ wb,
    const float* __restrict__ bng, const float* __restrict__ bnb,
    const float* __restrict__ bnm, const float* __restrict__ bnv,
    short* __restrict__ out) {
  int c = (blockIdx.z << 8) + threadIdx.x;  // channel 0..1023
  int b = blockIdx.y;
  int s0 = blockIdx.x * CTS;
  float wr[31];
#pragma unroll
  for (int kk = 0; kk < 31; ++kk) wr[kk] = w[c * 31 + kk];
  float zv[CTS + 30];
#pragma unroll
  for (int e = 0; e < CTS + 30; ++e) {
    int sr = s0 - 15 + e;
    zv[e] = (sr >= 0 && sr < S_) ? bf2f(z[((size_t)(b * S_ + sr) << 10) + c]) : 0.f;
  }
  float scale = bng[c] * rsqrtf(bnv[c] + 1e-5f);
  float shift = bnb[c] - bnm[c] * scale;
  float bias = wb[c];
#pragma unroll
  for (int s = 0; s < CTS; ++s) {
    float acc = 0.f;
#pragma unroll
    for (int kk = 0; kk < 31; ++kk) acc += zv[s + kk] * wr[kk];
    float v = (acc + bias) * scale + shift;
    v = v * sigmoidf_(v);
    out[((size_t)(b * S_ + s0 + s) << 10) + c] = f2bf(v);
  }
}

extern "C" void kernel_launch(void* const* d_in, const int* in_sizes, int n_in,
                              void* d_out, int out_size, void* d_ws, size_t ws_size,
                              hipStream_t stream) {
  const float* x_in = (const float*)d_in[0];
  const float* ff1_ln_g = (const float*)d_in[1];
  const float* ff1_ln_b = (const float*)d_in[2];
  const float* ff1_w1 = (const float*)d_in[3];
  const float* ff1_b1 = (const float*)d_in[4];
  const float* ff1_w2 = (const float*)d_in[5];
  const float* ff1_b2 = (const float*)d_in[6];
  const float* attn_ln_g = (const float*)d_in[7];
  const float* attn_ln_b = (const float*)d_in[8];
  const float* wq = (const float*)d_in[9];
  const float* bq = (const float*)d_in[10];
  const float* wk = (const float*)d_in[11];
  const float* bk = (const float*)d_in[12];
  const float* wv = (const float*)d_in[13];
  const float* bv = (const float*)d_in[14];
  const float* wpos = (const float*)d_in[15];
  const float* u_bias = (const float*)d_in[16];
  const float* v_bias = (const float*)d_in[17];
  const float* wo = (const float*)d_in[18];
  const float* bo = (const float*)d_in[19];
  const float* conv_ln_g = (const float*)d_in[20];
  const float* conv_ln_b = (const float*)d_in[21];
  const float* pw1_w = (const float*)d_in[22];
  const float* pw1_b = (const float*)d_in[23];
  const float* dw_w = (const float*)d_in[24];
  const float* dw_b = (const float*)d_in[25];
  const float* bn_g = (const float*)d_in[26];
  const float* bn_b = (const float*)d_in[27];
  const float* bn_mean = (const float*)d_in[28];
  const float* bn_var = (const float*)d_in[29];
  const float* pw2_w = (const float*)d_in[30];
  const float* pw2_b = (const float*)d_in[31];
  const float* ff2_ln_g = (const float*)d_in[32];
  const float* ff2_ln_b = (const float*)d_in[33];
  const float* ff2_w1 = (const float*)d_in[34];
  const float* ff2_b1 = (const float*)d_in[35];
  const float* ff2_w2 = (const float*)d_in[36];
  const float* ff2_b2 = (const float*)d_in[37];
  const float* norm_g = (const float*)d_in[38];
  const float* norm_b = (const float*)d_in[39];

  char* wsb = (char*)d_ws;
  float* xb = (float*)(wsb);                      // 16 MiB fp32 residual
  short* yb16 = (short*)(wsb + (16ull << 20));    // 8 MiB  LN out
  short* qu16 = (short*)(wsb + (24ull << 20));    // 8 MiB
  short* qv16 = (short*)(wsb + (32ull << 20));    // 8 MiB
  short* k16 = (short*)(wsb + (40ull << 20));     // 8 MiB
  short* vT16 = (short*)(wsb + (48ull << 20));    // 8 MiB
  short* ctx16 = (short*)(wsb + (56ull << 20));   // 8 MiB
  short* pos16 = (short*)(wsb + (64ull << 20));   // 1 MiB
  short* wt = (short*)(wsb + (65ull << 20));      // 13.5 MiB
  short* Pb16 = (short*)(wsb + (80ull << 20));    // 64 MiB (32-bh chunk), attn phase only
  short* hb16 = (short*)(wsb + (80ull << 20));    // 32 MiB FF hidden / pw1-out (non-attn phases)
  short* zb16 = (short*)(wsb + (112ull << 20));   // 16 MiB GLU out
  short* cb16 = (short*)(wsb + (128ull << 20));   // 16 MiB dwconv out
  short* peb16 = ctx16;                           // PE scratch (free at that point)

  short* ff1w1t = wt;
  short* ff1w2t = ff1w1t + 2048 * 512;
  short* wqt = ff1w2t + 512 * 2048;
  short* wkt = wqt + 512 * 512;
  short* wvt = wkt + 512 * 512;
  short* wot = wvt + 512 * 512;
  short* wpost = wot + 512 * 512;
  short* pw1t = wpost + 512 * 512;
  short* pw2t = pw1t + 2048 * 512;
  short* ff2w1t = pw2t + 512 * 1024;
  short* ff2w2t = ff2w1t + 2048 * 512;

  dim3 blk(256);

  // ---- weight transposes (fp32 [K,N] -> bf16 [N,K]) ----
  transpose_bf16_kernel<<<dim3(64, 16), blk, 0, stream>>>(ff1_w1, ff1w1t, 512, 2048);
  transpose_bf16_kernel<<<dim3(16, 64), blk, 0, stream>>>(ff1_w2, ff1w2t, 2048, 512);
  transpose_bf16_kernel<<<dim3(16, 16), blk, 0, stream>>>(wq, wqt, 512, 512);
  transpose_bf16_kernel<<<dim3(16, 16), blk, 0, stream>>>(wk, wkt, 512, 512);
  transpose_bf16_kernel<<<dim3(16, 16), blk, 0, stream>>>(wv, wvt, 512, 512);
  transpose_bf16_kernel<<<dim3(16, 16), blk, 0, stream>>>(wo, wot, 512, 512);
  transpose_bf16_kernel<<<dim3(16, 16), blk, 0, stream>>>(wpos, wpost, 512, 512);
  transpose_bf16_kernel<<<dim3(64, 16), blk, 0, stream>>>(pw1_w, pw1t, 512, 2048);
  transpose_bf16_kernel<<<dim3(16, 32), blk, 0, stream>>>(pw2_w, pw2t, 1024, 512);
  transpose_bf16_kernel<<<dim3(64, 16), blk, 0, stream>>>(ff2_w1, ff2w1t, 512, 2048);
  transpose_bf16_kernel<<<dim3(16, 64), blk, 0, stream>>>(ff2_w2, ff2w2t, 2048, 512);

  // ---- FF1 half-residual ----
  ln_kernel<short><<<NROWS, blk, 0, stream>>>(x_in, ff1_ln_g, ff1_ln_b, yb16);
  mfma_gemm<1, short><<<dim3(FF_ / 128, NROWS / 128), blk, 0, stream>>>(yb16, ff1w1t, ff1_b1, nullptr, hb16, nullptr, nullptr, nullptr, NROWS, FF_, D_);
  mfma_gemm<2, float><<<dim3(D_ / 128, NROWS / 128), blk, 0, stream>>>(hb16, ff1w2t, ff1_b2, x_in, xb, nullptr, nullptr, nullptr, NROWS, D_, FF_);

  // ---- attention ----
  ln_kernel<short><<<NROWS, blk, 0, stream>>>(xb, attn_ln_g, attn_ln_b, yb16);
  mfma_gemm<4, short><<<dim3(D_ / 128, NROWS / 128), blk, 0, stream>>>(yb16, wqt, bq, nullptr, qu16, qv16, u_bias, v_bias, NROWS, D_, D_);
  mfma_gemm<0, short><<<dim3(D_ / 128, NROWS / 128), blk, 0, stream>>>(yb16, wkt, bk, nullptr, k16, nullptr, nullptr, nullptr, NROWS, D_, D_);
  mfma_gemm<5, short><<<dim3(D_ / 128, NROWS / 128), blk, 0, stream>>>(yb16, wvt, bv, nullptr, vT16, nullptr, nullptr, nullptr, NROWS, D_, D_);
  pe_kernel<<<S_, blk, 0, stream>>>(peb16);
  mfma_gemm<0, short><<<dim3(D_ / 128, S_ / 128), blk, 0, stream>>>(peb16, wpost, nullptr, nullptr, pos16, nullptr, nullptr, nullptr, S_, D_, D_);

  const int CH = 32;  // bh per chunk (P chunk = 64 MiB bf16)
  for (int c = 0; c < 64 / CH; ++c) {
    int bh0 = c * CH;
    attn_pos_mfma<<<dim3(8, 8, CH), blk, 0, stream>>>(qv16, pos16, Pb16, bh0);
    attn_fused<<<dim3(S_ / 128, CH), dim3(512), 0, stream>>>(qu16, k16, vT16, Pb16, ctx16, bh0);
  }
  mfma_gemm<3, float><<<dim3(D_ / 128, NROWS / 128), blk, 0, stream>>>(ctx16, wot, bo, xb, xb, nullptr, nullptr, nullptr, NROWS, D_, D_);

  // ---- conv module ----
  ln_kernel<short><<<NROWS, blk, 0, stream>>>(xb, conv_ln_g, conv_ln_b, yb16);
  mfma_gemm<0, short><<<dim3(2 * INNER_ / 128, NROWS / 128), blk, 0, stream>>>(yb16, pw1t, pw1_b, nullptr, hb16, nullptr, nullptr, nullptr, NROWS, 2 * INNER_, D_);
  glu_kernel<<<NROWS * INNER_ / 1024, blk, 0, stream>>>(hb16, zb16);
  dwconv_kernel<<<dim3(S_ / CTS, B_, 4), blk, 0, stream>>>(zb16, dw_w, dw_b, bn_g, bn_b, bn_mean, bn_var, cb16);
  mfma_gemm<3, float><<<dim3(D_ / 128, NROWS / 128), blk, 0, stream>>>(cb16, pw2t, pw2_b, xb, xb, nullptr, nullptr, nullptr, NROWS, D_, INNER_);

  // ---- FF2 half-residual ----
  ln_kernel<short><<<NROWS, blk, 0, stream>>>(xb, ff2_ln_g, ff2_ln_b, yb16);
  mfma_gemm<1, short><<<dim3(FF_ / 128, NROWS / 128), blk, 0, stream>>>(yb16, ff2w1t, ff2_b1, nullptr, hb16, nullptr, nullptr, nullptr, NROWS, FF_, D_);
  mfma_gemm<2, float><<<dim3(D_ / 128, NROWS / 128), blk, 0, stream>>>(hb16, ff2w2t, ff2_b2, xb, xb, nullptr, nullptr, nullptr, NROWS, D_, FF_);

  // ---- final LN ----
  ln_kernel<float><<<NROWS, blk, 0, stream>>>(xb, norm_g, norm_b, (float*)d_out);
}

// Round 8
// 512.202 us; speedup vs baseline: 6.3044x; 1.1158x over previous
//
#include <hip/hip_runtime.h>
#include <cstdint>
#include <cstddef>

#define B_ 8
#define S_ 1024
#define D_ 512
#define H_ 8
#define DH_ 64
#define FF_ 2048
#define INNER_ 1024
#define NROWS 8192
#define INV_SQRT_D 0.04419417382415922f  // 1/sqrt(512)

typedef __attribute__((ext_vector_type(8))) short bf16x8;
typedef __attribute__((ext_vector_type(4))) float f32x4;
struct alignas(8) short4x { short x, y, z, w; };

__device__ __forceinline__ float sigmoidf_(float x) { return 1.f / (1.f + expf(-x)); }

__device__ __forceinline__ short f2bf(float f) {  // RNE float->bf16
  uint32_t u = __float_as_uint(f);
  u += 0x7fff + ((u >> 16) & 1);
  return (short)(u >> 16);
}
__device__ __forceinline__ float bf2f(short s) {
  return __uint_as_float(((uint32_t)(uint16_t)s) << 16);
}

__device__ __forceinline__ void store_out(float* C, size_t i, float v) { C[i] = v; }
__device__ __forceinline__ void store_out(short* C, size_t i, float v) { C[i] = f2bf(v); }

__device__ __forceinline__ void gload_lds16(const void* g, void* lds) {
  __builtin_amdgcn_global_load_lds(
      (const __attribute__((address_space(1))) uint32_t*)g,
      (__attribute__((address_space(3))) uint32_t*)lds, 16, 0, 0);
}

// ---------------- LayerNorm over D=512, one block (256 thr) per row ----------------
template <typename OutT>
__global__ __launch_bounds__(256) void ln_kernel(const float* __restrict__ in,
    const float* __restrict__ g, const float* __restrict__ b,
    OutT* __restrict__ out) {
  int row = blockIdx.x;
  const float* x = in + (size_t)row * D_;
  OutT* o = out + (size_t)row * D_;
  int t = threadIdx.x;
  float v0 = x[t], v1 = x[t + 256];
  float s = v0 + v1, q = v0 * v0 + v1 * v1;
#pragma unroll
  for (int off = 32; off > 0; off >>= 1) {
    s += __shfl_down(s, off);
    q += __shfl_down(q, off);
  }
  __shared__ float red[8];
  int wid = t >> 6, lane = t & 63;
  if (lane == 0) { red[wid] = s; red[wid + 4] = q; }
  __syncthreads();
  if (t == 0) {
    float S = red[0] + red[1] + red[2] + red[3];
    float Q = red[4] + red[5] + red[6] + red[7];
    float mean = S * (1.f / D_);
    float var = Q * (1.f / D_) - mean * mean;
    red[0] = mean;
    red[1] = rsqrtf(var + 1e-5f);
  }
  __syncthreads();
  float mean = red[0], inv = red[1];
  store_out(o, t, (v0 - mean) * inv * g[t] + b[t]);
  store_out(o, t + 256, (v1 - mean) * inv * g[t + 256] + b[t + 256]);
}

// ---------------- weight transpose + bf16 convert: in[K,N] fp32 -> out[N,K] bf16 ----------------
__global__ __launch_bounds__(256) void transpose_bf16_kernel(const float* __restrict__ in,
    short* __restrict__ out, int K, int N) {
  __shared__ float t[32][33];
  int n0 = blockIdx.x << 5, k0 = blockIdx.y << 5;
  int tx = threadIdx.x & 31, ty = threadIdx.x >> 5;  // 32 x 8
#pragma unroll
  for (int e = 0; e < 4; ++e)
    t[ty + e * 8][tx] = in[(size_t)(k0 + ty + e * 8) * N + n0 + tx];
  __syncthreads();
#pragma unroll
  for (int e = 0; e < 4; ++e)
    out[(size_t)(n0 + ty + e * 8) * K + k0 + tx] = f2bf(t[tx][ty + e * 8]);
}

// ---------------- MFMA bf16 GEMM: C[M,N] = epi(A[M,K] @ Bt[N,K]^T + bias) ----------------
// 128xBN tile (BN=128 or 64), BK=32, 4 waves, 16x16x32 MFMA, fp32 accum.
// Double-buffered LDS, 2-phase: stage(t+1) issued BEFORE compute(t); ONE barrier/step.
// XCD-aware block swizzle (T1). EPI: 0=bias, 1=bias+swish, 2=0.5*v+res, 3=v+res,
//      4=q-path (C=v+bias2, C2=v+bias3, both bf16), 5=v-transpose (vT[b,hd,s])
template <int BN, int EPI, typename OutT>
__global__ __launch_bounds__(256) void mfma_gemm(const short* __restrict__ A,
    const short* __restrict__ Bt, const float* __restrict__ bias,
    const float* __restrict__ res, OutT* __restrict__ C, short* __restrict__ C2,
    const float* __restrict__ bias2, const float* __restrict__ bias3,
    int M, int N, int K) {
  constexpr int NFN = BN / 32;  // N-frags per wave (wave tile 64 x BN/2)
  __shared__ short As[2][128 * 32];
  __shared__ short Bs[2][BN * 32];
  int tid = threadIdx.x;
  int w = tid >> 6, l = tid & 63;
  int nwg = gridDim.x * gridDim.y;
  int flat = blockIdx.y * gridDim.x + blockIdx.x;
  int W = (flat & 7) * (nwg >> 3) + (flat >> 3);
  int bm = (W / gridDim.x) << 7, bn = (W % gridDim.x) * BN;
  int wr = w >> 1, wc = w & 1;
  f32x4 acc[4][NFN] = {};

  int sr = l >> 2, sc = l & 3;
  int ra0 = (w * 2 + 0) * 16 + sr;
  int ra1 = (w * 2 + 1) * 16 + sr;
  int ga0 = sc ^ ((ra0 >> 1) & 3);
  int ga1 = sc ^ ((ra1 >> 1) & 3);
  const short* a0 = A + (size_t)(bm + ra0) * K + ga0 * 8;
  const short* a1 = A + (size_t)(bm + ra1) * K + ga1 * 8;
  int rb0 = (BN == 128) ? ra0 : (w * 16 + sr);
  int gb0 = sc ^ ((rb0 >> 1) & 3);
  const short* b0 = Bt + (size_t)(bn + rb0) * K + gb0 * 8;
  const short* b1 = Bt + (size_t)(bn + ra1) * K + ga1 * 8;  // BN==128 only
  int asd0 = (w * 2 + 0) * 512;
  int asd1 = (w * 2 + 1) * 512;
  int bsd0 = (BN == 128) ? asd0 : w * 512;

  int lcol = l & 15, lk = l >> 4;
  int aoff[4], boff[NFN];
#pragma unroll
  for (int m = 0; m < 4; ++m) {
    int r = wr * 64 + m * 16 + lcol;
    aoff[m] = r * 32 + ((lk ^ ((r >> 1) & 3)) << 3);
  }
#pragma unroll
  for (int n = 0; n < NFN; ++n) {
    int r = wc * (BN / 2) + n * 16 + lcol;
    boff[n] = r * 32 + ((lk ^ ((r >> 1) & 3)) << 3);
  }

  int nt = K >> 5;
  // prologue: stage tile 0 into buf 0
  gload_lds16(a0, &As[0][asd0]);
  gload_lds16(a1, &As[0][asd1]);
  gload_lds16(b0, &Bs[0][bsd0]);
  if constexpr (BN == 128) gload_lds16(b1, &Bs[0][asd1]);
  __syncthreads();

  for (int t = 0; t < nt; ++t) {
    int cur = t & 1;
    if (t + 1 < nt) {  // issue next tile's DMA BEFORE compute -> overlaps
      int k1 = (t + 1) << 5;
      gload_lds16(a0 + k1, &As[cur ^ 1][asd0]);
      gload_lds16(a1 + k1, &As[cur ^ 1][asd1]);
      gload_lds16(b0 + k1, &Bs[cur ^ 1][bsd0]);
      if constexpr (BN == 128) gload_lds16(b1 + k1, &Bs[cur ^ 1][asd1]);
    }
    bf16x8 af[4], bfr[NFN];
#pragma unroll
    for (int m = 0; m < 4; ++m) af[m] = *(const bf16x8*)(&As[cur][aoff[m]]);
#pragma unroll
    for (int n = 0; n < NFN; ++n) bfr[n] = *(const bf16x8*)(&Bs[cur][boff[n]]);
#pragma unroll
    for (int m = 0; m < 4; ++m)
#pragma unroll
      for (int n = 0; n < NFN; ++n)
        acc[m][n] = __builtin_amdgcn_mfma_f32_16x16x32_bf16(af[m], bfr[n], acc[m][n], 0, 0, 0);
    __syncthreads();  // drains next-tile DMA; protects cur buffer for next overwrite
  }

  int lrow = (l >> 4) << 2;
#pragma unroll
  for (int m = 0; m < 4; ++m) {
    int row0 = bm + wr * 64 + m * 16 + lrow;
#pragma unroll
    for (int n = 0; n < NFN; ++n) {
      int col = bn + wc * (BN / 2) + n * 16 + lcol;
      float bv = bias ? bias[col] : 0.f;
      if (EPI == 5) {
        short4x o;
        o.x = f2bf(acc[m][n][0] + bv);
        o.y = f2bf(acc[m][n][1] + bv);
        o.z = f2bf(acc[m][n][2] + bv);
        o.w = f2bf(acc[m][n][3] + bv);
        size_t tidx = ((size_t)(row0 >> 10) * 512 + col) * 1024 + (row0 & 1023);
        *(short4x*)((short*)C + tidx) = o;
      } else if (EPI == 4) {
#pragma unroll
        for (int r = 0; r < 4; ++r) {
          size_t idx = (size_t)(row0 + r) * N + col;
          float v = acc[m][n][r] + bv;
          ((short*)C)[idx] = f2bf(v + bias2[col]);
          C2[idx] = f2bf(v + bias3[col]);
        }
      } else {
#pragma unroll
        for (int r = 0; r < 4; ++r) {
          size_t idx = (size_t)(row0 + r) * N + col;
          float v = acc[m][n][r] + bv;
          if (EPI == 1) v = v * sigmoidf_(v);
          else if (EPI == 2) v = 0.5f * v + res[idx];
          else if (EPI == 3) v = v + res[idx];
          store_out(C, idx, v);
        }
      }
    }
  }
}

// ---------------- sinusoidal positional encoding (S=1024, D=512), bf16 out ----------------
__global__ __launch_bounds__(256) void pe_kernel(short* __restrict__ pe) {
  int t = blockIdx.x, i = threadIdx.x;  // i in 0..255
  float freq = expf((float)(2 * i) * (-9.2103403719761836f / 512.f));  // ln(10000)
  float arg = (float)t * freq;
  pe[(size_t)t * D_ + 2 * i] = f2bf(sinf(arg));
  pe[(size_t)t * D_ + 2 * i + 1] = f2bf(cosf(arg));
}

// ---------------- pos scores, PRE-SHIFTED: Pshift[z,i,j] = rel_shift(qv.pos)[i,j] ----------------
__global__ __launch_bounds__(256) void attn_pos_mfma(const short* __restrict__ Qb,
    const short* __restrict__ Pos, short* __restrict__ Out, int bh0) {
  __shared__ short Qs[128 * 64];
  __shared__ short Ks[128 * 64];
  int tid = threadIdx.x;
  int w = tid >> 6, l = tid & 63;
  int z = blockIdx.z;
  int bh = bh0 + z, b = bh >> 3, h = bh & 7;
  int bi = blockIdx.y << 7, bj = blockIdx.x << 7;
  int srow = w * 8 + (l >> 3);
  int sch = l & 7;
#pragma unroll
  for (int cc = 0; cc < 4; ++cc) {
    int r = cc * 32 + srow;
    int g = sch ^ (r & 7);
    gload_lds16(Qb + (size_t)(b * S_ + bi + r) * D_ + h * DH_ + g * 8, Qs + (cc * 32 + w * 8) * 64);
    gload_lds16(Pos + (size_t)(bj + r) * D_ + h * DH_ + g * 8, Ks + (cc * 32 + w * 8) * 64);
  }
  __syncthreads();
  int wr = w >> 1, wc = w & 1;
  int lcol = l & 15, lk = l >> 4;
  bf16x8 qf[4][2], kf[4][2];
#pragma unroll
  for (int m = 0; m < 4; ++m)
#pragma unroll
    for (int ks = 0; ks < 2; ++ks) {
      int r = wr * 64 + m * 16 + lcol;
      int c = ks * 4 + lk;
      qf[m][ks] = *(const bf16x8*)(Qs + r * 64 + ((c ^ (r & 7)) << 3));
    }
#pragma unroll
  for (int n = 0; n < 4; ++n)
#pragma unroll
    for (int ks = 0; ks < 2; ++ks) {
      int r = wc * 64 + n * 16 + lcol;
      int c = ks * 4 + lk;
      kf[n][ks] = *(const bf16x8*)(Ks + r * 64 + ((c ^ (r & 7)) << 3));
    }
  f32x4 acc[4][4] = {};
#pragma unroll
  for (int ks = 0; ks < 2; ++ks)
#pragma unroll
    for (int m = 0; m < 4; ++m)
#pragma unroll
      for (int n = 0; n < 4; ++n)
        acc[m][n] = __builtin_amdgcn_mfma_f32_16x16x32_bf16(qf[m][ks], kf[n][ks], acc[m][n], 0, 0, 0);
  int lrow = (l >> 4) << 2;
  short* Oz = Out + (size_t)z * S_ * S_;
#pragma unroll
  for (int m = 0; m < 4; ++m)
#pragma unroll
    for (int r = 0; r < 4; ++r) {
      int iG = bi + wr * 64 + m * 16 + lrow + r;
#pragma unroll
      for (int n = 0; n < 4; ++n) {
        int tG = bj + wc * 64 + n * 16 + lcol;
        short val = f2bf(acc[m][n][r]);
        if (tG >= S_ - 1 - iG)
          Oz[(size_t)iG * S_ + (tG - (S_ - 1 - iG))] = val;
        else if (iG >= 1)
          Oz[(size_t)(iG - 1) * S_ + (tG + iG + 1)] = val;
        if (tG == 0 && iG < S_ - 1)
          Oz[(size_t)iG * S_ + iG + 1] = 0;
      }
    }
}

// ---------------- fused attention: S=qu.k^T + Pshift; online softmax; O=P.V ----------------
__global__ __launch_bounds__(512) void attn_fused(const short* __restrict__ qu,
    const short* __restrict__ kk, const short* __restrict__ vT,
    const short* __restrict__ Psh, short* __restrict__ ctx, int bh0) {
  __shared__ short Ks[2][64 * 64];
  __shared__ short Vs[2][64 * 64];
  __shared__ short Ps[128 * 64];
  int tid = threadIdx.x;
  int w = tid >> 6, l = tid & 63;
  int z = blockIdx.y;
  int bh = bh0 + z, b = bh >> 3, h = bh & 7;
  int i0 = blockIdx.x << 7;
  bf16x8 qf0, qf1;
  {
    const short* qrow = qu + (size_t)(b * S_ + i0 + w * 16 + (l & 15)) * D_ + h * DH_ + ((l >> 4) << 3);
    qf0 = *(const bf16x8*)(qrow);
    qf1 = *(const bf16x8*)(qrow + 32);
  }
  f32x4 po[4] = {};
  float mrow[4], lrw[4];
  int gi[4];
#pragma unroll
  for (int r = 0; r < 4; ++r) {
    mrow[r] = -1e30f;
    lrw[r] = 0.f;
    gi[r] = i0 + w * 16 + ((l >> 4) << 2) + r;
  }
  const short* prow0 = Psh + (size_t)z * S_ * S_ + (size_t)gi[0] * S_ + (l & 15);
  const short* prow1 = prow0 + S_;
  const short* prow2 = prow1 + S_;
  const short* prow3 = prow2 + S_;

  int srw = (w << 3) + (l >> 3);      // 0..63
  int sg = (l & 7) ^ (srw & 7);       // swizzled source chunk
  const short* ksrc = kk + (size_t)(b * S_) * D_ + h * DH_ + (sg << 3);
  const short* vsrc = vT + (size_t)(b * 512 + h * DH_ + srw) * 1024 + (sg << 3);
  int sdst = (w << 3) * 64;

#define STAGE_KV(jt, buf)                                                  \
  {                                                                        \
    int j0_ = (jt) << 6;                                                   \
    gload_lds16(ksrc + (size_t)(j0_ + srw) * D_, &Ks[buf][sdst]);          \
    gload_lds16(vsrc + j0_, &Vs[buf][sdst]);                               \
  }

  float pvc[4][4], pvn[4][4];
#define PLOADF(jt, dst)                                                    \
  {                                                                        \
    int j0_ = (jt) << 6;                                                   \
    _Pragma("unroll") for (int n_ = 0; n_ < 4; ++n_) {                     \
      dst[n_][0] = bf2f(prow0[j0_ + (n_ << 4)]);                           \
      dst[n_][1] = bf2f(prow1[j0_ + (n_ << 4)]);                           \
      dst[n_][2] = bf2f(prow2[j0_ + (n_ << 4)]);                           \
      dst[n_][3] = bf2f(prow3[j0_ + (n_ << 4)]);                           \
    }                                                                      \
  }

  STAGE_KV(0, 0);
  PLOADF(0, pvc);
  __syncthreads();

  for (int jt = 0; jt < 16; ++jt) {
    int buf = jt & 1;
    if (jt < 15) {
      STAGE_KV(jt + 1, buf ^ 1);  // DMA into other buffer; completes by end-of-step barrier
      PLOADF(jt + 1, pvn);        // register prefetch, hides under this step's compute
    }
    f32x4 sc[4] = {};
#pragma unroll
    for (int ks = 0; ks < 2; ++ks)
#pragma unroll
      for (int n = 0; n < 4; ++n) {
        int rj = (n << 4) + (l & 15);
        int ck = (ks << 2) + (l >> 4);
        bf16x8 kf = *(const bf16x8*)(&Ks[buf][rj * 64 + ((ck ^ (rj & 7)) << 3)]);
        sc[n] = __builtin_amdgcn_mfma_f32_16x16x32_bf16(ks == 0 ? qf0 : qf1, kf, sc[n], 0, 0, 0);
      }
    float pm[4];
#pragma unroll
    for (int r = 0; r < 4; ++r) pm[r] = -1e30f;
#pragma unroll
    for (int n = 0; n < 4; ++n)
#pragma unroll
      for (int r = 0; r < 4; ++r) {
        float v = (sc[n][r] + pvc[n][r]) * INV_SQRT_D;
        sc[n][r] = v;
        pm[r] = fmaxf(pm[r], v);
      }
#pragma unroll
    for (int r = 0; r < 4; ++r)
#pragma unroll
      for (int off = 1; off < 16; off <<= 1) pm[r] = fmaxf(pm[r], __shfl_xor(pm[r], off));
    float psum[4];
#pragma unroll
    for (int r = 0; r < 4; ++r) {
      float mn = fmaxf(mrow[r], pm[r]);
      float f = __expf(mrow[r] - mn);
      mrow[r] = mn;
      lrw[r] *= f;
#pragma unroll
      for (int n = 0; n < 4; ++n) po[n][r] *= f;
      psum[r] = 0.f;
    }
#pragma unroll
    for (int n = 0; n < 4; ++n)
#pragma unroll
      for (int r = 0; r < 4; ++r) {
        float p = __expf(sc[n][r] - mrow[r]);
        psum[r] += p;
        int rr = (w << 4) + ((l >> 4) << 2) + r;
        int c = (n << 4) + (l & 15);
        Ps[rr * 64 + (((c >> 3) ^ (rr & 7)) << 3) + (c & 7)] = f2bf(p);
      }
#pragma unroll
    for (int r = 0; r < 4; ++r) {
#pragma unroll
      for (int off = 1; off < 16; off <<= 1) psum[r] += __shfl_xor(psum[r], off);
      lrw[r] += psum[r];
    }
    int rr2 = (w << 4) + (l & 15);
    bf16x8 pa[2];
#pragma unroll
    for (int ks = 0; ks < 2; ++ks) {
      int ck = (ks << 2) + (l >> 4);
      pa[ks] = *(const bf16x8*)(&Ps[rr2 * 64 + ((ck ^ (rr2 & 7)) << 3)]);
    }
#pragma unroll
    for (int ks = 0; ks < 2; ++ks)
#pragma unroll
      for (int n = 0; n < 4; ++n) {
        int rd = (n << 4) + (l & 15);
        int ck = (ks << 2) + (l >> 4);
        bf16x8 vf = *(const bf16x8*)(&Vs[buf][rd * 64 + ((ck ^ (rd & 7)) << 3)]);
        po[n] = __builtin_amdgcn_mfma_f32_16x16x32_bf16(pa[ks], vf, po[n], 0, 0, 0);
      }
    __syncthreads();
    if (jt < 15) {
#pragma unroll
      for (int n = 0; n < 4; ++n)
#pragma unroll
        for (int r = 0; r < 4; ++r) pvc[n][r] = pvn[n][r];
    }
  }
  short* Cz = ctx + (size_t)b * S_ * D_ + h * DH_;
#pragma unroll
  for (int r = 0; r < 4; ++r) {
    float inv = 1.f / lrw[r];
#pragma unroll
    for (int n = 0; n < 4; ++n)
      Cz[(size_t)gi[r] * D_ + (n << 4) + (l & 15)] = f2bf(po[n][r] * inv);
  }
#undef STAGE_KV
#undef PLOADF
}

// ---------------- GLU bf16: z[r,c] = a * sigmoid(g) ----------------
__global__ __launch_bounds__(256) void glu_kernel(const short* __restrict__ hbuf,
                                                  short* __restrict__ z) {
  size_t idx4 = ((size_t)blockIdx.x * 256 + threadIdx.x) << 2;
  size_t row = idx4 >> 10, c = idx4 & 1023;
  short4x a4 = *(const short4x*)(hbuf + row * 2048 + c);
  short4x g4 = *(const short4x*)(hbuf + row * 2048 + 1024 + c);
  short4x o;
  o.x = f2bf(bf2f(a4.x) * sigmoidf_(bf2f(g4.x)));
  o.y = f2bf(bf2f(a4.y) * sigmoidf_(bf2f(g4.y)));
  o.z = f2bf(bf2f(a4.z) * sigmoidf_(bf2f(g4.z)));
  o.w = f2bf(bf2f(a4.w) * sigmoidf_(bf2f(g4.w)));
  *(short4x*)(z + idx4) = o;
}

// ---------------- depthwise conv k=31 (+BN+swish), (b,s,c) bf16 in/out ----------------
#define CTS 32
__global__ __launch_bounds__(256) void dwconv_kernel(const short* __restrict__ z,
    const float* __restrict__ w, const float* __restrict__ wb,
    const float* __restrict__ bng, const float* __restrict__ bnb,
    const float* __restrict__ bnm, const float* __restrict__ bnv,
    short* __restrict__ out) {
  int c = (blockIdx.z << 8) + threadIdx.x;  // channel 0..1023
  int b = blockIdx.y;
  int s0 = blockIdx.x * CTS;
  float wr[31];
#pragma unroll
  for (int kk = 0; kk < 31; ++kk) wr[kk] = w[c * 31 + kk];
  float zv[CTS + 30];
#pragma unroll
  for (int e = 0; e < CTS + 30; ++e) {
    int sr = s0 - 15 + e;
    zv[e] = (sr >= 0 && sr < S_) ? bf2f(z[((size_t)(b * S_ + sr) << 10) + c]) : 0.f;
  }
  float scale = bng[c] * rsqrtf(bnv[c] + 1e-5f);
  float shift = bnb[c] - bnm[c] * scale;
  float bias = wb[c];
#pragma unroll
  for (int s = 0; s < CTS; ++s) {
    float acc = 0.f;
#pragma unroll
    for (int kk = 0; kk < 31; ++kk) acc += zv[s + kk] * wr[kk];
    float v = (acc + bias) * scale + shift;
    v = v * sigmoidf_(v);
    out[((size_t)(b * S_ + s0 + s) << 10) + c] = f2bf(v);
  }
}

extern "C" void kernel_launch(void* const* d_in, const int* in_sizes, int n_in,
                              void* d_out, int out_size, void* d_ws, size_t ws_size,
                              hipStream_t stream) {
  const float* x_in = (const float*)d_in[0];
  const float* ff1_ln_g = (const float*)d_in[1];
  const float* ff1_ln_b = (const float*)d_in[2];
  const float* ff1_w1 = (const float*)d_in[3];
  const float* ff1_b1 = (const float*)d_in[4];
  const float* ff1_w2 = (const float*)d_in[5];
  const float* ff1_b2 = (const float*)d_in[6];
  const float* attn_ln_g = (const float*)d_in[7];
  const float* attn_ln_b = (const float*)d_in[8];
  const float* wq = (const float*)d_in[9];
  const float* bq = (const float*)d_in[10];
  const float* wk = (const float*)d_in[11];
  const float* bk = (const float*)d_in[12];
  const float* wv = (const float*)d_in[13];
  const float* bv = (const float*)d_in[14];
  const float* wpos = (const float*)d_in[15];
  const float* u_bias = (const float*)d_in[16];
  const float* v_bias = (const float*)d_in[17];
  const float* wo = (const float*)d_in[18];
  const float* bo = (const float*)d_in[19];
  const float* conv_ln_g = (const float*)d_in[20];
  const float* conv_ln_b = (const float*)d_in[21];
  const float* pw1_w = (const float*)d_in[22];
  const float* pw1_b = (const float*)d_in[23];
  const float* dw_w = (const float*)d_in[24];
  const float* dw_b = (const float*)d_in[25];
  const float* bn_g = (const float*)d_in[26];
  const float* bn_b = (const float*)d_in[27];
  const float* bn_mean = (const float*)d_in[28];
  const float* bn_var = (const float*)d_in[29];
  const float* pw2_w = (const float*)d_in[30];
  const float* pw2_b = (const float*)d_in[31];
  const float* ff2_ln_g = (const float*)d_in[32];
  const float* ff2_ln_b = (const float*)d_in[33];
  const float* ff2_w1 = (const float*)d_in[34];
  const float* ff2_b1 = (const float*)d_in[35];
  const float* ff2_w2 = (const float*)d_in[36];
  const float* ff2_b2 = (const float*)d_in[37];
  const float* norm_g = (const float*)d_in[38];
  const float* norm_b = (const float*)d_in[39];

  char* wsb = (char*)d_ws;
  float* xb = (float*)(wsb);                      // 16 MiB fp32 residual
  short* yb16 = (short*)(wsb + (16ull << 20));    // 8 MiB  LN out
  short* qu16 = (short*)(wsb + (24ull << 20));    // 8 MiB
  short* qv16 = (short*)(wsb + (32ull << 20));    // 8 MiB
  short* k16 = (short*)(wsb + (40ull << 20));     // 8 MiB
  short* vT16 = (short*)(wsb + (48ull << 20));    // 8 MiB
  short* ctx16 = (short*)(wsb + (56ull << 20));   // 8 MiB
  short* pos16 = (short*)(wsb + (64ull << 20));   // 1 MiB
  short* wt = (short*)(wsb + (65ull << 20));      // 13.5 MiB
  short* Pb16 = (short*)(wsb + (80ull << 20));    // 64 MiB (32-bh chunk), attn phase only
  short* hb16 = (short*)(wsb + (80ull << 20));    // 32 MiB FF hidden / pw1-out (non-attn phases)
  short* zb16 = (short*)(wsb + (112ull << 20));   // 16 MiB GLU out
  short* cb16 = (short*)(wsb + (128ull << 20));   // 16 MiB dwconv out
  short* peb16 = ctx16;                           // PE scratch (free at that point)

  short* ff1w1t = wt;
  short* ff1w2t = ff1w1t + 2048 * 512;
  short* wqt = ff1w2t + 512 * 2048;
  short* wkt = wqt + 512 * 512;
  short* wvt = wkt + 512 * 512;
  short* wot = wvt + 512 * 512;
  short* wpost = wot + 512 * 512;
  short* pw1t = wpost + 512 * 512;
  short* pw2t = pw1t + 2048 * 512;
  short* ff2w1t = pw2t + 512 * 1024;
  short* ff2w2t = ff2w1t + 2048 * 512;

  dim3 blk(256);

  // ---- weight transposes (fp32 [K,N] -> bf16 [N,K]) ----
  transpose_bf16_kernel<<<dim3(64, 16), blk, 0, stream>>>(ff1_w1, ff1w1t, 512, 2048);
  transpose_bf16_kernel<<<dim3(16, 64), blk, 0, stream>>>(ff1_w2, ff1w2t, 2048, 512);
  transpose_bf16_kernel<<<dim3(16, 16), blk, 0, stream>>>(wq, wqt, 512, 512);
  transpose_bf16_kernel<<<dim3(16, 16), blk, 0, stream>>>(wk, wkt, 512, 512);
  transpose_bf16_kernel<<<dim3(16, 16), blk, 0, stream>>>(wv, wvt, 512, 512);
  transpose_bf16_kernel<<<dim3(16, 16), blk, 0, stream>>>(wo, wot, 512, 512);
  transpose_bf16_kernel<<<dim3(16, 16), blk, 0, stream>>>(wpos, wpost, 512, 512);
  transpose_bf16_kernel<<<dim3(64, 16), blk, 0, stream>>>(pw1_w, pw1t, 512, 2048);
  transpose_bf16_kernel<<<dim3(16, 32), blk, 0, stream>>>(pw2_w, pw2t, 1024, 512);
  transpose_bf16_kernel<<<dim3(64, 16), blk, 0, stream>>>(ff2_w1, ff2w1t, 512, 2048);
  transpose_bf16_kernel<<<dim3(16, 64), blk, 0, stream>>>(ff2_w2, ff2w2t, 2048, 512);

  // ---- FF1 half-residual ----
  ln_kernel<short><<<NROWS, blk, 0, stream>>>(x_in, ff1_ln_g, ff1_ln_b, yb16);
  mfma_gemm<128, 1, short><<<dim3(FF_ / 128, NROWS / 128), blk, 0, stream>>>(yb16, ff1w1t, ff1_b1, nullptr, hb16, nullptr, nullptr, nullptr, NROWS, FF_, D_);
  mfma_gemm<64, 2, float><<<dim3(D_ / 64, NROWS / 128), blk, 0, stream>>>(hb16, ff1w2t, ff1_b2, x_in, xb, nullptr, nullptr, nullptr, NROWS, D_, FF_);

  // ---- attention ----
  ln_kernel<short><<<NROWS, blk, 0, stream>>>(xb, attn_ln_g, attn_ln_b, yb16);
  mfma_gemm<64, 4, short><<<dim3(D_ / 64, NROWS / 128), blk, 0, stream>>>(yb16, wqt, bq, nullptr, qu16, qv16, u_bias, v_bias, NROWS, D_, D_);
  mfma_gemm<64, 0, short><<<dim3(D_ / 64, NROWS / 128), blk, 0, stream>>>(yb16, wkt, bk, nullptr, k16, nullptr, nullptr, nullptr, NROWS, D_, D_);
  mfma_gemm<64, 5, short><<<dim3(D_ / 64, NROWS / 128), blk, 0, stream>>>(yb16, wvt, bv, nullptr, vT16, nullptr, nullptr, nullptr, NROWS, D_, D_);
  pe_kernel<<<S_, blk, 0, stream>>>(peb16);
  mfma_gemm<64, 0, short><<<dim3(D_ / 64, S_ / 128), blk, 0, stream>>>(peb16, wpost, nullptr, nullptr, pos16, nullptr, nullptr, nullptr, S_, D_, D_);

  const int CH = 32;  // bh per chunk (P chunk = 64 MiB bf16)
  for (int c = 0; c < 64 / CH; ++c) {
    int bh0 = c * CH;
    attn_pos_mfma<<<dim3(8, 8, CH), blk, 0, stream>>>(qv16, pos16, Pb16, bh0);
    attn_fused<<<dim3(S_ / 128, CH), dim3(512), 0, stream>>>(qu16, k16, vT16, Pb16, ctx16, bh0);
  }
  mfma_gemm<64, 3, float><<<dim3(D_ / 64, NROWS / 128), blk, 0, stream>>>(ctx16, wot, bo, xb, xb, nullptr, nullptr, nullptr, NROWS, D_, D_);

  // ---- conv module ----
  ln_kernel<short><<<NROWS, blk, 0, stream>>>(xb, conv_ln_g, conv_ln_b, yb16);
  mfma_gemm<128, 0, short><<<dim3(2 * INNER_ / 128, NROWS / 128), blk, 0, stream>>>(yb16, pw1t, pw1_b, nullptr, hb16, nullptr, nullptr, nullptr, NROWS, 2 * INNER_, D_);
  glu_kernel<<<NROWS * INNER_ / 1024, blk, 0, stream>>>(hb16, zb16);
  dwconv_kernel<<<dim3(S_ / CTS, B_, 4), blk, 0, stream>>>(zb16, dw_w, dw_b, bn_g, bn_b, bn_mean, bn_var, cb16);
  mfma_gemm<64, 3, float><<<dim3(D_ / 64, NROWS / 128), blk, 0, stream>>>(cb16, pw2t, pw2_b, xb, xb, nullptr, nullptr, nullptr, NROWS, D_, INNER_);

  // ---- FF2 half-residual ----
  ln_kernel<short><<<NROWS, blk, 0, stream>>>(xb, ff2_ln_g, ff2_ln_b, yb16);
  mfma_gemm<128, 1, short><<<dim3(FF_ / 128, NROWS / 128), blk, 0, stream>>>(yb16, ff2w1t, ff2_b1, nullptr, hb16, nullptr, nullptr, nullptr, NROWS, FF_, D_);
  mfma_gemm<64, 2, float><<<dim3(D_ / 64, NROWS / 128), blk, 0, stream>>>(hb16, ff2w2t, ff2_b2, xb, xb, nullptr, nullptr, nullptr, NROWS, D_, FF_);

  // ---- final LN ----
  ln_kernel<float><<<NROWS, blk, 0, stream>>>(xb, norm_g, norm_b, (float*)d_out);
}